// Round 4
// baseline (2261.283 us; speedup 1.0000x reference)
//
#include <hip/hip_runtime.h>
#include <math.h>

#define YB (50*128*512)   // y_seq batch stride (floats)
#define YT (128*512)      // y_seq time stride
#define DTc 0.5f
#define NBLK 512

typedef __attribute__((ext_vector_type(8))) short bf16x8;
typedef __attribute__((ext_vector_type(4))) float f32x4;

__device__ __forceinline__ unsigned short f2bf(float f) {
    unsigned int u = __builtin_bit_cast(unsigned int, f);
    u += 0x7fffu + ((u >> 16) & 1u);          // RNE
    return (unsigned short)(u >> 16);
}

__device__ __forceinline__ float tanh_fast(float x) {
    float ax = fabsf(x);
    float e  = __expf(-2.f * ax);
    float r  = (1.f - e) * __builtin_amdgcn_rcpf(1.f + e);
    return __builtin_copysignf(r, x);
}

// raw block barrier: waits LDS ops only, lets global stores stay in flight
__device__ __forceinline__ void lds_sync() {
    asm volatile("s_waitcnt lgkmcnt(0)" ::: "memory");
    __builtin_amdgcn_sched_barrier(0);
    __builtin_amdgcn_s_barrier();
    __builtin_amdgcn_sched_barrier(0);
}

// ==================== fused weight prep ====================
struct WSrc { const float* p[11]; };  // ow1,aw1,hw1, ow2,ow3,aw2,aw3,hw2,hw3,hw4, wy
__global__ void wprep_all_k(WSrc s, float* __restrict__ wt, unsigned short* __restrict__ w2) {
    int idx = blockIdx.x * 256 + threadIdx.x;
    if (idx < 9216) {
        int wsel = idx / 3072, r = idx % 3072;
        int row = r >> 7, co = r & 127;
        int ci = row / 3, k = row - ci * 3;
        wt[idx] = s.p[wsel][(co * 8 + ci) * 3 + k];
    } else if (idx < 353280) {
        int r = idx - 9216;
        int wsel = 3 + r / 49152, q = r % 49152;
        int row = q >> 7, co = q & 127;
        int ci = row / 3, k = row - ci * 3;
        wt[idx] = s.p[wsel][(co * 128 + ci) * 3 + k];
    } else if (idx < 402432) {
        int q = idx - 353280;
        int co = q / 384, kap = q - co * 384;
        int k = kap >> 7;
        int ci = ((kap >> 5) & 3) * 32 + (kap & 31);
        w2[q] = f2bf(s.p[10][(co * 128 + ci) * 3 + k]);
    }
}

// ==================== encoder convs (fp32, job-batched) ====================
struct Job { const float* src; float* dst; const float* wt; const float* bias; int sbs, dbs, act; };
struct Jobs3 { Job j[3]; };

__global__ __launch_bounds__(256) void conv8x3_k(Jobs3 js) {
    int jb = blockIdx.y % 3;
    Job jo = js.j[jb];
    int b = blockIdx.z, tile = blockIdx.x, tid = threadIdx.x;
    int l0 = tile * 64;
    int tl4 = (tid & 15) * 4;
    int co0 = (tid >> 4) * 8;
    __shared__ float xs[8 * 68];
    __shared__ float wsh[24 * 128];
    const float* sb = jo.src + (size_t)b * jo.sbs;
    for (int idx = tid; idx < 8 * 66; idx += 256) {
        int ci = idx / 66, ll = idx - ci * 66;
        int gl = l0 - 1 + ll;
        xs[ci * 68 + ll] = (gl >= 0 && gl < 512) ? sb[ci * 512 + gl] : 0.f;
    }
    for (int idx = tid; idx < 24 * 128; idx += 256) wsh[idx] = jo.wt[idx];
    __syncthreads();
    float acc[8][4] = {};
    #pragma unroll
    for (int ci = 0; ci < 8; ++ci) {
        float x6[6];
        #pragma unroll
        for (int j = 0; j < 6; ++j) x6[j] = xs[ci * 68 + tl4 + j];
        #pragma unroll
        for (int k = 0; k < 3; ++k) {
            float w8[8];
            #pragma unroll
            for (int i = 0; i < 8; ++i) w8[i] = wsh[(ci * 3 + k) * 128 + co0 + i];
            #pragma unroll
            for (int i = 0; i < 8; ++i)
                #pragma unroll
                for (int j = 0; j < 4; ++j)
                    acc[i][j] = fmaf(w8[i], x6[k + j], acc[i][j]);
        }
    }
    #pragma unroll
    for (int i = 0; i < 8; ++i) {
        int co = co0 + i;
        float bv = jo.bias[co];
        float4 o;
        o.x = fmaxf(acc[i][0] + bv, 0.f);
        o.y = fmaxf(acc[i][1] + bv, 0.f);
        o.z = fmaxf(acc[i][2] + bv, 0.f);
        o.w = fmaxf(acc[i][3] + bv, 0.f);
        *(float4*)(jo.dst + (size_t)b * jo.dbs + (size_t)co * 512 + l0 + tl4) = o;
    }
}

__global__ __launch_bounds__(256) void conv128x3_k(Jobs3 js) {
    int jb = blockIdx.y >> 1, cb = blockIdx.y & 1;
    Job jo = js.j[jb];
    int b = blockIdx.z, tile = blockIdx.x, tid = threadIdx.x;
    int l0 = tile * 64;
    int tl4 = (tid & 15) * 4;
    int col = (tid >> 4) * 4;
    __shared__ float xs[32 * 68];
    __shared__ float wsh[96 * 64];
    const float* sb = jo.src + (size_t)b * jo.sbs;
    float acc[4][4] = {};
    for (int chunk = 0; chunk < 4; ++chunk) {
        for (int idx = tid; idx < 32 * 66; idx += 256) {
            int ci = idx / 66, ll = idx - ci * 66;
            int gl = l0 - 1 + ll;
            xs[ci * 68 + ll] = (gl >= 0 && gl < 512) ? sb[(chunk * 32 + ci) * 512 + gl] : 0.f;
        }
        for (int idx = tid; idx < 96 * 16; idx += 256) {
            int row = idx >> 4, j = (idx & 15) * 4;
            *(float4*)(wsh + row * 64 + j) =
                *(const float4*)(jo.wt + (size_t)(chunk * 96 + row) * 128 + cb * 64 + j);
        }
        __syncthreads();
        #pragma unroll 4
        for (int ci = 0; ci < 32; ++ci) {
            float x6[6];
            #pragma unroll
            for (int j = 0; j < 6; ++j) x6[j] = xs[ci * 68 + tl4 + j];
            #pragma unroll
            for (int k = 0; k < 3; ++k) {
                float w4[4];
                #pragma unroll
                for (int i = 0; i < 4; ++i) w4[i] = wsh[(ci * 3 + k) * 64 + col + i];
                #pragma unroll
                for (int i = 0; i < 4; ++i)
                    #pragma unroll
                    for (int j = 0; j < 4; ++j)
                        acc[i][j] = fmaf(w4[i], x6[k + j], acc[i][j]);
            }
        }
        __syncthreads();
    }
    #pragma unroll
    for (int i = 0; i < 4; ++i) {
        int co = cb * 64 + col + i;
        float bv = jo.bias[co];
        float v[4];
        #pragma unroll
        for (int j = 0; j < 4; ++j) {
            float tv = acc[i][j] + bv;
            if (jo.act == 1) tv = fmaxf(tv, 0.f);
            else if (jo.act == 2) tv = tanhf(tv);
            v[j] = tv;
        }
        *(float4*)(jo.dst + (size_t)b * jo.dbs + (size_t)co * 512 + l0 + tl4) = *(float4*)v;
    }
}

// ==================== grid barrier ====================
__global__ void zero_bar_k(unsigned* bar) { if (threadIdx.x < 2) bar[threadIdx.x] = 0u; }

__device__ __forceinline__ void grid_barrier(unsigned* bar) {
    unsigned g = __hip_atomic_load(bar + 1, __ATOMIC_ACQUIRE, __HIP_MEMORY_SCOPE_AGENT);
    unsigned a = __hip_atomic_fetch_add(bar, 1u, __ATOMIC_ACQ_REL, __HIP_MEMORY_SCOPE_AGENT);
    if (a == NBLK - 1) {
        __hip_atomic_store(bar, 0u, __ATOMIC_RELAXED, __HIP_MEMORY_SCOPE_AGENT);
        __hip_atomic_fetch_add(bar + 1, 1u, __ATOMIC_ACQ_REL, __HIP_MEMORY_SCOPE_AGENT);
    } else {
        while (__hip_atomic_load(bar + 1, __ATOMIC_ACQUIRE, __HIP_MEMORY_SCOPE_AGENT) == g)
            __builtin_amdgcn_s_sleep(8);
    }
}

// ==================== persistent recurrence ====================
// 512 blocks (16 l-tiles x 32 b), 512 threads (8 waves = 8 co-tiles), 2 blocks/CU.
// Block state: W=48 rows (l = l0-8 .. l0+39) x 128 co; 3 lt frags of 16 rows.
// Lane (wid, lr, kg): co = wid*16+lr; rows 16*lt + kg*4 + j.
// hyS: 50 bf16 rows (l0-9 .. l0+40), [row][ci-chunk ^ (row&7)].
// Chunk = 8 steps; halo via y slab + parity HZE + grid barrier (6 total).
__global__ __launch_bounds__(512, 4) void recur_fused_k(
    const float* __restrict__ hy0,     // [b][co][l], b-stride YB
    const float* __restrict__ omega,   // [b][co][l], b-stride 65536
    const float* __restrict__ alpha,
    const unsigned short* __restrict__ w2,
    float* __restrict__ yout,          // slab 0 base
    float* __restrict__ hze,           // [2][32][16][128][16] f32
    float* __restrict__ part,          // [32][50][128][16]
    unsigned* __restrict__ bar)
{
    int tile = blockIdx.x, b = blockIdx.y;
    int tid = threadIdx.x, lane = tid & 63, wid = tid >> 6;
    int lr = lane & 15, kg = lane >> 4;
    int co = wid * 16 + lr;
    int l0 = tile * 32;

    __shared__ uint4 hyS4[50 * 16];
    __shared__ float temp[128 * 64];
    unsigned short* hyS16 = (unsigned short*)hyS4;

    // B weights (held in regs, 48 VGPR)
    bf16x8 Bw[12];
    {
        const bf16x8* wp = (const bf16x8*)(w2 + (size_t)co * 384);
        #pragma unroll
        for (int s = 0; s < 12; ++s) Bw[s] = wp[s * 4 + kg];
    }

    f32x4 hyR[3], hzR[3], omR[3], alR[3];

    // ---- stage hy (temp covers l = l0-12 .. l0+51)
    for (int i = tid; i < 2048; i += 512) {
        int c = i >> 4, p4 = (i & 15) * 4;
        int l = (l0 - 12 + p4) & 511;
        *(f32x4*)(temp + c * 64 + p4) = *(const f32x4*)(hy0 + (size_t)b * YB + (size_t)c * 512 + l);
    }
    __syncthreads();
    #pragma unroll
    for (int lt = 0; lt < 3; ++lt)
        hyR[lt] = *(const f32x4*)(temp + co * 64 + 4 + 16 * lt + 4 * kg);
    for (int i = tid; i < 50 * 16; i += 512) {
        int h = i >> 4, c8 = i & 15;
        unsigned short pk[8];
        #pragma unroll
        for (int q = 0; q < 8; ++q) pk[q] = f2bf(temp[(c8 * 8 + q) * 64 + h + 3]);
        hyS4[h * 16 + (c8 ^ (h & 7))] = *(uint4*)pk;
    }
    __syncthreads();
    // ---- stage omega
    for (int i = tid; i < 2048; i += 512) {
        int c = i >> 4, p4 = (i & 15) * 4;
        int l = (l0 - 12 + p4) & 511;
        *(f32x4*)(temp + c * 64 + p4) = *(const f32x4*)(omega + (size_t)b * 65536 + (size_t)c * 512 + l);
    }
    __syncthreads();
    #pragma unroll
    for (int lt = 0; lt < 3; ++lt)
        omR[lt] = *(const f32x4*)(temp + co * 64 + 4 + 16 * lt + 4 * kg);
    __syncthreads();
    // ---- stage alpha
    for (int i = tid; i < 2048; i += 512) {
        int c = i >> 4, p4 = (i & 15) * 4;
        int l = (l0 - 12 + p4) & 511;
        *(f32x4*)(temp + c * 64 + p4) = *(const f32x4*)(alpha + (size_t)b * 65536 + (size_t)c * 512 + l);
    }
    __syncthreads();
    #pragma unroll
    for (int lt = 0; lt < 3; ++lt)
        alR[lt] = *(const f32x4*)(temp + co * 64 + 4 + 16 * lt + 4 * kg);
    #pragma unroll
    for (int lt = 0; lt < 3; ++lt) hzR[lt] = (f32x4){0.f, 0.f, 0.f, 0.f};
    __syncthreads();

    // ---- main loop
    for (int t = 0; t < 50; ++t) {
        f32x4 acc[3];
        #pragma unroll
        for (int lt = 0; lt < 3; ++lt) acc[lt] = (f32x4){0.f, 0.f, 0.f, 0.f};
        #pragma unroll
        for (int s = 0; s < 12; ++s) {
            int k = s >> 2;
            int chunk = (s & 3) * 4 + kg;
            bf16x8 Bf = Bw[s];
            #pragma unroll
            for (int lt = 0; lt < 3; ++lt) {
                int arow = 16 * lt + lr + k;
                bf16x8 a = __builtin_bit_cast(bf16x8, hyS4[arow * 16 + ((arow & 7) ^ chunk)]);
                acc[lt] = __builtin_amdgcn_mfma_f32_16x16x32_bf16(a, Bf, acc[lt], 0, 0, 0);
            }
        }
        lds_sync();   // all hyS reads complete; global stores keep flowing

        float lsum = 0.f;
        float* yslab = yout + (size_t)b * YB + (size_t)t * YT + (size_t)co * 512;
        #pragma unroll
        for (int lt = 0; lt < 3; ++lt) {
            #pragma unroll
            for (int j = 0; j < 4; ++j) {
                float spring = tanh_fast(acc[lt][j]);
                float zn = hzR[lt][j] + DTc * (spring - omR[lt][j] * hyR[lt][j] - alR[lt][j] * hzR[lt][j]);
                float hn = hyR[lt][j] + DTc * zn;
                hzR[lt][j] = zn;
                hyR[lt][j] = hn;
            }
            bool valid = (lt == 0) ? (kg >= 2) : (lt == 2) ? (kg < 2) : true;
            if (valid) {
                *(f32x4*)(yslab + (l0 - 8 + 16 * lt + 4 * kg)) = hyR[lt];
                lsum += hyR[lt][0] + hyR[lt][1] + hyR[lt][2] + hyR[lt][3];
            }
            if (t < 49) {
                #pragma unroll
                for (int j = 0; j < 4; ++j) {
                    int rr = 16 * lt + 4 * kg + j + 1;
                    int sidx = rr * 128 + (((co >> 3) ^ (rr & 7)) << 3) + (co & 7);
                    hyS16[sidx] = f2bf(hyR[lt][j]);
                }
            }
        }
        lsum += __shfl_xor(lsum, 16);
        lsum += __shfl_xor(lsum, 32);
        if (kg == 0) part[(((size_t)b * 50 + t) * 128 + co) * 16 + tile] = lsum;

        if ((t & 7) == 7 && t < 49) {
            // ---- chunk boundary
            int par = (t >> 3) & 1;
            float* hb = hze + ((((size_t)par * 32 + b) * 16 + tile) * 128 + co) * 16;
            if (kg >= 2) *(f32x4*)(hb + (kg - 2) * 4) = hzR[0];   // rows 8..15  (left export)
            else         *(f32x4*)(hb + 8 + kg * 4)  = hzR[2];   // rows 32..39 (right export)
            __threadfence();
            __syncthreads();                 // full drain: y + hze visible
            if (tid == 0) grid_barrier(bar);
            __syncthreads();
            __threadfence();
            const float* ycur = yout + (size_t)b * YB + (size_t)t * YT;
            if (kg < 2) {    // refresh rows 0..7
                hyR[0] = *(const f32x4*)(ycur + (size_t)co * 512 + ((l0 - 8 + kg * 4) & 511));
                const float* hbl = hze + ((((size_t)par * 32 + b) * 16 + ((tile + 15) & 15)) * 128 + co) * 16;
                hzR[0] = *(const f32x4*)(hbl + 8 + kg * 4);
            } else {         // refresh rows 40..47
                hyR[2] = *(const f32x4*)(ycur + (size_t)co * 512 + ((l0 + 24 + kg * 4) & 511));
                const float* hbr = hze + ((((size_t)par * 32 + b) * 16 + ((tile + 1) & 15)) * 128 + co) * 16;
                hzR[2] = *(const f32x4*)(hbr + (kg - 2) * 4);
            }
            // refresh hyS halo rows 0..8 and 41..49
            for (int i = tid; i < 18 * 128; i += 512) {
                int hr = i >> 7, c = i & 127;
                int h = (hr < 9) ? hr : (32 + hr);
                int l = (l0 - 9 + h) & 511;
                float v = ycur[(size_t)c * 512 + l];
                int sidx = h * 128 + (((c >> 3) ^ (h & 7)) << 3) + (c & 7);
                hyS16[sidx] = f2bf(v);
            }
            __syncthreads();
        } else if (t < 49) {
            lds_sync();   // hyS writes visible for next step
        }
    }
}

// ==================== readout ====================
__global__ __launch_bounds__(256) void readout_k(
    const float* __restrict__ part, const float* __restrict__ fct,
    const float* __restrict__ rw1, const float* __restrict__ rb1,
    const float* __restrict__ rw2, const float* __restrict__ rb2,
    const float* __restrict__ rw3, const float* __restrict__ rb3,
    float* __restrict__ out)
{
    int b = blockIdx.x, tid = threadIdx.x;
    __shared__ float ybar[50 * 128];
    __shared__ float feat[26 * 128];
    __shared__ float h1[64];
    __shared__ float h2[32];
    for (int idx = tid; idx < 50 * 128; idx += 256) {
        const float* p = part + ((size_t)b * 6400 + idx) * 16;
        float s = 0.f;
        #pragma unroll
        for (int q = 0; q < 16; ++q) s += p[q];
        ybar[idx] = s * (1.f / 512.f);
    }
    __syncthreads();
    for (int idx = tid; idx < 26 * 128; idx += 256) {
        int k = idx >> 7, c = idx & 127;
        float s = 0.f;
        for (int t = 0; t < 50; ++t) s += fct[k * 50 + t] * ybar[t * 128 + c];
        feat[idx] = s;
    }
    __syncthreads();
    {
        int j = tid >> 2, q = tid & 3;
        float s = 0.f;
        const float* r = rw1 + (size_t)j * 3328 + q * 832;
        const float* f = feat + q * 832;
        for (int i = 0; i < 832; ++i) s += f[i] * r[i];
        s += __shfl_xor(s, 1);
        s += __shfl_xor(s, 2);
        if (q == 0) h1[j] = fmaxf(s + rb1[j], 0.f);
    }
    __syncthreads();
    if (tid < 32) {
        float s = 0.f;
        for (int i = 0; i < 64; ++i) s += h1[i] * rw2[tid * 64 + i];
        h2[tid] = fmaxf(s + rb2[tid], 0.f);
    }
    __syncthreads();
    if (tid == 0) {
        float s = 0.f;
        for (int i = 0; i < 32; ++i) s += h2[i] * rw3[i];
        out[b] = s + rb3[0];
    }
}

// ==================== launch ====================
extern "C" void kernel_launch(void* const* d_in, const int* in_sizes, int n_in,
                              void* d_out, int out_size, void* d_ws, size_t ws_size,
                              hipStream_t stream)
{
    const float* x   = (const float*)d_in[0];
    const float* ow1 = (const float*)d_in[1];  const float* ob1 = (const float*)d_in[2];
    const float* ow2 = (const float*)d_in[3];  const float* ob2 = (const float*)d_in[4];
    const float* ow3 = (const float*)d_in[5];  const float* ob3 = (const float*)d_in[6];
    const float* aw1 = (const float*)d_in[7];  const float* ab1 = (const float*)d_in[8];
    const float* aw2 = (const float*)d_in[9];  const float* ab2 = (const float*)d_in[10];
    const float* aw3 = (const float*)d_in[11]; const float* ab3 = (const float*)d_in[12];
    const float* hw1 = (const float*)d_in[13]; const float* hb1 = (const float*)d_in[14];
    const float* hw2 = (const float*)d_in[15]; const float* hb2 = (const float*)d_in[16];
    const float* hw3 = (const float*)d_in[17]; const float* hb3 = (const float*)d_in[18];
    const float* hw4 = (const float*)d_in[19]; const float* hb4 = (const float*)d_in[20];
    const float* wy  = (const float*)d_in[21];
    const float* fct = (const float*)d_in[22];
    const float* rw1 = (const float*)d_in[23]; const float* rb1 = (const float*)d_in[24];
    const float* rw2 = (const float*)d_in[25]; const float* rb2 = (const float*)d_in[26];
    const float* rw3 = (const float*)d_in[27]; const float* rb3 = (const float*)d_in[28];

    float* out  = (float*)d_out;
    float* yout = out + 32;                       // y_seq region
    float* ws   = (float*)d_ws;

    // ws layout (float offsets)
    float* OMEGA = ws;                            // 2,097,152
    float* ALPHA = ws + 2097152;                  // 2,097,152
    float* WT    = ws + 4194304;                  // 353,280
    float* PART  = ws + 4547584;                  // 3,276,800 (32*50*128*16)
    float* HZE   = ws + 7824384;                  // 2,097,152 (2*32*16*128*16)
    unsigned short* W2 = (unsigned short*)(ws + 9921536);  // 49,152 u16
    unsigned* BAR = (unsigned*)(ws + 9946112);    // 2 u32
    // total ~39.8 MB

    // encoder scratch slabs inside y region (overwritten at t >= slab idx, after last use)
    float* To1 = yout + 44 * YT;
    float* Ta1 = yout + 45 * YT;
    float* Th1 = yout + 46 * YT;
    float* To2 = yout + 47 * YT;
    float* Ta2 = yout + 43 * YT;
    float* Th2 = yout + 49 * YT;
    float* Th3 = yout + 42 * YT;
    float* HY0 = yout + 48 * YT;

    float* OW1T = WT + 0;      float* AW1T = WT + 3072;   float* HW1T = WT + 6144;
    float* OW2T = WT + 9216;   float* OW3T = WT + 58368;
    float* AW2T = WT + 107520; float* AW3T = WT + 156672;
    float* HW2T = WT + 205824; float* HW3T = WT + 254976; float* HW4T = WT + 304128;

    WSrc wsrc;
    wsrc.p[0] = ow1; wsrc.p[1] = aw1; wsrc.p[2] = hw1;
    wsrc.p[3] = ow2; wsrc.p[4] = ow3; wsrc.p[5] = aw2; wsrc.p[6] = aw3;
    wsrc.p[7] = hw2; wsrc.p[8] = hw3; wsrc.p[9] = hw4; wsrc.p[10] = wy;
    wprep_all_k<<<1572, 256, 0, stream>>>(wsrc, WT, W2);

    Jobs3 d1 = {{ {x, To1, OW1T, ob1, 4096, YB, 1},
                  {x, Ta1, AW1T, ab1, 4096, YB, 1},
                  {x, Th1, HW1T, hb1, 4096, YB, 1} }};
    conv8x3_k<<<dim3(8, 3, 32), 256, 0, stream>>>(d1);

    Jobs3 d2 = {{ {To1, To2, OW2T, ob2, YB, YB, 1},
                  {Ta1, Ta2, AW2T, ab2, YB, YB, 1},
                  {Th1, Th2, HW2T, hb2, YB, YB, 1} }};
    conv128x3_k<<<dim3(8, 6, 32), 256, 0, stream>>>(d2);

    Jobs3 d3 = {{ {To2, OMEGA, OW3T, ob3, YB, 65536, 1},
                  {Ta2, ALPHA, AW3T, ab3, YB, 65536, 1},
                  {Th2, Th3, HW3T, hb3, YB, YB, 1} }};
    conv128x3_k<<<dim3(8, 6, 32), 256, 0, stream>>>(d3);

    Jobs3 d4 = {{ {Th3, HY0, HW4T, hb4, YB, YB, 2},
                  {Th3, HY0, HW4T, hb4, YB, YB, 2},
                  {Th3, HY0, HW4T, hb4, YB, YB, 2} }};
    conv128x3_k<<<dim3(8, 2, 32), 256, 0, stream>>>(d4);

    zero_bar_k<<<1, 64, 0, stream>>>(BAR);
    recur_fused_k<<<dim3(16, 32), 512, 0, stream>>>(HY0, OMEGA, ALPHA, W2,
                                                    yout, HZE, PART, BAR);

    readout_k<<<32, 256, 0, stream>>>(PART, fct, rw1, rb1, rw2, rb2, rw3, rb3, out);
}

// Round 5
// 1205.801 us; speedup vs baseline: 1.8753x; 1.8753x over previous
//
#include <hip/hip_runtime.h>
#include <math.h>

#define YB (50*128*512)   // y_seq batch stride (floats)
#define YT (128*512)      // y_seq time stride
#define DTc 0.5f
#define NBLK 256

typedef __attribute__((ext_vector_type(8))) short bf16x8;
typedef __attribute__((ext_vector_type(4))) float f32x4;

__device__ __forceinline__ unsigned short f2bf(float f) {
    unsigned int u = __builtin_bit_cast(unsigned int, f);
    u += 0x7fffu + ((u >> 16) & 1u);          // RNE
    return (unsigned short)(u >> 16);
}

__device__ __forceinline__ float tanh_fast(float x) {
    float ax = fabsf(x);
    float e  = __expf(-2.f * ax);
    float r  = (1.f - e) * __builtin_amdgcn_rcpf(1.f + e);
    return __builtin_copysignf(r, x);
}

// raw block barrier: waits LDS ops only, lets global stores stay in flight
__device__ __forceinline__ void lds_sync() {
    asm volatile("s_waitcnt lgkmcnt(0)" ::: "memory");
    __builtin_amdgcn_sched_barrier(0);
    __builtin_amdgcn_s_barrier();
    __builtin_amdgcn_sched_barrier(0);
}

// ==================== fused weight prep ====================
struct WSrc { const float* p[11]; };  // ow1,aw1,hw1, ow2,ow3,aw2,aw3,hw2,hw3,hw4, wy
__global__ void wprep_all_k(WSrc s, float* __restrict__ wt, unsigned short* __restrict__ w2) {
    int idx = blockIdx.x * 256 + threadIdx.x;
    if (idx < 9216) {
        int wsel = idx / 3072, r = idx % 3072;
        int row = r >> 7, co = r & 127;
        int ci = row / 3, k = row - ci * 3;
        wt[idx] = s.p[wsel][(co * 8 + ci) * 3 + k];
    } else if (idx < 353280) {
        int r = idx - 9216;
        int wsel = 3 + r / 49152, q = r % 49152;
        int row = q >> 7, co = q & 127;
        int ci = row / 3, k = row - ci * 3;
        wt[idx] = s.p[wsel][(co * 128 + ci) * 3 + k];
    } else if (idx < 402432) {
        int q = idx - 353280;
        int co = q / 384, kap = q - co * 384;
        int k = kap >> 7;
        int ci = ((kap >> 5) & 3) * 32 + (kap & 31);
        w2[q] = f2bf(s.p[10][(co * 128 + ci) * 3 + k]);
    }
}

// ==================== encoder convs (fp32, job-batched) ====================
struct Job { const float* src; float* dst; const float* wt; const float* bias; int sbs, dbs, act; };
struct Jobs3 { Job j[3]; };

__global__ __launch_bounds__(256) void conv8x3_k(Jobs3 js) {
    int jb = blockIdx.y % 3;
    Job jo = js.j[jb];
    int b = blockIdx.z, tile = blockIdx.x, tid = threadIdx.x;
    int l0 = tile * 64;
    int tl4 = (tid & 15) * 4;
    int co0 = (tid >> 4) * 8;
    __shared__ float xs[8 * 68];
    __shared__ float wsh[24 * 128];
    const float* sb = jo.src + (size_t)b * jo.sbs;
    for (int idx = tid; idx < 8 * 66; idx += 256) {
        int ci = idx / 66, ll = idx - ci * 66;
        int gl = l0 - 1 + ll;
        xs[ci * 68 + ll] = (gl >= 0 && gl < 512) ? sb[ci * 512 + gl] : 0.f;
    }
    for (int idx = tid; idx < 24 * 128; idx += 256) wsh[idx] = jo.wt[idx];
    __syncthreads();
    float acc[8][4] = {};
    #pragma unroll
    for (int ci = 0; ci < 8; ++ci) {
        float x6[6];
        #pragma unroll
        for (int j = 0; j < 6; ++j) x6[j] = xs[ci * 68 + tl4 + j];
        #pragma unroll
        for (int k = 0; k < 3; ++k) {
            float w8[8];
            #pragma unroll
            for (int i = 0; i < 8; ++i) w8[i] = wsh[(ci * 3 + k) * 128 + co0 + i];
            #pragma unroll
            for (int i = 0; i < 8; ++i)
                #pragma unroll
                for (int j = 0; j < 4; ++j)
                    acc[i][j] = fmaf(w8[i], x6[k + j], acc[i][j]);
        }
    }
    #pragma unroll
    for (int i = 0; i < 8; ++i) {
        int co = co0 + i;
        float bv = jo.bias[co];
        float4 o;
        o.x = fmaxf(acc[i][0] + bv, 0.f);
        o.y = fmaxf(acc[i][1] + bv, 0.f);
        o.z = fmaxf(acc[i][2] + bv, 0.f);
        o.w = fmaxf(acc[i][3] + bv, 0.f);
        *(float4*)(jo.dst + (size_t)b * jo.dbs + (size_t)co * 512 + l0 + tl4) = o;
    }
}

__global__ __launch_bounds__(256) void conv128x3_k(Jobs3 js) {
    int jb = blockIdx.y >> 1, cb = blockIdx.y & 1;
    Job jo = js.j[jb];
    int b = blockIdx.z, tile = blockIdx.x, tid = threadIdx.x;
    int l0 = tile * 64;
    int tl4 = (tid & 15) * 4;
    int col = (tid >> 4) * 4;
    __shared__ float xs[32 * 68];
    __shared__ float wsh[96 * 64];
    const float* sb = jo.src + (size_t)b * jo.sbs;
    float acc[4][4] = {};
    for (int chunk = 0; chunk < 4; ++chunk) {
        for (int idx = tid; idx < 32 * 66; idx += 256) {
            int ci = idx / 66, ll = idx - ci * 66;
            int gl = l0 - 1 + ll;
            xs[ci * 68 + ll] = (gl >= 0 && gl < 512) ? sb[(chunk * 32 + ci) * 512 + gl] : 0.f;
        }
        for (int idx = tid; idx < 96 * 16; idx += 256) {
            int row = idx >> 4, j = (idx & 15) * 4;
            *(float4*)(wsh + row * 64 + j) =
                *(const float4*)(jo.wt + (size_t)(chunk * 96 + row) * 128 + cb * 64 + j);
        }
        __syncthreads();
        #pragma unroll 4
        for (int ci = 0; ci < 32; ++ci) {
            float x6[6];
            #pragma unroll
            for (int j = 0; j < 6; ++j) x6[j] = xs[ci * 68 + tl4 + j];
            #pragma unroll
            for (int k = 0; k < 3; ++k) {
                float w4[4];
                #pragma unroll
                for (int i = 0; i < 4; ++i) w4[i] = wsh[(ci * 3 + k) * 64 + col + i];
                #pragma unroll
                for (int i = 0; i < 4; ++i)
                    #pragma unroll
                    for (int j = 0; j < 4; ++j)
                        acc[i][j] = fmaf(w4[i], x6[k + j], acc[i][j]);
            }
        }
        __syncthreads();
    }
    #pragma unroll
    for (int i = 0; i < 4; ++i) {
        int co = cb * 64 + col + i;
        float bv = jo.bias[co];
        float v[4];
        #pragma unroll
        for (int j = 0; j < 4; ++j) {
            float tv = acc[i][j] + bv;
            if (jo.act == 1) tv = fmaxf(tv, 0.f);
            else if (jo.act == 2) tv = tanhf(tv);
            v[j] = tv;
        }
        *(float4*)(jo.dst + (size_t)b * jo.dbs + (size_t)co * 512 + l0 + tl4) = *(float4*)v;
    }
}

// ==================== grid barrier ====================
__global__ void zero_bar_k(unsigned* bar) { if (threadIdx.x < 2) bar[threadIdx.x] = 0u; }

__device__ __forceinline__ void grid_barrier(unsigned* bar) {
    unsigned g = __hip_atomic_load(bar + 1, __ATOMIC_ACQUIRE, __HIP_MEMORY_SCOPE_AGENT);
    unsigned a = __hip_atomic_fetch_add(bar, 1u, __ATOMIC_ACQ_REL, __HIP_MEMORY_SCOPE_AGENT);
    if (a == NBLK - 1) {
        __hip_atomic_store(bar, 0u, __ATOMIC_RELAXED, __HIP_MEMORY_SCOPE_AGENT);
        __hip_atomic_fetch_add(bar + 1, 1u, __ATOMIC_ACQ_REL, __HIP_MEMORY_SCOPE_AGENT);
    } else {
        while (__hip_atomic_load(bar + 1, __ATOMIC_ACQUIRE, __HIP_MEMORY_SCOPE_AGENT) == g)
            __builtin_amdgcn_s_sleep(8);
    }
}

// ==================== persistent recurrence ====================
// r3 geometry: 256 blocks (8 l-tiles x 32 b), 512 threads, 1 block/CU.
// Block state: W=80 rows (l0-8 .. l0+71) x 128 co; 5 lt frags.
// Per-step barriers are lgkmcnt-only (lds_sync): y stores pipeline across
// steps; vmcnt drains only at the 6 chunk boundaries (threadfence).
__global__ __launch_bounds__(512, 2) void recur_fused_k(
    const float* __restrict__ hy0,     // [b][co][l], b-stride YB
    const float* __restrict__ omega,   // [b][co][l], b-stride 65536
    const float* __restrict__ alpha,
    const unsigned short* __restrict__ w2,
    float* __restrict__ yout,          // slab 0 base
    float* __restrict__ hze,           // [2][32][8][128][16] f32
    float* __restrict__ part,          // [32][50][128][8]
    unsigned* __restrict__ bar)
{
    int tile = blockIdx.x, b = blockIdx.y;
    int tid = threadIdx.x, lane = tid & 63, wid = tid >> 6;
    int lr = lane & 15, kg = lane >> 4;
    int co = wid * 16 + lr;
    int l0 = tile * 64;

    __shared__ uint4 hyS4[82 * 16];            // [row][chunk ^ (row&7)]
    __shared__ float temp[128 * 92];           // staging, [co][92]
    unsigned short* hyS16 = (unsigned short*)hyS4;

    // ---- B weights (once)
    bf16x8 Bw[12];
    {
        const bf16x8* wp = (const bf16x8*)(w2 + (size_t)co * 384);
        #pragma unroll
        for (int s = 0; s < 12; ++s) Bw[s] = wp[s * 4 + kg];
    }

    // ---- stage+load initial state
    f32x4 hyR[5], hzR[5], omR[5], alR[5];

    // hy
    for (int i = tid; i < 128 * 22; i += 512) {
        int c = i / 22, p4 = (i - c * 22) * 4;
        int l = (l0 - 12 + p4) & 511;
        *(f32x4*)(temp + c * 92 + p4) = *(const f32x4*)(hy0 + (size_t)b * YB + (size_t)c * 512 + l);
    }
    __syncthreads();
    #pragma unroll
    for (int lt = 0; lt < 5; ++lt)
        hyR[lt] = *(const f32x4*)(temp + co * 92 + 16 * lt + kg * 4 + 4);
    for (int i = tid; i < 82 * 16; i += 512) {
        int h = i >> 4, c8 = i & 15;
        unsigned short pk[8];
        #pragma unroll
        for (int q = 0; q < 8; ++q) pk[q] = f2bf(temp[(c8 * 8 + q) * 92 + (h + 3)]);
        hyS4[h * 16 + (c8 ^ (h & 7))] = *(uint4*)pk;
    }
    __syncthreads();
    // omega
    for (int i = tid; i < 128 * 22; i += 512) {
        int c = i / 22, p4 = (i - c * 22) * 4;
        int l = (l0 - 12 + p4) & 511;
        *(f32x4*)(temp + c * 92 + p4) = *(const f32x4*)(omega + (size_t)b * 65536 + (size_t)c * 512 + l);
    }
    __syncthreads();
    #pragma unroll
    for (int lt = 0; lt < 5; ++lt)
        omR[lt] = *(const f32x4*)(temp + co * 92 + 16 * lt + kg * 4 + 4);
    __syncthreads();
    // alpha
    for (int i = tid; i < 128 * 22; i += 512) {
        int c = i / 22, p4 = (i - c * 22) * 4;
        int l = (l0 - 12 + p4) & 511;
        *(f32x4*)(temp + c * 92 + p4) = *(const f32x4*)(alpha + (size_t)b * 65536 + (size_t)c * 512 + l);
    }
    __syncthreads();
    #pragma unroll
    for (int lt = 0; lt < 5; ++lt)
        alR[lt] = *(const f32x4*)(temp + co * 92 + 16 * lt + kg * 4 + 4);
    #pragma unroll
    for (int lt = 0; lt < 5; ++lt) hzR[lt] = (f32x4){0.f, 0.f, 0.f, 0.f};
    __syncthreads();

    // ---- main loop
    for (int t = 0; t < 50; ++t) {
        // MFMA: conv over hyS
        f32x4 acc[5];
        #pragma unroll
        for (int lt = 0; lt < 5; ++lt) acc[lt] = (f32x4){0.f, 0.f, 0.f, 0.f};
        #pragma unroll
        for (int s = 0; s < 12; ++s) {
            int k = s >> 2;
            int arow = lr + k;
            int aidx = arow * 16 + ((arow & 7) ^ ((s & 3) * 4 + kg));
            bf16x8 Bf = Bw[s];
            #pragma unroll
            for (int lt = 0; lt < 5; ++lt) {
                bf16x8 a = __builtin_bit_cast(bf16x8, hyS4[aidx + lt * 256]);
                acc[lt] = __builtin_amdgcn_mfma_f32_16x16x32_bf16(a, Bf, acc[lt], 0, 0, 0);
            }
        }
        lds_sync();   // all hyS reads complete; global stores keep flowing

        // pointwise update + y write + hyS rewrite
        float lsum = 0.f;
        float* yslab = yout + (size_t)b * YB + (size_t)t * YT + (size_t)co * 512;
        #pragma unroll
        for (int lt = 0; lt < 5; ++lt) {
            #pragma unroll
            for (int j = 0; j < 4; ++j) {
                float spring = tanh_fast(acc[lt][j]);
                float zn = hzR[lt][j] + DTc * (spring - omR[lt][j] * hyR[lt][j] - alR[lt][j] * hzR[lt][j]);
                float hn = hyR[lt][j] + DTc * zn;
                hzR[lt][j] = zn;
                hyR[lt][j] = hn;
            }
            bool valid = (lt > 0 || kg >= 2) && (lt < 4 || kg < 2);
            if (valid) {
                int r0 = lt * 16 + kg * 4;
                *(f32x4*)(yslab + (l0 - 8 + r0)) = hyR[lt];
                lsum += hyR[lt][0] + hyR[lt][1] + hyR[lt][2] + hyR[lt][3];
            }
            if (t < 49) {
                #pragma unroll
                for (int j = 0; j < 4; ++j) {
                    int rr = lt * 16 + kg * 4 + j + 1;   // hyS row
                    int sidx = rr * 128 + (((co >> 3) ^ (rr & 7)) << 3) + (co & 7);
                    hyS16[sidx] = f2bf(hyR[lt][j]);
                }
            }
        }
        lsum += __shfl_xor(lsum, 16);
        lsum += __shfl_xor(lsum, 32);
        if (kg == 0) part[(((size_t)b * 50 + t) * 128 + co) * 8 + tile] = lsum;

        if ((t & 7) == 7 && t < 49) {
            // ---- chunk boundary: halo exchange (full drain here only)
            int par = (t >> 3) & 1;
            float* hb = hze + ((((size_t)par * 32 + b) * 8 + tile) * 128 + co) * 16;
            if (kg >= 2) *(f32x4*)(hb + (kg - 2) * 4) = hzR[0];  // center rows 8..15 -> e 0..7
            else         *(f32x4*)(hb + 8 + kg * 4)  = hzR[4];  // center rows 64..71 -> e 8..15
            __threadfence();
            __syncthreads();
            if (tid == 0) grid_barrier(bar);
            __syncthreads();
            __threadfence();
            // refresh halo regs
            const float* ycur = yout + (size_t)b * YB + (size_t)t * YT;
            if (kg < 2) {        // state rows 0..7 (lt0)
                int l = (l0 - 8 + kg * 4) & 511;
                hyR[0] = *(const f32x4*)(ycur + (size_t)co * 512 + l);
                const float* hbl = hze + ((((size_t)par * 32 + b) * 8 + ((tile + 7) & 7)) * 128 + co) * 16;
                hzR[0] = *(const f32x4*)(hbl + 8 + kg * 4);
            } else {             // state rows 72..79 (lt4)
                int l = (l0 + 64 + (kg - 2) * 4) & 511;
                hyR[4] = *(const f32x4*)(ycur + (size_t)co * 512 + l);
                const float* hbr = hze + ((((size_t)par * 32 + b) * 8 + ((tile + 1) & 7)) * 128 + co) * 16;
                hzR[4] = *(const f32x4*)(hbr + (kg - 2) * 4);
            }
            // refresh hyS halo rows 0..8, 73..81
            for (int i = tid; i < 18 * 128; i += 512) {
                int hr = i >> 7, c2 = i & 127;
                int h = (hr < 9) ? hr : (64 + hr);
                int l = (l0 - 9 + h) & 511;
                float v = ycur[(size_t)c2 * 512 + l];
                int sidx = h * 128 + (((c2 >> 3) ^ (h & 7)) << 3) + (c2 & 7);
                hyS16[sidx] = f2bf(v);
            }
            __syncthreads();
        } else if (t < 49) {
            lds_sync();   // hyS writes visible for next step
        }
    }
}

// ==================== readout ====================
__global__ __launch_bounds__(256) void readout_k(
    const float* __restrict__ part, const float* __restrict__ fct,
    const float* __restrict__ rw1, const float* __restrict__ rb1,
    const float* __restrict__ rw2, const float* __restrict__ rb2,
    const float* __restrict__ rw3, const float* __restrict__ rb3,
    float* __restrict__ out)
{
    int b = blockIdx.x, tid = threadIdx.x;
    __shared__ float ybar[50 * 128];
    __shared__ float feat[26 * 128];
    __shared__ float h1[64];
    __shared__ float h2[32];
    for (int idx = tid; idx < 50 * 128; idx += 256) {
        const float* p = part + ((size_t)b * 6400 + idx) * 8;
        float s = 0.f;
        #pragma unroll
        for (int q = 0; q < 8; ++q) s += p[q];
        ybar[idx] = s * (1.f / 512.f);
    }
    __syncthreads();
    for (int idx = tid; idx < 26 * 128; idx += 256) {
        int k = idx >> 7, c = idx & 127;
        float s = 0.f;
        for (int t = 0; t < 50; ++t) s += fct[k * 50 + t] * ybar[t * 128 + c];
        feat[idx] = s;
    }
    __syncthreads();
    {
        int j = tid >> 2, q = tid & 3;
        float s = 0.f;
        const float* r = rw1 + (size_t)j * 3328 + q * 832;
        const float* f = feat + q * 832;
        for (int i = 0; i < 832; ++i) s += f[i] * r[i];
        s += __shfl_xor(s, 1);
        s += __shfl_xor(s, 2);
        if (q == 0) h1[j] = fmaxf(s + rb1[j], 0.f);
    }
    __syncthreads();
    if (tid < 32) {
        float s = 0.f;
        for (int i = 0; i < 64; ++i) s += h1[i] * rw2[tid * 64 + i];
        h2[tid] = fmaxf(s + rb2[tid], 0.f);
    }
    __syncthreads();
    if (tid == 0) {
        float s = 0.f;
        for (int i = 0; i < 32; ++i) s += h2[i] * rw3[i];
        out[b] = s + rb3[0];
    }
}

// ==================== launch ====================
extern "C" void kernel_launch(void* const* d_in, const int* in_sizes, int n_in,
                              void* d_out, int out_size, void* d_ws, size_t ws_size,
                              hipStream_t stream)
{
    const float* x   = (const float*)d_in[0];
    const float* ow1 = (const float*)d_in[1];  const float* ob1 = (const float*)d_in[2];
    const float* ow2 = (const float*)d_in[3];  const float* ob2 = (const float*)d_in[4];
    const float* ow3 = (const float*)d_in[5];  const float* ob3 = (const float*)d_in[6];
    const float* aw1 = (const float*)d_in[7];  const float* ab1 = (const float*)d_in[8];
    const float* aw2 = (const float*)d_in[9];  const float* ab2 = (const float*)d_in[10];
    const float* aw3 = (const float*)d_in[11]; const float* ab3 = (const float*)d_in[12];
    const float* hw1 = (const float*)d_in[13]; const float* hb1 = (const float*)d_in[14];
    const float* hw2 = (const float*)d_in[15]; const float* hb2 = (const float*)d_in[16];
    const float* hw3 = (const float*)d_in[17]; const float* hb3 = (const float*)d_in[18];
    const float* hw4 = (const float*)d_in[19]; const float* hb4 = (const float*)d_in[20];
    const float* wy  = (const float*)d_in[21];
    const float* fct = (const float*)d_in[22];
    const float* rw1 = (const float*)d_in[23]; const float* rb1 = (const float*)d_in[24];
    const float* rw2 = (const float*)d_in[25]; const float* rb2 = (const float*)d_in[26];
    const float* rw3 = (const float*)d_in[27]; const float* rb3 = (const float*)d_in[28];

    float* out  = (float*)d_out;
    float* yout = out + 32;                       // y_seq region
    float* ws   = (float*)d_ws;

    // ws layout (float offsets)
    float* OMEGA = ws;                            // 2,097,152
    float* ALPHA = ws + 2097152;                  // 2,097,152
    float* WT    = ws + 4194304;                  // 353,280
    float* PART  = ws + 4547584;                  // 1,638,400
    float* HZE   = ws + 6185984;                  // 1,048,576
    unsigned short* W2 = (unsigned short*)(ws + 7234560);  // 49,152 u16
    unsigned* BAR = (unsigned*)(ws + 7259136);    // 2 u32
    // total ~29 MB

    // encoder scratch slabs inside y region (overwritten at t >= slab idx, after last use)
    float* To1 = yout + 44 * YT;
    float* Ta1 = yout + 45 * YT;
    float* Th1 = yout + 46 * YT;
    float* To2 = yout + 47 * YT;
    float* Ta2 = yout + 43 * YT;
    float* Th2 = yout + 49 * YT;
    float* Th3 = yout + 42 * YT;
    float* HY0 = yout + 48 * YT;

    float* OW1T = WT + 0;      float* AW1T = WT + 3072;   float* HW1T = WT + 6144;
    float* OW2T = WT + 9216;   float* OW3T = WT + 58368;
    float* AW2T = WT + 107520; float* AW3T = WT + 156672;
    float* HW2T = WT + 205824; float* HW3T = WT + 254976; float* HW4T = WT + 304128;

    WSrc wsrc;
    wsrc.p[0] = ow1; wsrc.p[1] = aw1; wsrc.p[2] = hw1;
    wsrc.p[3] = ow2; wsrc.p[4] = ow3; wsrc.p[5] = aw2; wsrc.p[6] = aw3;
    wsrc.p[7] = hw2; wsrc.p[8] = hw3; wsrc.p[9] = hw4; wsrc.p[10] = wy;
    wprep_all_k<<<1572, 256, 0, stream>>>(wsrc, WT, W2);

    Jobs3 d1 = {{ {x, To1, OW1T, ob1, 4096, YB, 1},
                  {x, Ta1, AW1T, ab1, 4096, YB, 1},
                  {x, Th1, HW1T, hb1, 4096, YB, 1} }};
    conv8x3_k<<<dim3(8, 3, 32), 256, 0, stream>>>(d1);

    Jobs3 d2 = {{ {To1, To2, OW2T, ob2, YB, YB, 1},
                  {Ta1, Ta2, AW2T, ab2, YB, YB, 1},
                  {Th1, Th2, HW2T, hb2, YB, YB, 1} }};
    conv128x3_k<<<dim3(8, 6, 32), 256, 0, stream>>>(d2);

    Jobs3 d3 = {{ {To2, OMEGA, OW3T, ob3, YB, 65536, 1},
                  {Ta2, ALPHA, AW3T, ab3, YB, 65536, 1},
                  {Th2, Th3, HW3T, hb3, YB, YB, 1} }};
    conv128x3_k<<<dim3(8, 6, 32), 256, 0, stream>>>(d3);

    Jobs3 d4 = {{ {Th3, HY0, HW4T, hb4, YB, YB, 2},
                  {Th3, HY0, HW4T, hb4, YB, YB, 2},
                  {Th3, HY0, HW4T, hb4, YB, YB, 2} }};
    conv128x3_k<<<dim3(8, 2, 32), 256, 0, stream>>>(d4);

    zero_bar_k<<<1, 64, 0, stream>>>(BAR);
    recur_fused_k<<<dim3(8, 32), 512, 0, stream>>>(HY0, OMEGA, ALPHA, W2,
                                                   yout, HZE, PART, BAR);

    readout_k<<<32, 256, 0, stream>>>(PART, fct, rw1, rb1, rw2, rb2, rw3, rb3, out);
}

// Round 7
// 1169.713 us; speedup vs baseline: 1.9332x; 1.0309x over previous
//
#include <hip/hip_runtime.h>
#include <math.h>

#define YB (50*128*512)   // y_seq batch stride (floats)
#define YT (128*512)      // y_seq time stride
#define DTc 0.5f
#define NBLK 256
#define TSTR 100          // temp row stride in floats (400B: 16B-aligned, odd/4 banks)

typedef __attribute__((ext_vector_type(8))) short bf16x8;
typedef __attribute__((ext_vector_type(4))) float f32x4;

__device__ __forceinline__ unsigned short f2bf(float f) {
    unsigned int u = __builtin_bit_cast(unsigned int, f);
    u += 0x7fffu + ((u >> 16) & 1u);          // RNE
    return (unsigned short)(u >> 16);
}

__device__ __forceinline__ float tanh_fast(float x) {
    float ax = fabsf(x);
    float e  = __expf(-2.f * ax);
    float r  = (1.f - e) * __builtin_amdgcn_rcpf(1.f + e);
    return __builtin_copysignf(r, x);
}

// raw block barrier: waits LDS ops only, lets global stores stay in flight
__device__ __forceinline__ void lds_sync() {
    asm volatile("s_waitcnt lgkmcnt(0)" ::: "memory");
    __builtin_amdgcn_sched_barrier(0);
    __builtin_amdgcn_s_barrier();
    __builtin_amdgcn_sched_barrier(0);
}

// ==================== fused weight prep ====================
struct WSrc { const float* p[11]; };  // ow1,aw1,hw1, ow2,ow3,aw2,aw3,hw2,hw3,hw4, wy
__global__ void wprep_all_k(WSrc s, float* __restrict__ wt, unsigned short* __restrict__ w2) {
    int idx = blockIdx.x * 256 + threadIdx.x;
    if (idx < 9216) {
        int wsel = idx / 3072, r = idx % 3072;
        int row = r >> 7, co = r & 127;
        int ci = row / 3, k = row - ci * 3;
        wt[idx] = s.p[wsel][(co * 8 + ci) * 3 + k];
    } else if (idx < 353280) {
        int r = idx - 9216;
        int wsel = 3 + r / 49152, q = r % 49152;
        int row = q >> 7, co = q & 127;
        int ci = row / 3, k = row - ci * 3;
        wt[idx] = s.p[wsel][(co * 128 + ci) * 3 + k];
    } else if (idx < 402432) {
        int q = idx - 353280;
        int co = q / 384, kap = q - co * 384;
        int k = kap >> 7;
        int ci = ((kap >> 5) & 3) * 32 + (kap & 31);
        w2[q] = f2bf(s.p[10][(co * 128 + ci) * 3 + k]);
    }
}

// ==================== encoder convs (fp32, job-batched) ====================
struct Job { const float* src; float* dst; const float* wt; const float* bias; int sbs, dbs, act; };
struct Jobs3 { Job j[3]; };

__global__ __launch_bounds__(256) void conv8x3_k(Jobs3 js) {
    int jb = blockIdx.y % 3;
    Job jo = js.j[jb];
    int b = blockIdx.z, tile = blockIdx.x, tid = threadIdx.x;
    int l0 = tile * 64;
    int tl4 = (tid & 15) * 4;
    int co0 = (tid >> 4) * 8;
    __shared__ float xs[8 * 68];
    __shared__ float wsh[24 * 128];
    const float* sb = jo.src + (size_t)b * jo.sbs;
    for (int idx = tid; idx < 8 * 66; idx += 256) {
        int ci = idx / 66, ll = idx - ci * 66;
        int gl = l0 - 1 + ll;
        xs[ci * 68 + ll] = (gl >= 0 && gl < 512) ? sb[ci * 512 + gl] : 0.f;
    }
    for (int idx = tid; idx < 24 * 128; idx += 256) wsh[idx] = jo.wt[idx];
    __syncthreads();
    float acc[8][4] = {};
    #pragma unroll
    for (int ci = 0; ci < 8; ++ci) {
        float x6[6];
        #pragma unroll
        for (int j = 0; j < 6; ++j) x6[j] = xs[ci * 68 + tl4 + j];
        #pragma unroll
        for (int k = 0; k < 3; ++k) {
            float w8[8];
            #pragma unroll
            for (int i = 0; i < 8; ++i) w8[i] = wsh[(ci * 3 + k) * 128 + co0 + i];
            #pragma unroll
            for (int i = 0; i < 8; ++i)
                #pragma unroll
                for (int j = 0; j < 4; ++j)
                    acc[i][j] = fmaf(w8[i], x6[k + j], acc[i][j]);
        }
    }
    #pragma unroll
    for (int i = 0; i < 8; ++i) {
        int co = co0 + i;
        float bv = jo.bias[co];
        float4 o;
        o.x = fmaxf(acc[i][0] + bv, 0.f);
        o.y = fmaxf(acc[i][1] + bv, 0.f);
        o.z = fmaxf(acc[i][2] + bv, 0.f);
        o.w = fmaxf(acc[i][3] + bv, 0.f);
        *(float4*)(jo.dst + (size_t)b * jo.dbs + (size_t)co * 512 + l0 + tl4) = o;
    }
}

__global__ __launch_bounds__(256) void conv128x3_k(Jobs3 js) {
    int jb = blockIdx.y >> 1, cb = blockIdx.y & 1;
    Job jo = js.j[jb];
    int b = blockIdx.z, tile = blockIdx.x, tid = threadIdx.x;
    int l0 = tile * 64;
    int tl4 = (tid & 15) * 4;
    int col = (tid >> 4) * 4;
    __shared__ float xs[32 * 68];
    __shared__ float wsh[96 * 64];
    const float* sb = jo.src + (size_t)b * jo.sbs;
    float acc[4][4] = {};
    for (int chunk = 0; chunk < 4; ++chunk) {
        for (int idx = tid; idx < 32 * 66; idx += 256) {
            int ci = idx / 66, ll = idx - ci * 66;
            int gl = l0 - 1 + ll;
            xs[ci * 68 + ll] = (gl >= 0 && gl < 512) ? sb[(chunk * 32 + ci) * 512 + gl] : 0.f;
        }
        for (int idx = tid; idx < 96 * 16; idx += 256) {
            int row = idx >> 4, j = (idx & 15) * 4;
            *(float4*)(wsh + row * 64 + j) =
                *(const float4*)(jo.wt + (size_t)(chunk * 96 + row) * 128 + cb * 64 + j);
        }
        __syncthreads();
        #pragma unroll 4
        for (int ci = 0; ci < 32; ++ci) {
            float x6[6];
            #pragma unroll
            for (int j = 0; j < 6; ++j) x6[j] = xs[ci * 68 + tl4 + j];
            #pragma unroll
            for (int k = 0; k < 3; ++k) {
                float w4[4];
                #pragma unroll
                for (int i = 0; i < 4; ++i) w4[i] = wsh[(ci * 3 + k) * 64 + col + i];
                #pragma unroll
                for (int i = 0; i < 4; ++i)
                    #pragma unroll
                    for (int j = 0; j < 4; ++j)
                        acc[i][j] = fmaf(w4[i], x6[k + j], acc[i][j]);
            }
        }
        __syncthreads();
    }
    #pragma unroll
    for (int i = 0; i < 4; ++i) {
        int co = cb * 64 + col + i;
        float bv = jo.bias[co];
        float v[4];
        #pragma unroll
        for (int j = 0; j < 4; ++j) {
            float tv = acc[i][j] + bv;
            if (jo.act == 1) tv = fmaxf(tv, 0.f);
            else if (jo.act == 2) tv = tanhf(tv);
            v[j] = tv;
        }
        *(float4*)(jo.dst + (size_t)b * jo.dbs + (size_t)co * 512 + l0 + tl4) = *(float4*)v;
    }
}

// ==================== grid barrier ====================
__global__ void zero_bar_k(unsigned* bar) { if (threadIdx.x < 2) bar[threadIdx.x] = 0u; }

__device__ __forceinline__ void grid_barrier(unsigned* bar) {
    unsigned g = __hip_atomic_load(bar + 1, __ATOMIC_ACQUIRE, __HIP_MEMORY_SCOPE_AGENT);
    unsigned a = __hip_atomic_fetch_add(bar, 1u, __ATOMIC_ACQ_REL, __HIP_MEMORY_SCOPE_AGENT);
    if (a == NBLK - 1) {
        __hip_atomic_store(bar, 0u, __ATOMIC_RELAXED, __HIP_MEMORY_SCOPE_AGENT);
        __hip_atomic_fetch_add(bar + 1, 1u, __ATOMIC_ACQ_REL, __HIP_MEMORY_SCOPE_AGENT);
    } else {
        while (__hip_atomic_load(bar + 1, __ATOMIC_ACQUIRE, __HIP_MEMORY_SCOPE_AGENT) == g)
            __builtin_amdgcn_s_sleep(8);
    }
}

// ==================== persistent recurrence ====================
// r3 geometry: 256 blocks (8 l-tiles x 32 b), 512 threads, 1 block/CU.
// W=80 state rows (l0-8 .. l0+71) x 128 co; 5 lt frags.
// NEW: y-store COALESCED through LDS temp[co][row] (stride 100):
//   update phase stages fp32 hy into temp; after barrier-2 each wave stores
//   16 co-rows as contiguous 256B runs. Removes the 16B/2KB-stride scatter.
__global__ __launch_bounds__(512, 2) void recur_fused_k(
    const float* __restrict__ hy0,     // [b][co][l], b-stride YB
    const float* __restrict__ omega,   // [b][co][l], b-stride 65536
    const float* __restrict__ alpha,
    const unsigned short* __restrict__ w2,
    float* __restrict__ yout,          // slab 0 base
    float* __restrict__ hze,           // [2][32][8][128][16] f32
    float* __restrict__ part,          // [32][50][128][8]
    unsigned* __restrict__ bar)
{
    int tile = blockIdx.x, b = blockIdx.y;
    int tid = threadIdx.x, lane = tid & 63, wid = tid >> 6;
    int lr = lane & 15, kg = lane >> 4;
    int co = wid * 16 + lr;
    int l0 = tile * 64;

    __shared__ uint4 hyS4[82 * 16];            // [row][chunk ^ (row&7)]
    __shared__ float temp[128 * TSTR];         // staging, [co][TSTR]
    unsigned short* hyS16 = (unsigned short*)hyS4;

    // ---- B weights (once)
    bf16x8 Bw[12];
    {
        const bf16x8* wp = (const bf16x8*)(w2 + (size_t)co * 384);
        #pragma unroll
        for (int s = 0; s < 12; ++s) Bw[s] = wp[s * 4 + kg];
    }

    // ---- stage+load initial state
    f32x4 hyR[5], hzR[5], omR[5], alR[5];

    // hy (temp covers l = l0-12 .. l0+75, width 88)
    for (int i = tid; i < 128 * 22; i += 512) {
        int c = i / 22, p4 = (i - c * 22) * 4;
        int l = (l0 - 12 + p4) & 511;
        *(f32x4*)(temp + c * TSTR + p4) = *(const f32x4*)(hy0 + (size_t)b * YB + (size_t)c * 512 + l);
    }
    __syncthreads();
    #pragma unroll
    for (int lt = 0; lt < 5; ++lt)
        hyR[lt] = *(const f32x4*)(temp + co * TSTR + 16 * lt + kg * 4 + 4);
    for (int i = tid; i < 82 * 16; i += 512) {
        int h = i >> 4, c8 = i & 15;
        unsigned short pk[8];
        #pragma unroll
        for (int q = 0; q < 8; ++q) pk[q] = f2bf(temp[(c8 * 8 + q) * TSTR + (h + 3)]);
        hyS4[h * 16 + (c8 ^ (h & 7))] = *(uint4*)pk;
    }
    __syncthreads();
    // omega
    for (int i = tid; i < 128 * 22; i += 512) {
        int c = i / 22, p4 = (i - c * 22) * 4;
        int l = (l0 - 12 + p4) & 511;
        *(f32x4*)(temp + c * TSTR + p4) = *(const f32x4*)(omega + (size_t)b * 65536 + (size_t)c * 512 + l);
    }
    __syncthreads();
    #pragma unroll
    for (int lt = 0; lt < 5; ++lt)
        omR[lt] = *(const f32x4*)(temp + co * TSTR + 16 * lt + kg * 4 + 4);
    __syncthreads();
    // alpha
    for (int i = tid; i < 128 * 22; i += 512) {
        int c = i / 22, p4 = (i - c * 22) * 4;
        int l = (l0 - 12 + p4) & 511;
        *(f32x4*)(temp + c * TSTR + p4) = *(const f32x4*)(alpha + (size_t)b * 65536 + (size_t)c * 512 + l);
    }
    __syncthreads();
    #pragma unroll
    for (int lt = 0; lt < 5; ++lt)
        alR[lt] = *(const f32x4*)(temp + co * TSTR + 16 * lt + kg * 4 + 4);
    #pragma unroll
    for (int lt = 0; lt < 5; ++lt) hzR[lt] = (f32x4){0.f, 0.f, 0.f, 0.f};
    __syncthreads();

    // ---- main loop
    for (int t = 0; t < 50; ++t) {
        // MFMA: conv over hyS
        f32x4 acc[5];
        #pragma unroll
        for (int lt = 0; lt < 5; ++lt) acc[lt] = (f32x4){0.f, 0.f, 0.f, 0.f};
        #pragma unroll
        for (int s = 0; s < 12; ++s) {
            int k = s >> 2;
            int arow = lr + k;
            int aidx = arow * 16 + ((arow & 7) ^ ((s & 3) * 4 + kg));
            bf16x8 Bf = Bw[s];
            #pragma unroll
            for (int lt = 0; lt < 5; ++lt) {
                bf16x8 a = __builtin_bit_cast(bf16x8, hyS4[aidx + lt * 256]);
                acc[lt] = __builtin_amdgcn_mfma_f32_16x16x32_bf16(a, Bf, acc[lt], 0, 0, 0);
            }
        }
        lds_sync();   // barrier 1: hyS reads + prior temp reads complete

        // pointwise update + temp/ hyS staging
        float lsum = 0.f;
        #pragma unroll
        for (int lt = 0; lt < 5; ++lt) {
            #pragma unroll
            for (int j = 0; j < 4; ++j) {
                float spring = tanh_fast(acc[lt][j]);
                float zn = hzR[lt][j] + DTc * (spring - omR[lt][j] * hyR[lt][j] - alR[lt][j] * hzR[lt][j]);
                float hn = hyR[lt][j] + DTc * zn;
                hzR[lt][j] = zn;
                hyR[lt][j] = hn;
            }
            bool valid = (lt > 0 || kg >= 2) && (lt < 4 || kg < 2);
            if (valid) {
                int r0 = lt * 16 + kg * 4;           // state row 8..71
                *(f32x4*)(temp + co * TSTR + r0) = hyR[lt];
                lsum += hyR[lt][0] + hyR[lt][1] + hyR[lt][2] + hyR[lt][3];
            }
            if (t < 49) {
                #pragma unroll
                for (int j = 0; j < 4; ++j) {
                    int rr = lt * 16 + kg * 4 + j + 1;   // hyS row
                    int sidx = rr * 128 + (((co >> 3) ^ (rr & 7)) << 3) + (co & 7);
                    hyS16[sidx] = f2bf(hyR[lt][j]);
                }
            }
        }
        lsum += __shfl_xor(lsum, 16);
        lsum += __shfl_xor(lsum, 32);
        if (kg == 0) part[(((size_t)b * 50 + t) * 128 + co) * 8 + tile] = lsum;

        lds_sync();   // barrier 2: temp + hyS writes visible

        // coalesced y store: wave wid stores co rows wid*16..wid*16+15,
        // lanes 0..15 cover 64 contiguous l (256B run per co row)
        {
            float* yrow = yout + (size_t)b * YB + (size_t)t * YT;
            int cs = wid * 16 + (lane >> 4);          // 4 co per pass
            int lq = (lane & 15) * 4;
            #pragma unroll
            for (int cq = 0; cq < 4; ++cq) {
                f32x4 v = *(const f32x4*)(temp + (cs + cq * 4) * TSTR + 8 + lq);
                *(f32x4*)(yrow + (size_t)(cs + cq * 4) * 512 + l0 + lq) = v;
            }
        }

        if ((t & 7) == 7 && t < 49) {
            // ---- chunk boundary: halo exchange (full drain here only)
            int par = (t >> 3) & 1;
            float* hb = hze + ((((size_t)par * 32 + b) * 8 + tile) * 128 + co) * 16;
            if (kg >= 2) *(f32x4*)(hb + (kg - 2) * 4) = hzR[0];  // center rows 8..15 -> e 0..7
            else         *(f32x4*)(hb + 8 + kg * 4)  = hzR[4];  // center rows 64..71 -> e 8..15
            __threadfence();
            __syncthreads();
            if (tid == 0) grid_barrier(bar);
            __syncthreads();
            __threadfence();
            // refresh halo regs
            const float* ycur = yout + (size_t)b * YB + (size_t)t * YT;
            if (kg < 2) {        // state rows 0..7 (lt0)
                int l = (l0 - 8 + kg * 4) & 511;
                hyR[0] = *(const f32x4*)(ycur + (size_t)co * 512 + l);
                const float* hbl = hze + ((((size_t)par * 32 + b) * 8 + ((tile + 7) & 7)) * 128 + co) * 16;
                hzR[0] = *(const f32x4*)(hbl + 8 + kg * 4);
            } else {             // state rows 72..79 (lt4)
                int l = (l0 + 64 + (kg - 2) * 4) & 511;
                hyR[4] = *(const f32x4*)(ycur + (size_t)co * 512 + l);
                const float* hbr = hze + ((((size_t)par * 32 + b) * 8 + ((tile + 1) & 7)) * 128 + co) * 16;
                hzR[4] = *(const f32x4*)(hbr + (kg - 2) * 4);
            }
            // refresh hyS halo rows 0..8, 73..81
            for (int i = tid; i < 18 * 128; i += 512) {
                int hr = i >> 7, c2 = i & 127;
                int h = (hr < 9) ? hr : (64 + hr);
                int l = (l0 - 9 + h) & 511;
                float v = ycur[(size_t)c2 * 512 + l];
                int sidx = h * 128 + (((c2 >> 3) ^ (h & 7)) << 3) + (c2 & 7);
                hyS16[sidx] = f2bf(v);
            }
            __syncthreads();
        }
    }
}

// ==================== readout ====================
__global__ __launch_bounds__(256) void readout_k(
    const float* __restrict__ part, const float* __restrict__ fct,
    const float* __restrict__ rw1, const float* __restrict__ rb1,
    const float* __restrict__ rw2, const float* __restrict__ rb2,
    const float* __restrict__ rw3, const float* __restrict__ rb3,
    float* __restrict__ out)
{
    int b = blockIdx.x, tid = threadIdx.x;
    __shared__ float ybar[50 * 128];
    __shared__ float feat[26 * 128];
    __shared__ float h1[64];
    __shared__ float h2[32];
    for (int idx = tid; idx < 50 * 128; idx += 256) {
        const float* p = part + ((size_t)b * 6400 + idx) * 8;
        float s = 0.f;
        #pragma unroll
        for (int q = 0; q < 8; ++q) s += p[q];
        ybar[idx] = s * (1.f / 512.f);
    }
    __syncthreads();
    for (int idx = tid; idx < 26 * 128; idx += 256) {
        int k = idx >> 7, c = idx & 127;
        float s = 0.f;
        for (int t = 0; t < 50; ++t) s += fct[k * 50 + t] * ybar[t * 128 + c];
        feat[idx] = s;
    }
    __syncthreads();
    {
        int j = tid >> 2, q = tid & 3;
        float s = 0.f;
        const float* r = rw1 + (size_t)j * 3328 + q * 832;
        const float* f = feat + q * 832;
        for (int i = 0; i < 832; ++i) s += f[i] * r[i];
        s += __shfl_xor(s, 1);
        s += __shfl_xor(s, 2);
        if (q == 0) h1[j] = fmaxf(s + rb1[j], 0.f);
    }
    __syncthreads();
    if (tid < 32) {
        float s = 0.f;
        for (int i = 0; i < 64; ++i) s += h1[i] * rw2[tid * 64 + i];
        h2[tid] = fmaxf(s + rb2[tid], 0.f);
    }
    __syncthreads();
    if (tid == 0) {
        float s = 0.f;
        for (int i = 0; i < 32; ++i) s += h2[i] * rw3[i];
        out[b] = s + rb3[0];
    }
}

// ==================== launch ====================
extern "C" void kernel_launch(void* const* d_in, const int* in_sizes, int n_in,
                              void* d_out, int out_size, void* d_ws, size_t ws_size,
                              hipStream_t stream)
{
    const float* x   = (const float*)d_in[0];
    const float* ow1 = (const float*)d_in[1];  const float* ob1 = (const float*)d_in[2];
    const float* ow2 = (const float*)d_in[3];  const float* ob2 = (const float*)d_in[4];
    const float* ow3 = (const float*)d_in[5];  const float* ob3 = (const float*)d_in[6];
    const float* aw1 = (const float*)d_in[7];  const float* ab1 = (const float*)d_in[8];
    const float* aw2 = (const float*)d_in[9];  const float* ab2 = (const float*)d_in[10];
    const float* aw3 = (const float*)d_in[11]; const float* ab3 = (const float*)d_in[12];
    const float* hw1 = (const float*)d_in[13]; const float* hb1 = (const float*)d_in[14];
    const float* hw2 = (const float*)d_in[15]; const float* hb2 = (const float*)d_in[16];
    const float* hw3 = (const float*)d_in[17]; const float* hb3 = (const float*)d_in[18];
    const float* hw4 = (const float*)d_in[19]; const float* hb4 = (const float*)d_in[20];
    const float* wy  = (const float*)d_in[21];
    const float* fct = (const float*)d_in[22];
    const float* rw1 = (const float*)d_in[23]; const float* rb1 = (const float*)d_in[24];
    const float* rw2 = (const float*)d_in[25]; const float* rb2 = (const float*)d_in[26];
    const float* rw3 = (const float*)d_in[27]; const float* rb3 = (const float*)d_in[28];

    float* out  = (float*)d_out;
    float* yout = out + 32;                       // y_seq region
    float* ws   = (float*)d_ws;

    // ws layout (float offsets)
    float* OMEGA = ws;                            // 2,097,152
    float* ALPHA = ws + 2097152;                  // 2,097,152
    float* WT    = ws + 4194304;                  // 353,280
    float* PART  = ws + 4547584;                  // 1,638,400
    float* HZE   = ws + 6185984;                  // 1,048,576
    unsigned short* W2 = (unsigned short*)(ws + 7234560);  // 49,152 u16
    unsigned* BAR = (unsigned*)(ws + 7259136);    // 2 u32
    // total ~29 MB

    // encoder scratch slabs inside y region (overwritten at t >= slab idx, after last use)
    float* To1 = yout + 44 * YT;
    float* Ta1 = yout + 45 * YT;
    float* Th1 = yout + 46 * YT;
    float* To2 = yout + 47 * YT;
    float* Ta2 = yout + 43 * YT;
    float* Th2 = yout + 49 * YT;
    float* Th3 = yout + 42 * YT;
    float* HY0 = yout + 48 * YT;

    float* OW1T = WT + 0;      float* AW1T = WT + 3072;   float* HW1T = WT + 6144;
    float* OW2T = WT + 9216;   float* OW3T = WT + 58368;
    float* AW2T = WT + 107520; float* AW3T = WT + 156672;
    float* HW2T = WT + 205824; float* HW3T = WT + 254976; float* HW4T = WT + 304128;

    WSrc wsrc;
    wsrc.p[0] = ow1; wsrc.p[1] = aw1; wsrc.p[2] = hw1;
    wsrc.p[3] = ow2; wsrc.p[4] = ow3; wsrc.p[5] = aw2; wsrc.p[6] = aw3;
    wsrc.p[7] = hw2; wsrc.p[8] = hw3; wsrc.p[9] = hw4; wsrc.p[10] = wy;
    wprep_all_k<<<1572, 256, 0, stream>>>(wsrc, WT, W2);

    Jobs3 d1 = {{ {x, To1, OW1T, ob1, 4096, YB, 1},
                  {x, Ta1, AW1T, ab1, 4096, YB, 1},
                  {x, Th1, HW1T, hb1, 4096, YB, 1} }};
    conv8x3_k<<<dim3(8, 3, 32), 256, 0, stream>>>(d1);

    Jobs3 d2 = {{ {To1, To2, OW2T, ob2, YB, YB, 1},
                  {Ta1, Ta2, AW2T, ab2, YB, YB, 1},
                  {Th1, Th2, HW2T, hb2, YB, YB, 1} }};
    conv128x3_k<<<dim3(8, 6, 32), 256, 0, stream>>>(d2);

    Jobs3 d3 = {{ {To2, OMEGA, OW3T, ob3, YB, 65536, 1},
                  {Ta2, ALPHA, AW3T, ab3, YB, 65536, 1},
                  {Th2, Th3, HW3T, hb3, YB, YB, 1} }};
    conv128x3_k<<<dim3(8, 6, 32), 256, 0, stream>>>(d3);

    Jobs3 d4 = {{ {Th3, HY0, HW4T, hb4, YB, YB, 2},
                  {Th3, HY0, HW4T, hb4, YB, YB, 2},
                  {Th3, HY0, HW4T, hb4, YB, YB, 2} }};
    conv128x3_k<<<dim3(8, 2, 32), 256, 0, stream>>>(d4);

    zero_bar_k<<<1, 64, 0, stream>>>(BAR);
    recur_fused_k<<<dim3(8, 32), 512, 0, stream>>>(HY0, OMEGA, ALPHA, W2,
                                                   yout, HZE, PART, BAR);

    readout_k<<<32, 256, 0, stream>>>(PART, fct, rw1, rb1, rw2, rb2, rw3, rb3, out);
}

// Round 8
// 770.753 us; speedup vs baseline: 2.9339x; 1.5176x over previous
//
#include <hip/hip_runtime.h>
#include <math.h>

#define YB (50*128*512)   // y_seq batch stride (floats)
#define YT (128*512)      // y_seq time stride
#define DTc 0.5f
#define TSTR 56           // temp row stride (floats)

typedef __attribute__((ext_vector_type(8))) short bf16x8;
typedef __attribute__((ext_vector_type(4))) float f32x4;

__device__ __forceinline__ unsigned short f2bf(float f) {
    unsigned int u = __builtin_bit_cast(unsigned int, f);
    u += 0x7fffu + ((u >> 16) & 1u);          // RNE
    return (unsigned short)(u >> 16);
}

__device__ __forceinline__ float tanh_fast(float x) {
    float ax = fabsf(x);
    float e  = __expf(-2.f * ax);
    float r  = (1.f - e) * __builtin_amdgcn_rcpf(1.f + e);
    return __builtin_copysignf(r, x);
}

// raw block barrier: waits LDS ops only, lets global stores stay in flight
__device__ __forceinline__ void lds_sync() {
    asm volatile("s_waitcnt lgkmcnt(0)" ::: "memory");
    __builtin_amdgcn_sched_barrier(0);
    __builtin_amdgcn_s_barrier();
    __builtin_amdgcn_sched_barrier(0);
}

// ==================== fused weight prep ====================
struct WSrc { const float* p[11]; };  // ow1,aw1,hw1, ow2,ow3,aw2,aw3,hw2,hw3,hw4, wy
__global__ void wprep_all_k(WSrc s, float* __restrict__ wt, unsigned short* __restrict__ w2) {
    int idx = blockIdx.x * 256 + threadIdx.x;
    if (idx < 9216) {
        int wsel = idx / 3072, r = idx % 3072;
        int row = r >> 7, co = r & 127;
        int ci = row / 3, k = row - ci * 3;
        wt[idx] = s.p[wsel][(co * 8 + ci) * 3 + k];
    } else if (idx < 353280) {
        int r = idx - 9216;
        int wsel = 3 + r / 49152, q = r % 49152;
        int row = q >> 7, co = q & 127;
        int ci = row / 3, k = row - ci * 3;
        wt[idx] = s.p[wsel][(co * 128 + ci) * 3 + k];
    } else if (idx < 402432) {
        int q = idx - 353280;
        int co = q / 384, kap = q - co * 384;
        int k = kap >> 7;
        int ci = ((kap >> 5) & 3) * 32 + (kap & 31);
        w2[q] = f2bf(s.p[10][(co * 128 + ci) * 3 + k]);
    }
}

// ==================== encoder convs (fp32, job-batched) ====================
struct Job { const float* src; float* dst; const float* wt; const float* bias; int sbs, dbs, act; };
struct Jobs3 { Job j[3]; };

__global__ __launch_bounds__(256) void conv8x3_k(Jobs3 js) {
    int jb = blockIdx.y % 3;
    Job jo = js.j[jb];
    int b = blockIdx.z, tile = blockIdx.x, tid = threadIdx.x;
    int l0 = tile * 64;
    int tl4 = (tid & 15) * 4;
    int co0 = (tid >> 4) * 8;
    __shared__ float xs[8 * 68];
    __shared__ float wsh[24 * 128];
    const float* sb = jo.src + (size_t)b * jo.sbs;
    for (int idx = tid; idx < 8 * 66; idx += 256) {
        int ci = idx / 66, ll = idx - ci * 66;
        int gl = l0 - 1 + ll;
        xs[ci * 68 + ll] = (gl >= 0 && gl < 512) ? sb[ci * 512 + gl] : 0.f;
    }
    for (int idx = tid; idx < 24 * 128; idx += 256) wsh[idx] = jo.wt[idx];
    __syncthreads();
    float acc[8][4] = {};
    #pragma unroll
    for (int ci = 0; ci < 8; ++ci) {
        float x6[6];
        #pragma unroll
        for (int j = 0; j < 6; ++j) x6[j] = xs[ci * 68 + tl4 + j];
        #pragma unroll
        for (int k = 0; k < 3; ++k) {
            float w8[8];
            #pragma unroll
            for (int i = 0; i < 8; ++i) w8[i] = wsh[(ci * 3 + k) * 128 + co0 + i];
            #pragma unroll
            for (int i = 0; i < 8; ++i)
                #pragma unroll
                for (int j = 0; j < 4; ++j)
                    acc[i][j] = fmaf(w8[i], x6[k + j], acc[i][j]);
        }
    }
    #pragma unroll
    for (int i = 0; i < 8; ++i) {
        int co = co0 + i;
        float bv = jo.bias[co];
        float4 o;
        o.x = fmaxf(acc[i][0] + bv, 0.f);
        o.y = fmaxf(acc[i][1] + bv, 0.f);
        o.z = fmaxf(acc[i][2] + bv, 0.f);
        o.w = fmaxf(acc[i][3] + bv, 0.f);
        *(float4*)(jo.dst + (size_t)b * jo.dbs + (size_t)co * 512 + l0 + tl4) = o;
    }
}

__global__ __launch_bounds__(256) void conv128x3_k(Jobs3 js) {
    int jb = blockIdx.y >> 1, cb = blockIdx.y & 1;
    Job jo = js.j[jb];
    int b = blockIdx.z, tile = blockIdx.x, tid = threadIdx.x;
    int l0 = tile * 64;
    int tl4 = (tid & 15) * 4;
    int col = (tid >> 4) * 4;
    __shared__ float xs[32 * 68];
    __shared__ float wsh[96 * 64];
    const float* sb = jo.src + (size_t)b * jo.sbs;
    float acc[4][4] = {};
    for (int chunk = 0; chunk < 4; ++chunk) {
        for (int idx = tid; idx < 32 * 66; idx += 256) {
            int ci = idx / 66, ll = idx - ci * 66;
            int gl = l0 - 1 + ll;
            xs[ci * 68 + ll] = (gl >= 0 && gl < 512) ? sb[(chunk * 32 + ci) * 512 + gl] : 0.f;
        }
        for (int idx = tid; idx < 96 * 16; idx += 256) {
            int row = idx >> 4, j = (idx & 15) * 4;
            *(float4*)(wsh + row * 64 + j) =
                *(const float4*)(jo.wt + (size_t)(chunk * 96 + row) * 128 + cb * 64 + j);
        }
        __syncthreads();
        #pragma unroll 4
        for (int ci = 0; ci < 32; ++ci) {
            float x6[6];
            #pragma unroll
            for (int j = 0; j < 6; ++j) x6[j] = xs[ci * 68 + tl4 + j];
            #pragma unroll
            for (int k = 0; k < 3; ++k) {
                float w4[4];
                #pragma unroll
                for (int i = 0; i < 4; ++i) w4[i] = wsh[(ci * 3 + k) * 64 + col + i];
                #pragma unroll
                for (int i = 0; i < 4; ++i)
                    #pragma unroll
                    for (int j = 0; j < 4; ++j)
                        acc[i][j] = fmaf(w4[i], x6[k + j], acc[i][j]);
            }
        }
        __syncthreads();
    }
    #pragma unroll
    for (int i = 0; i < 4; ++i) {
        int co = cb * 64 + col + i;
        float bv = jo.bias[co];
        float v[4];
        #pragma unroll
        for (int j = 0; j < 4; ++j) {
            float tv = acc[i][j] + bv;
            if (jo.act == 1) tv = fmaxf(tv, 0.f);
            else if (jo.act == 2) tv = tanhf(tv);
            v[j] = tv;
        }
        *(float4*)(jo.dst + (size_t)b * jo.dbs + (size_t)co * 512 + l0 + tl4) = *(float4*)v;
    }
}

// ==================== 5-step chunk kernel (no grid barrier) ====================
// 512 blocks (16 l-tiles of center 32 x 32 b), 512 threads (8 waves), 2 blocks/CU.
// Stages 48 state rows (l0-8 .. l0+39) + 50 hyS rows (l0-9 .. l0+40); shrinking
// halo keeps center [8,39] valid through 5 steps. Reads hy from y slab t0-1
// (or HY0), hz from ping-pong; writes 5 y slabs + hz center. No cross-block
// coupling within a launch.
__global__ __launch_bounds__(512, 2) void chunk_k(
    const float* __restrict__ hy_in,   // [b][co][l], b-stride YB
    const float* __restrict__ hz_in,   // [b][co][l], b-stride 65536 (unused t0==0)
    float* __restrict__ hz_out,
    const float* __restrict__ omega, const float* __restrict__ alpha,
    const unsigned short* __restrict__ w2,
    float* __restrict__ ybase,         // slab t0 base (b-stride YB, slab stride YT)
    float* __restrict__ part, int t0)
{
    int tile = blockIdx.x, b = blockIdx.y;
    int tid = threadIdx.x, lane = tid & 63, wid = tid >> 6;
    int lr = lane & 15, kg = lane >> 4;
    int co = wid * 16 + lr;
    int l0 = tile * 32;

    __shared__ float temp[128 * TSTR];     // stage cols: l0-12 .. ; loop cols: l0..l0+31
    __shared__ uint4 hyS4[50 * 16];        // row h <-> l0-9+h, [row][chunk ^ (row&7)]
    unsigned short* hyS16 = (unsigned short*)hyS4;

    bf16x8 Bw[12];
    {
        const bf16x8* wp = (const bf16x8*)(w2 + (size_t)co * 384);
        #pragma unroll
        for (int s = 0; s < 12; ++s) Bw[s] = wp[s * 4 + kg];
    }

    f32x4 hyR[3], hzR[3], omR[3], alR[3];

    // ---- stage hy (cols 0..55 <-> l0-12 .. l0+43)
    {
        const float* src = hy_in + (size_t)b * YB;
        for (int i = tid; i < 128 * 14; i += 512) {
            int c = i / 14, p4 = (i - c * 14) * 4;
            int l = (l0 - 12 + p4) & 511;
            *(f32x4*)(temp + c * TSTR + p4) = *(const f32x4*)(src + (size_t)c * 512 + l);
        }
    }
    __syncthreads();
    #pragma unroll
    for (int lt = 0; lt < 3; ++lt)
        hyR[lt] = *(const f32x4*)(temp + co * TSTR + 16 * lt + 4 * kg + 4);
    for (int i = tid; i < 50 * 16; i += 512) {
        int h = i >> 4, c8 = i & 15;
        unsigned short pk[8];
        #pragma unroll
        for (int q = 0; q < 8; ++q) pk[q] = f2bf(temp[(c8 * 8 + q) * TSTR + h + 3]);
        hyS4[h * 16 + (c8 ^ (h & 7))] = *(uint4*)pk;
    }
    __syncthreads();
    // ---- stage omega
    {
        const float* src = omega + (size_t)b * 65536;
        for (int i = tid; i < 128 * 14; i += 512) {
            int c = i / 14, p4 = (i - c * 14) * 4;
            int l = (l0 - 12 + p4) & 511;
            *(f32x4*)(temp + c * TSTR + p4) = *(const f32x4*)(src + (size_t)c * 512 + l);
        }
    }
    __syncthreads();
    #pragma unroll
    for (int lt = 0; lt < 3; ++lt)
        omR[lt] = *(const f32x4*)(temp + co * TSTR + 16 * lt + 4 * kg + 4);
    __syncthreads();
    // ---- stage alpha
    {
        const float* src = alpha + (size_t)b * 65536;
        for (int i = tid; i < 128 * 14; i += 512) {
            int c = i / 14, p4 = (i - c * 14) * 4;
            int l = (l0 - 12 + p4) & 511;
            *(f32x4*)(temp + c * TSTR + p4) = *(const f32x4*)(src + (size_t)c * 512 + l);
        }
    }
    __syncthreads();
    #pragma unroll
    for (int lt = 0; lt < 3; ++lt)
        alR[lt] = *(const f32x4*)(temp + co * TSTR + 16 * lt + 4 * kg + 4);
    // ---- stage hz (or zero)
    if (t0 > 0) {
        __syncthreads();
        const float* src = hz_in + (size_t)b * 65536;
        for (int i = tid; i < 128 * 14; i += 512) {
            int c = i / 14, p4 = (i - c * 14) * 4;
            int l = (l0 - 12 + p4) & 511;
            *(f32x4*)(temp + c * TSTR + p4) = *(const f32x4*)(src + (size_t)c * 512 + l);
        }
        __syncthreads();
        #pragma unroll
        for (int lt = 0; lt < 3; ++lt)
            hzR[lt] = *(const f32x4*)(temp + co * TSTR + 16 * lt + 4 * kg + 4);
    } else {
        #pragma unroll
        for (int lt = 0; lt < 3; ++lt) hzR[lt] = (f32x4){0.f, 0.f, 0.f, 0.f};
    }
    __syncthreads();

    // ---- 5 steps
    for (int i = 0; i < 5; ++i) {
        int t = t0 + i;
        f32x4 acc[3];
        #pragma unroll
        for (int lt = 0; lt < 3; ++lt) acc[lt] = (f32x4){0.f, 0.f, 0.f, 0.f};
        #pragma unroll
        for (int s = 0; s < 12; ++s) {
            int chunk = (s & 3) * 4 + kg;
            int k = s >> 2;
            bf16x8 Bf = Bw[s];
            #pragma unroll
            for (int lt = 0; lt < 3; ++lt) {
                int arow = 16 * lt + lr + k;
                bf16x8 a = __builtin_bit_cast(bf16x8, hyS4[arow * 16 + ((arow & 7) ^ chunk)]);
                acc[lt] = __builtin_amdgcn_mfma_f32_16x16x32_bf16(a, Bf, acc[lt], 0, 0, 0);
            }
        }
        lds_sync();   // all hyS/temp reads complete

        float lsum = 0.f;
        #pragma unroll
        for (int lt = 0; lt < 3; ++lt) {
            #pragma unroll
            for (int j = 0; j < 4; ++j) {
                float spring = tanh_fast(acc[lt][j]);
                float zn = hzR[lt][j] + DTc * (spring - omR[lt][j] * hyR[lt][j] - alR[lt][j] * hzR[lt][j]);
                float hn = hyR[lt][j] + DTc * zn;
                hzR[lt][j] = zn;
                hyR[lt][j] = hn;
            }
            bool valid = (lt == 0) ? (kg >= 2) : (lt == 2) ? (kg < 2) : true;
            int r0 = 16 * lt + 4 * kg;
            if (valid) {
                *(f32x4*)(temp + co * TSTR + (r0 - 8)) = hyR[lt];
                lsum += hyR[lt][0] + hyR[lt][1] + hyR[lt][2] + hyR[lt][3];
                if (i == 4)
                    *(f32x4*)(hz_out + (size_t)b * 65536 + (size_t)co * 512 + l0 + (r0 - 8)) = hzR[lt];
            }
            if (i < 4) {
                #pragma unroll
                for (int j = 0; j < 4; ++j) {
                    int rr = r0 + j + 1;
                    int sidx = rr * 128 + (((co >> 3) ^ (rr & 7)) << 3) + (co & 7);
                    hyS16[sidx] = f2bf(hyR[lt][j]);
                }
            }
        }
        lsum += __shfl_xor(lsum, 16);
        lsum += __shfl_xor(lsum, 32);
        if (kg == 0) part[(((size_t)b * 50 + t) * 128 + co) * 16 + tile] = lsum;

        lds_sync();   // temp + hyS writes visible

        // coalesced y store: center 32 l per co as 128B runs
        {
            float* yrow = ybase + (size_t)b * YB + (size_t)i * YT;
            int cs = wid * 16 + (lane >> 3);
            int lq = (lane & 7) * 4;
            #pragma unroll
            for (int cq = 0; cq < 2; ++cq) {
                int c2 = cs + cq * 8;
                f32x4 v = *(const f32x4*)(temp + c2 * TSTR + lq);
                *(f32x4*)(yrow + (size_t)c2 * 512 + l0 + lq) = v;
            }
        }
    }
}

// ==================== readout ====================
__global__ __launch_bounds__(256) void readout_k(
    const float* __restrict__ part, const float* __restrict__ fct,
    const float* __restrict__ rw1, const float* __restrict__ rb1,
    const float* __restrict__ rw2, const float* __restrict__ rb2,
    const float* __restrict__ rw3, const float* __restrict__ rb3,
    float* __restrict__ out)
{
    int b = blockIdx.x, tid = threadIdx.x;
    __shared__ float ybar[50 * 128];
    __shared__ float feat[26 * 128];
    __shared__ float h1[64];
    __shared__ float h2[32];
    for (int idx = tid; idx < 50 * 128; idx += 256) {
        const float* p = part + ((size_t)b * 6400 + idx) * 16;
        float s = 0.f;
        #pragma unroll
        for (int q = 0; q < 16; ++q) s += p[q];
        ybar[idx] = s * (1.f / 512.f);
    }
    __syncthreads();
    for (int idx = tid; idx < 26 * 128; idx += 256) {
        int k = idx >> 7, c = idx & 127;
        float s = 0.f;
        for (int t = 0; t < 50; ++t) s += fct[k * 50 + t] * ybar[t * 128 + c];
        feat[idx] = s;
    }
    __syncthreads();
    {
        int j = tid >> 2, q = tid & 3;
        float s = 0.f;
        const float* r = rw1 + (size_t)j * 3328 + q * 832;
        const float* f = feat + q * 832;
        for (int i = 0; i < 832; ++i) s += f[i] * r[i];
        s += __shfl_xor(s, 1);
        s += __shfl_xor(s, 2);
        if (q == 0) h1[j] = fmaxf(s + rb1[j], 0.f);
    }
    __syncthreads();
    if (tid < 32) {
        float s = 0.f;
        for (int i = 0; i < 64; ++i) s += h1[i] * rw2[tid * 64 + i];
        h2[tid] = fmaxf(s + rb2[tid], 0.f);
    }
    __syncthreads();
    if (tid == 0) {
        float s = 0.f;
        for (int i = 0; i < 32; ++i) s += h2[i] * rw3[i];
        out[b] = s + rb3[0];
    }
}

// ==================== launch ====================
extern "C" void kernel_launch(void* const* d_in, const int* in_sizes, int n_in,
                              void* d_out, int out_size, void* d_ws, size_t ws_size,
                              hipStream_t stream)
{
    const float* x   = (const float*)d_in[0];
    const float* ow1 = (const float*)d_in[1];  const float* ob1 = (const float*)d_in[2];
    const float* ow2 = (const float*)d_in[3];  const float* ob2 = (const float*)d_in[4];
    const float* ow3 = (const float*)d_in[5];  const float* ob3 = (const float*)d_in[6];
    const float* aw1 = (const float*)d_in[7];  const float* ab1 = (const float*)d_in[8];
    const float* aw2 = (const float*)d_in[9];  const float* ab2 = (const float*)d_in[10];
    const float* aw3 = (const float*)d_in[11]; const float* ab3 = (const float*)d_in[12];
    const float* hw1 = (const float*)d_in[13]; const float* hb1 = (const float*)d_in[14];
    const float* hw2 = (const float*)d_in[15]; const float* hb2 = (const float*)d_in[16];
    const float* hw3 = (const float*)d_in[17]; const float* hb3 = (const float*)d_in[18];
    const float* hw4 = (const float*)d_in[19]; const float* hb4 = (const float*)d_in[20];
    const float* wy  = (const float*)d_in[21];
    const float* fct = (const float*)d_in[22];
    const float* rw1 = (const float*)d_in[23]; const float* rb1 = (const float*)d_in[24];
    const float* rw2 = (const float*)d_in[25]; const float* rb2 = (const float*)d_in[26];
    const float* rw3 = (const float*)d_in[27]; const float* rb3 = (const float*)d_in[28];

    float* out  = (float*)d_out;
    float* yout = out + 32;                       // y_seq region
    float* ws   = (float*)d_ws;

    // ws layout (float offsets)
    float* OMEGA = ws;                            // 2,097,152
    float* ALPHA = ws + 2097152;                  // 2,097,152
    float* WT    = ws + 4194304;                  // 353,280
    float* PART  = ws + 4547584;                  // 3,276,800 (32*50*128*16)
    float* HZ0   = ws + 7824384;                  // 2,097,152
    float* HZ1   = ws + 9921536;                  // 2,097,152
    unsigned short* W2 = (unsigned short*)(ws + 12018688);  // 49,152 u16
    // total ~48.2 MB

    // encoder scratch slabs inside y region (overwritten at chunks covering
    // t >= 42, long after last encoder use)
    float* To1 = yout + 44 * YT;
    float* Ta1 = yout + 45 * YT;
    float* Th1 = yout + 46 * YT;
    float* To2 = yout + 47 * YT;
    float* Ta2 = yout + 43 * YT;
    float* Th2 = yout + 49 * YT;
    float* Th3 = yout + 42 * YT;
    float* HY0 = yout + 48 * YT;

    float* OW1T = WT + 0;      float* AW1T = WT + 3072;   float* HW1T = WT + 6144;
    float* OW2T = WT + 9216;   float* OW3T = WT + 58368;
    float* AW2T = WT + 107520; float* AW3T = WT + 156672;
    float* HW2T = WT + 205824; float* HW3T = WT + 254976; float* HW4T = WT + 304128;

    WSrc wsrc;
    wsrc.p[0] = ow1; wsrc.p[1] = aw1; wsrc.p[2] = hw1;
    wsrc.p[3] = ow2; wsrc.p[4] = ow3; wsrc.p[5] = aw2; wsrc.p[6] = aw3;
    wsrc.p[7] = hw2; wsrc.p[8] = hw3; wsrc.p[9] = hw4; wsrc.p[10] = wy;
    wprep_all_k<<<1572, 256, 0, stream>>>(wsrc, WT, W2);

    Jobs3 d1 = {{ {x, To1, OW1T, ob1, 4096, YB, 1},
                  {x, Ta1, AW1T, ab1, 4096, YB, 1},
                  {x, Th1, HW1T, hb1, 4096, YB, 1} }};
    conv8x3_k<<<dim3(8, 3, 32), 256, 0, stream>>>(d1);

    Jobs3 d2 = {{ {To1, To2, OW2T, ob2, YB, YB, 1},
                  {Ta1, Ta2, AW2T, ab2, YB, YB, 1},
                  {Th1, Th2, HW2T, hb2, YB, YB, 1} }};
    conv128x3_k<<<dim3(8, 6, 32), 256, 0, stream>>>(d2);

    Jobs3 d3 = {{ {To2, OMEGA, OW3T, ob3, YB, 65536, 1},
                  {Ta2, ALPHA, AW3T, ab3, YB, 65536, 1},
                  {Th2, Th3, HW3T, hb3, YB, YB, 1} }};
    conv128x3_k<<<dim3(8, 6, 32), 256, 0, stream>>>(d3);

    Jobs3 d4 = {{ {Th3, HY0, HW4T, hb4, YB, YB, 2},
                  {Th3, HY0, HW4T, hb4, YB, YB, 2},
                  {Th3, HY0, HW4T, hb4, YB, YB, 2} }};
    conv128x3_k<<<dim3(8, 2, 32), 256, 0, stream>>>(d4);

    // ---- recurrence: 10 chunk launches of 5 steps each
    for (int c = 0; c < 10; ++c) {
        int t0 = c * 5;
        const float* hyin = (c == 0) ? HY0 : (yout + (size_t)(t0 - 1) * YT);
        const float* hzin = (c & 1) ? HZ1 : HZ0;
        float* hzout      = (c & 1) ? HZ0 : HZ1;
        chunk_k<<<dim3(16, 32), 512, 0, stream>>>(hyin, hzin, hzout,
                                                  OMEGA, ALPHA, W2,
                                                  yout + (size_t)t0 * YT, PART, t0);
    }

    readout_k<<<32, 256, 0, stream>>>(PART, fct, rw1, rb1, rw2, rb2, rw3, rb3, out);
}

// Round 9
// 720.600 us; speedup vs baseline: 3.1381x; 1.0696x over previous
//
#include <hip/hip_runtime.h>
#include <math.h>

#define YB (50*128*512)   // y_seq batch stride (floats)
#define YT (128*512)      // y_seq time stride
#define DTc 0.5f

typedef __attribute__((ext_vector_type(8))) short bf16x8;
typedef __attribute__((ext_vector_type(4))) float f32x4;

__device__ __forceinline__ unsigned short f2bf(float f) {
    unsigned int u = __builtin_bit_cast(unsigned int, f);
    u += 0x7fffu + ((u >> 16) & 1u);          // RNE
    return (unsigned short)(u >> 16);
}

__device__ __forceinline__ float tanh_fast(float x) {
    float ax = fabsf(x);
    float e  = __expf(-2.f * ax);
    float r  = (1.f - e) * __builtin_amdgcn_rcpf(1.f + e);
    return __builtin_copysignf(r, x);
}

// raw block barrier: waits LDS ops only, lets global stores stay in flight
__device__ __forceinline__ void lds_sync() {
    asm volatile("s_waitcnt lgkmcnt(0)" ::: "memory");
    __builtin_amdgcn_sched_barrier(0);
    __builtin_amdgcn_s_barrier();
    __builtin_amdgcn_sched_barrier(0);
}

// ==================== fused weight prep ====================
struct WSrc { const float* p[11]; };  // ow1,aw1,hw1, ow2,ow3,aw2,aw3,hw2,hw3,hw4, wy
__global__ void wprep_all_k(WSrc s, float* __restrict__ wt, unsigned short* __restrict__ w2) {
    int idx = blockIdx.x * 256 + threadIdx.x;
    if (idx < 9216) {
        int wsel = idx / 3072, r = idx % 3072;
        int row = r >> 7, co = r & 127;
        int ci = row / 3, k = row - ci * 3;
        wt[idx] = s.p[wsel][(co * 8 + ci) * 3 + k];
    } else if (idx < 353280) {
        int r = idx - 9216;
        int wsel = 3 + r / 49152, q = r % 49152;
        int row = q >> 7, co = q & 127;
        int ci = row / 3, k = row - ci * 3;
        wt[idx] = s.p[wsel][(co * 128 + ci) * 3 + k];
    } else if (idx < 402432) {
        int q = idx - 353280;
        int co = q / 384, kap = q - co * 384;
        int k = kap >> 7;
        int ci = ((kap >> 5) & 3) * 32 + (kap & 31);
        w2[q] = f2bf(s.p[10][(co * 128 + ci) * 3 + k]);
    }
}

// ==================== encoder convs (fp32, job-batched) ====================
struct Job { const float* src; float* dst; const float* wt; const float* bias; int sbs, dbs, act; };
struct Jobs3 { Job j[3]; };

__global__ __launch_bounds__(256) void conv8x3_k(Jobs3 js) {
    int jb = blockIdx.y % 3;
    Job jo = js.j[jb];
    int b = blockIdx.z, tile = blockIdx.x, tid = threadIdx.x;
    int l0 = tile * 64;
    int tl4 = (tid & 15) * 4;
    int co0 = (tid >> 4) * 8;
    __shared__ float xs[8 * 68];
    __shared__ float wsh[24 * 128];
    const float* sb = jo.src + (size_t)b * jo.sbs;
    for (int idx = tid; idx < 8 * 66; idx += 256) {
        int ci = idx / 66, ll = idx - ci * 66;
        int gl = l0 - 1 + ll;
        xs[ci * 68 + ll] = (gl >= 0 && gl < 512) ? sb[ci * 512 + gl] : 0.f;
    }
    for (int idx = tid; idx < 24 * 128; idx += 256) wsh[idx] = jo.wt[idx];
    __syncthreads();
    float acc[8][4] = {};
    #pragma unroll
    for (int ci = 0; ci < 8; ++ci) {
        float x6[6];
        #pragma unroll
        for (int j = 0; j < 6; ++j) x6[j] = xs[ci * 68 + tl4 + j];
        #pragma unroll
        for (int k = 0; k < 3; ++k) {
            float w8[8];
            #pragma unroll
            for (int i = 0; i < 8; ++i) w8[i] = wsh[(ci * 3 + k) * 128 + co0 + i];
            #pragma unroll
            for (int i = 0; i < 8; ++i)
                #pragma unroll
                for (int j = 0; j < 4; ++j)
                    acc[i][j] = fmaf(w8[i], x6[k + j], acc[i][j]);
        }
    }
    #pragma unroll
    for (int i = 0; i < 8; ++i) {
        int co = co0 + i;
        float bv = jo.bias[co];
        float4 o;
        o.x = fmaxf(acc[i][0] + bv, 0.f);
        o.y = fmaxf(acc[i][1] + bv, 0.f);
        o.z = fmaxf(acc[i][2] + bv, 0.f);
        o.w = fmaxf(acc[i][3] + bv, 0.f);
        *(float4*)(jo.dst + (size_t)b * jo.dbs + (size_t)co * 512 + l0 + tl4) = o;
    }
}

__global__ __launch_bounds__(256) void conv128x3_k(Jobs3 js) {
    int jb = blockIdx.y >> 1, cb = blockIdx.y & 1;
    Job jo = js.j[jb];
    int b = blockIdx.z, tile = blockIdx.x, tid = threadIdx.x;
    int l0 = tile * 64;
    int tl4 = (tid & 15) * 4;
    int col = (tid >> 4) * 4;
    __shared__ float xs[32 * 68];
    __shared__ float wsh[96 * 64];
    const float* sb = jo.src + (size_t)b * jo.sbs;
    float acc[4][4] = {};
    for (int chunk = 0; chunk < 4; ++chunk) {
        for (int idx = tid; idx < 32 * 66; idx += 256) {
            int ci = idx / 66, ll = idx - ci * 66;
            int gl = l0 - 1 + ll;
            xs[ci * 68 + ll] = (gl >= 0 && gl < 512) ? sb[(chunk * 32 + ci) * 512 + gl] : 0.f;
        }
        for (int idx = tid; idx < 96 * 16; idx += 256) {
            int row = idx >> 4, j = (idx & 15) * 4;
            *(float4*)(wsh + row * 64 + j) =
                *(const float4*)(jo.wt + (size_t)(chunk * 96 + row) * 128 + cb * 64 + j);
        }
        __syncthreads();
        #pragma unroll 4
        for (int ci = 0; ci < 32; ++ci) {
            float x6[6];
            #pragma unroll
            for (int j = 0; j < 6; ++j) x6[j] = xs[ci * 68 + tl4 + j];
            #pragma unroll
            for (int k = 0; k < 3; ++k) {
                float w4[4];
                #pragma unroll
                for (int i = 0; i < 4; ++i) w4[i] = wsh[(ci * 3 + k) * 64 + col + i];
                #pragma unroll
                for (int i = 0; i < 4; ++i)
                    #pragma unroll
                    for (int j = 0; j < 4; ++j)
                        acc[i][j] = fmaf(w4[i], x6[k + j], acc[i][j]);
            }
        }
        __syncthreads();
    }
    #pragma unroll
    for (int i = 0; i < 4; ++i) {
        int co = cb * 64 + col + i;
        float bv = jo.bias[co];
        float v[4];
        #pragma unroll
        for (int j = 0; j < 4; ++j) {
            float tv = acc[i][j] + bv;
            if (jo.act == 1) tv = fmaxf(tv, 0.f);
            else if (jo.act == 2) tv = tanhf(tv);
            v[j] = tv;
        }
        *(float4*)(jo.dst + (size_t)b * jo.dbs + (size_t)co * 512 + l0 + tl4) = *(float4*)v;
    }
}

// ==================== 5-step chunk kernel ====================
// 512 blocks (16 l-tiles of center 32 x 32 b), 512 threads, 2 blocks/CU.
// hyS double-buffered + y-temp double-buffered -> ONE lds_sync per step.
// omega/alpha/hz loaded DIRECT from global (no LDS staging passes).
// Shrinking halo: staged rows l0-8..l0+39, center [l0,l0+31] valid all 5 steps.
__global__ __launch_bounds__(512, 2) void chunk_k(
    const float* __restrict__ hy_in,   // [b][co][l], b-stride YB
    const float* __restrict__ hz_in,   // [b][co][l], b-stride 65536
    float* __restrict__ hz_out,
    const float* __restrict__ omega, const float* __restrict__ alpha,
    const unsigned short* __restrict__ w2,
    float* __restrict__ ybase,         // slab t0 base
    float* __restrict__ part, int t0)
{
    int tile = blockIdx.x, b = blockIdx.y;
    int tid = threadIdx.x, lane = tid & 63, wid = tid >> 6;
    int lr = lane & 15, kg = lane >> 4;
    int co = wid * 16 + lr;
    int l0 = tile * 32;

    __shared__ uint4 hySd[2][800];         // [buf][row h 0..49][chunk ^ (h&7)]
    __shared__ float ytmp[2 * 4608];       // [buf][co][36]; prologue aliases as stage[128][56]
    float* stage = ytmp;

    bf16x8 Bw[12];
    {
        const bf16x8* wp = (const bf16x8*)(w2 + (size_t)co * 384);
        #pragma unroll
        for (int s = 0; s < 12; ++s) Bw[s] = wp[s * 4 + kg];
    }

    f32x4 hyR[3], hzR[3], omR[3], alR[3];

    // ---- prologue: coalesced hy stage (cols 0..55 <-> l0-12 .. l0+43)
    {
        const float* src = hy_in + (size_t)b * YB;
        for (int i = tid; i < 128 * 14; i += 512) {
            int c = i / 14, p4 = (i - c * 14) * 4;
            int l = (l0 - 12 + p4) & 511;
            *(f32x4*)(stage + c * 56 + p4) = *(const f32x4*)(src + (size_t)c * 512 + l);
        }
    }
    __syncthreads();
    #pragma unroll
    for (int lt = 0; lt < 3; ++lt)
        hyR[lt] = *(const f32x4*)(stage + co * 56 + 16 * lt + 4 * kg + 4);
    for (int i = tid; i < 50 * 16; i += 512) {
        int h = i >> 4, c8 = i & 15;
        unsigned short pk[8];
        #pragma unroll
        for (int q = 0; q < 8; ++q) pk[q] = f2bf(stage[(c8 * 8 + q) * 56 + h + 3]);
        hySd[0][h * 16 + (c8 ^ (h & 7))] = *(uint4*)pk;
    }
    // direct global loads: omega/alpha/hz (thread's own state rows)
    {
        size_t ob = (size_t)b * 65536 + (size_t)co * 512;
        #pragma unroll
        for (int lt = 0; lt < 3; ++lt) {
            int l = (l0 - 8 + 16 * lt + 4 * kg) & 511;
            omR[lt] = *(const f32x4*)(omega + ob + l);
            alR[lt] = *(const f32x4*)(alpha + ob + l);
            if (t0 > 0) hzR[lt] = *(const f32x4*)(hz_in + ob + l);
            else        hzR[lt] = (f32x4){0.f, 0.f, 0.f, 0.f};
        }
    }
    __syncthreads();   // hyS[0] visible; stage reads done before loop overwrites ytmp

    // ---- 5 steps, ONE lds_sync each
    for (int i = 0; i < 5; ++i) {
        const uint4* hc = &hySd[i & 1][0];
        unsigned short* hn16 = (unsigned short*)&hySd[(i + 1) & 1][0];
        float* yt = ytmp + (i & 1) * 4608;

        f32x4 acc[3];
        #pragma unroll
        for (int lt = 0; lt < 3; ++lt) acc[lt] = (f32x4){0.f, 0.f, 0.f, 0.f};
        #pragma unroll
        for (int s = 0; s < 12; ++s) {
            int chunk = (s & 3) * 4 + kg;
            int k = s >> 2;
            bf16x8 Bf = Bw[s];
            #pragma unroll
            for (int lt = 0; lt < 3; ++lt) {
                int arow = 16 * lt + lr + k;
                bf16x8 a = __builtin_bit_cast(bf16x8, hc[arow * 16 + ((arow & 7) ^ chunk)]);
                acc[lt] = __builtin_amdgcn_mfma_f32_16x16x32_bf16(a, Bf, acc[lt], 0, 0, 0);
            }
        }

        float lsum = 0.f;
        #pragma unroll
        for (int lt = 0; lt < 3; ++lt) {
            #pragma unroll
            for (int j = 0; j < 4; ++j) {
                float spring = tanh_fast(acc[lt][j]);
                float zn = hzR[lt][j] + DTc * (spring - omR[lt][j] * hyR[lt][j] - alR[lt][j] * hzR[lt][j]);
                float hn = hyR[lt][j] + DTc * zn;
                hzR[lt][j] = zn;
                hyR[lt][j] = hn;
            }
            bool valid = (lt == 0) ? (kg >= 2) : (lt == 2) ? (kg < 2) : true;
            int r0 = 16 * lt + 4 * kg;
            if (valid) {
                *(f32x4*)(yt + co * 36 + (r0 - 8)) = hyR[lt];
                lsum += hyR[lt][0] + hyR[lt][1] + hyR[lt][2] + hyR[lt][3];
                if (i == 4)
                    *(f32x4*)(hz_out + (size_t)b * 65536 + (size_t)co * 512 + l0 + (r0 - 8)) = hzR[lt];
            }
            if (i < 4) {
                #pragma unroll
                for (int j = 0; j < 4; ++j) {
                    int rr = r0 + j + 1;
                    int sidx = rr * 128 + (((co >> 3) ^ (rr & 7)) << 3) + (co & 7);
                    hn16[sidx] = f2bf(hyR[lt][j]);
                }
            }
        }
        lsum += __shfl_xor(lsum, 16);
        lsum += __shfl_xor(lsum, 32);
        if (kg == 0) part[(((size_t)b * 50 + t0 + i) * 128 + co) * 16 + tile] = lsum;

        lds_sync();   // hyS[nxt] + yt writes visible; prior yt reads drained

        // coalesced y store from yt (128B runs)
        {
            float* yrow = ybase + (size_t)b * YB + (size_t)i * YT;
            int cs = wid * 16 + (lane >> 3);
            int lq = (lane & 7) * 4;
            #pragma unroll
            for (int cq = 0; cq < 2; ++cq) {
                int c2 = cs + cq * 8;
                f32x4 v = *(const f32x4*)(yt + c2 * 36 + lq);
                *(f32x4*)(yrow + (size_t)c2 * 512 + l0 + lq) = v;
            }
        }
    }
}

// ==================== readout ====================
__global__ __launch_bounds__(256) void readout_k(
    const float* __restrict__ part, const float* __restrict__ fct,
    const float* __restrict__ rw1, const float* __restrict__ rb1,
    const float* __restrict__ rw2, const float* __restrict__ rb2,
    const float* __restrict__ rw3, const float* __restrict__ rb3,
    float* __restrict__ out)
{
    int b = blockIdx.x, tid = threadIdx.x;
    __shared__ float ybar[50 * 128];
    __shared__ float feat[26 * 128];
    __shared__ float h1[64];
    __shared__ float h2[32];
    for (int idx = tid; idx < 50 * 128; idx += 256) {
        const float* p = part + ((size_t)b * 6400 + idx) * 16;
        float s = 0.f;
        #pragma unroll
        for (int q = 0; q < 16; ++q) s += p[q];
        ybar[idx] = s * (1.f / 512.f);
    }
    __syncthreads();
    for (int idx = tid; idx < 26 * 128; idx += 256) {
        int k = idx >> 7, c = idx & 127;
        float s = 0.f;
        for (int t = 0; t < 50; ++t) s += fct[k * 50 + t] * ybar[t * 128 + c];
        feat[idx] = s;
    }
    __syncthreads();
    {
        int j = tid >> 2, q = tid & 3;
        float s = 0.f;
        const float* r = rw1 + (size_t)j * 3328 + q * 832;
        const float* f = feat + q * 832;
        for (int i = 0; i < 832; ++i) s += f[i] * r[i];
        s += __shfl_xor(s, 1);
        s += __shfl_xor(s, 2);
        if (q == 0) h1[j] = fmaxf(s + rb1[j], 0.f);
    }
    __syncthreads();
    if (tid < 32) {
        float s = 0.f;
        for (int i = 0; i < 64; ++i) s += h1[i] * rw2[tid * 64 + i];
        h2[tid] = fmaxf(s + rb2[tid], 0.f);
    }
    __syncthreads();
    if (tid == 0) {
        float s = 0.f;
        for (int i = 0; i < 32; ++i) s += h2[i] * rw3[i];
        out[b] = s + rb3[0];
    }
}

// ==================== launch ====================
extern "C" void kernel_launch(void* const* d_in, const int* in_sizes, int n_in,
                              void* d_out, int out_size, void* d_ws, size_t ws_size,
                              hipStream_t stream)
{
    const float* x   = (const float*)d_in[0];
    const float* ow1 = (const float*)d_in[1];  const float* ob1 = (const float*)d_in[2];
    const float* ow2 = (const float*)d_in[3];  const float* ob2 = (const float*)d_in[4];
    const float* ow3 = (const float*)d_in[5];  const float* ob3 = (const float*)d_in[6];
    const float* aw1 = (const float*)d_in[7];  const float* ab1 = (const float*)d_in[8];
    const float* aw2 = (const float*)d_in[9];  const float* ab2 = (const float*)d_in[10];
    const float* aw3 = (const float*)d_in[11]; const float* ab3 = (const float*)d_in[12];
    const float* hw1 = (const float*)d_in[13]; const float* hb1 = (const float*)d_in[14];
    const float* hw2 = (const float*)d_in[15]; const float* hb2 = (const float*)d_in[16];
    const float* hw3 = (const float*)d_in[17]; const float* hb3 = (const float*)d_in[18];
    const float* hw4 = (const float*)d_in[19]; const float* hb4 = (const float*)d_in[20];
    const float* wy  = (const float*)d_in[21];
    const float* fct = (const float*)d_in[22];
    const float* rw1 = (const float*)d_in[23]; const float* rb1 = (const float*)d_in[24];
    const float* rw2 = (const float*)d_in[25]; const float* rb2 = (const float*)d_in[26];
    const float* rw3 = (const float*)d_in[27]; const float* rb3 = (const float*)d_in[28];

    float* out  = (float*)d_out;
    float* yout = out + 32;                       // y_seq region
    float* ws   = (float*)d_ws;

    // ws layout (float offsets)
    float* OMEGA = ws;                            // 2,097,152
    float* ALPHA = ws + 2097152;                  // 2,097,152
    float* WT    = ws + 4194304;                  // 353,280
    float* PART  = ws + 4547584;                  // 3,276,800 (32*50*128*16)
    float* HZ0   = ws + 7824384;                  // 2,097,152
    float* HZ1   = ws + 9921536;                  // 2,097,152
    unsigned short* W2 = (unsigned short*)(ws + 12018688);  // 49,152 u16
    // total ~48.2 MB

    // encoder scratch slabs inside y region (overwritten by chunks covering
    // t >= 42, long after last encoder use)
    float* To1 = yout + 44 * YT;
    float* Ta1 = yout + 45 * YT;
    float* Th1 = yout + 46 * YT;
    float* To2 = yout + 47 * YT;
    float* Ta2 = yout + 43 * YT;
    float* Th2 = yout + 49 * YT;
    float* Th3 = yout + 42 * YT;
    float* HY0 = yout + 48 * YT;

    float* OW1T = WT + 0;      float* AW1T = WT + 3072;   float* HW1T = WT + 6144;
    float* OW2T = WT + 9216;   float* OW3T = WT + 58368;
    float* AW2T = WT + 107520; float* AW3T = WT + 156672;
    float* HW2T = WT + 205824; float* HW3T = WT + 254976; float* HW4T = WT + 304128;

    WSrc wsrc;
    wsrc.p[0] = ow1; wsrc.p[1] = aw1; wsrc.p[2] = hw1;
    wsrc.p[3] = ow2; wsrc.p[4] = ow3; wsrc.p[5] = aw2; wsrc.p[6] = aw3;
    wsrc.p[7] = hw2; wsrc.p[8] = hw3; wsrc.p[9] = hw4; wsrc.p[10] = wy;
    wprep_all_k<<<1572, 256, 0, stream>>>(wsrc, WT, W2);

    Jobs3 d1 = {{ {x, To1, OW1T, ob1, 4096, YB, 1},
                  {x, Ta1, AW1T, ab1, 4096, YB, 1},
                  {x, Th1, HW1T, hb1, 4096, YB, 1} }};
    conv8x3_k<<<dim3(8, 3, 32), 256, 0, stream>>>(d1);

    Jobs3 d2 = {{ {To1, To2, OW2T, ob2, YB, YB, 1},
                  {Ta1, Ta2, AW2T, ab2, YB, YB, 1},
                  {Th1, Th2, HW2T, hb2, YB, YB, 1} }};
    conv128x3_k<<<dim3(8, 6, 32), 256, 0, stream>>>(d2);

    Jobs3 d3 = {{ {To2, OMEGA, OW3T, ob3, YB, 65536, 1},
                  {Ta2, ALPHA, AW3T, ab3, YB, 65536, 1},
                  {Th2, Th3, HW3T, hb3, YB, YB, 1} }};
    conv128x3_k<<<dim3(8, 6, 32), 256, 0, stream>>>(d3);

    Jobs3 d4 = {{ {Th3, HY0, HW4T, hb4, YB, YB, 2},
                  {Th3, HY0, HW4T, hb4, YB, YB, 2},
                  {Th3, HY0, HW4T, hb4, YB, YB, 2} }};
    conv128x3_k<<<dim3(8, 2, 32), 256, 0, stream>>>(d4);

    // ---- recurrence: 10 chunk launches of 5 steps each
    for (int c = 0; c < 10; ++c) {
        int t0 = c * 5;
        const float* hyin = (c == 0) ? HY0 : (yout + (size_t)(t0 - 1) * YT);
        const float* hzin = (c & 1) ? HZ1 : HZ0;
        float* hzout      = (c & 1) ? HZ0 : HZ1;
        chunk_k<<<dim3(16, 32), 512, 0, stream>>>(hyin, hzin, hzout,
                                                  OMEGA, ALPHA, W2,
                                                  yout + (size_t)t0 * YT, PART, t0);
    }

    readout_k<<<32, 256, 0, stream>>>(PART, fct, rw1, rb1, rw2, rb2, rw3, rb3, out);
}

// Round 10
// 627.052 us; speedup vs baseline: 3.6062x; 1.1492x over previous
//
#include <hip/hip_runtime.h>
#include <math.h>

#define YB (50*128*512)   // y_seq batch stride (floats)
#define YT (128*512)      // y_seq time stride
#define DTc 0.5f

typedef __attribute__((ext_vector_type(8))) short bf16x8;
typedef __attribute__((ext_vector_type(4))) float f32x4;

__device__ __forceinline__ unsigned short f2bf(float f) {
    unsigned int u = __builtin_bit_cast(unsigned int, f);
    u += 0x7fffu + ((u >> 16) & 1u);          // RNE
    return (unsigned short)(u >> 16);
}

__device__ __forceinline__ float tanh_fast(float x) {
    float ax = fabsf(x);
    float e  = __expf(-2.f * ax);
    float r  = (1.f - e) * __builtin_amdgcn_rcpf(1.f + e);
    return __builtin_copysignf(r, x);
}

// raw block barrier: waits LDS ops only, lets global stores stay in flight
__device__ __forceinline__ void lds_sync() {
    asm volatile("s_waitcnt lgkmcnt(0)" ::: "memory");
    __builtin_amdgcn_sched_barrier(0);
    __builtin_amdgcn_s_barrier();
    __builtin_amdgcn_sched_barrier(0);
}

// ==================== fused weight prep ====================
// wt: [0,9216) conv8 transposes; [9216,205824) ow2,ow3,aw2,aw3 fp32 transposes.
// u16 region at wt+205824: 4x49152 bf16 kappa-format: wy, hw2, hw3, hw4.
struct WSrc { const float* p[11]; };  // ow1,aw1,hw1, ow2,ow3,aw2,aw3,hw2,hw3,hw4, wy
__global__ void wprep_all_k(WSrc s, float* __restrict__ wt) {
    int idx = blockIdx.x * 256 + threadIdx.x;
    if (idx < 9216) {
        int wsel = idx / 3072, r = idx % 3072;
        int row = r >> 7, co = r & 127;
        int ci = row / 3, k = row - ci * 3;
        wt[idx] = s.p[wsel][(co * 8 + ci) * 3 + k];
    } else if (idx < 205824) {
        int r = idx - 9216;
        int wsel = 3 + r / 49152, q = r % 49152;
        int row = q >> 7, co = q & 127;
        int ci = row / 3, k = row - ci * 3;
        wt[idx] = s.p[wsel][(co * 128 + ci) * 3 + k];
    } else if (idx < 402432) {
        int q = idx - 205824;
        int cv = q / 49152, r = q % 49152;
        int co = r / 384, kap = r % 384;
        int k = kap >> 7;
        int ci = ((kap >> 5) & 3) * 32 + (kap & 31);
        int sel = (cv == 0) ? 10 : 6 + cv;        // wy, hw2, hw3, hw4
        ((unsigned short*)(wt + 205824))[q] = f2bf(s.p[sel][(co * 128 + ci) * 3 + k]);
    }
}

// ==================== encoder convs (fp32, job-batched) ====================
struct Job { const float* src; float* dst; const float* wt; const float* bias; int sbs, dbs, act; };
struct Jobs3 { Job j[3]; };

__global__ __launch_bounds__(256) void conv8x3_k(Jobs3 js) {
    int jb = blockIdx.y % 3;
    Job jo = js.j[jb];
    int b = blockIdx.z, tile = blockIdx.x, tid = threadIdx.x;
    int l0 = tile * 64;
    int tl4 = (tid & 15) * 4;
    int co0 = (tid >> 4) * 8;
    __shared__ float xs[8 * 68];
    __shared__ float wsh[24 * 128];
    const float* sb = jo.src + (size_t)b * jo.sbs;
    for (int idx = tid; idx < 8 * 66; idx += 256) {
        int ci = idx / 66, ll = idx - ci * 66;
        int gl = l0 - 1 + ll;
        xs[ci * 68 + ll] = (gl >= 0 && gl < 512) ? sb[ci * 512 + gl] : 0.f;
    }
    for (int idx = tid; idx < 24 * 128; idx += 256) wsh[idx] = jo.wt[idx];
    __syncthreads();
    float acc[8][4] = {};
    #pragma unroll
    for (int ci = 0; ci < 8; ++ci) {
        float x6[6];
        #pragma unroll
        for (int j = 0; j < 6; ++j) x6[j] = xs[ci * 68 + tl4 + j];
        #pragma unroll
        for (int k = 0; k < 3; ++k) {
            float w8[8];
            #pragma unroll
            for (int i = 0; i < 8; ++i) w8[i] = wsh[(ci * 3 + k) * 128 + co0 + i];
            #pragma unroll
            for (int i = 0; i < 8; ++i)
                #pragma unroll
                for (int j = 0; j < 4; ++j)
                    acc[i][j] = fmaf(w8[i], x6[k + j], acc[i][j]);
        }
    }
    #pragma unroll
    for (int i = 0; i < 8; ++i) {
        int co = co0 + i;
        float bv = jo.bias[co];
        float4 o;
        o.x = fmaxf(acc[i][0] + bv, 0.f);
        o.y = fmaxf(acc[i][1] + bv, 0.f);
        o.z = fmaxf(acc[i][2] + bv, 0.f);
        o.w = fmaxf(acc[i][3] + bv, 0.f);
        *(float4*)(jo.dst + (size_t)b * jo.dbs + (size_t)co * 512 + l0 + tl4) = o;
    }
}

__global__ __launch_bounds__(256) void conv128x3_k(Jobs3 js) {
    int jb = blockIdx.y >> 1, cb = blockIdx.y & 1;
    Job jo = js.j[jb];
    int b = blockIdx.z, tile = blockIdx.x, tid = threadIdx.x;
    int l0 = tile * 64;
    int tl4 = (tid & 15) * 4;
    int col = (tid >> 4) * 4;
    __shared__ float xs[32 * 68];
    __shared__ float wsh[96 * 64];
    const float* sb = jo.src + (size_t)b * jo.sbs;
    float acc[4][4] = {};
    for (int chunk = 0; chunk < 4; ++chunk) {
        for (int idx = tid; idx < 32 * 66; idx += 256) {
            int ci = idx / 66, ll = idx - ci * 66;
            int gl = l0 - 1 + ll;
            xs[ci * 68 + ll] = (gl >= 0 && gl < 512) ? sb[(chunk * 32 + ci) * 512 + gl] : 0.f;
        }
        for (int idx = tid; idx < 96 * 16; idx += 256) {
            int row = idx >> 4, j = (idx & 15) * 4;
            *(float4*)(wsh + row * 64 + j) =
                *(const float4*)(jo.wt + (size_t)(chunk * 96 + row) * 128 + cb * 64 + j);
        }
        __syncthreads();
        #pragma unroll 4
        for (int ci = 0; ci < 32; ++ci) {
            float x6[6];
            #pragma unroll
            for (int j = 0; j < 6; ++j) x6[j] = xs[ci * 68 + tl4 + j];
            #pragma unroll
            for (int k = 0; k < 3; ++k) {
                float w4[4];
                #pragma unroll
                for (int i = 0; i < 4; ++i) w4[i] = wsh[(ci * 3 + k) * 64 + col + i];
                #pragma unroll
                for (int i = 0; i < 4; ++i)
                    #pragma unroll
                    for (int j = 0; j < 4; ++j)
                        acc[i][j] = fmaf(w4[i], x6[k + j], acc[i][j]);
            }
        }
        __syncthreads();
    }
    #pragma unroll
    for (int i = 0; i < 4; ++i) {
        int co = cb * 64 + col + i;
        float bv = jo.bias[co];
        float v[4];
        #pragma unroll
        for (int j = 0; j < 4; ++j) {
            float tv = acc[i][j] + bv;
            if (jo.act == 1) tv = fmaxf(tv, 0.f);
            else if (jo.act == 2) tv = tanhf(tv);
            v[j] = tv;
        }
        *(float4*)(jo.dst + (size_t)b * jo.dbs + (size_t)co * 512 + l0 + tl4) = *(float4*)v;
    }
}

// ==================== bf16-MFMA conv128 (hy chain) ====================
// fp32 [b][ci][l] -> stage/pack bf16 -> MFMA (zero-pad SAME) -> act -> fp32 [b][co][l]
__global__ __launch_bounds__(512) void mconv_k(
    const float* __restrict__ src, int sbs,
    float* __restrict__ dst, int dbs,
    const unsigned short* __restrict__ w2,     // [co][384] bf16 kappa-format
    const float* __restrict__ bias, int act)   // 1 relu, 2 tanh
{
    int tile = blockIdx.x, b = blockIdx.y;
    int tid = threadIdx.x, lane = tid & 63, wid = tid >> 6;
    int lr = lane & 15, kg = lane >> 4;
    int co = wid * 16 + lr;
    int l0 = tile * 32;

    __shared__ float stage[128 * 40];      // cols <-> l0-4 .. l0+35
    __shared__ uint4 hyX[34 * 16];         // row h <-> l0-1+h, [row][chunk ^ (h&7)]

    bf16x8 Bw[12];
    {
        const bf16x8* wp = (const bf16x8*)(w2 + (size_t)co * 384);
        #pragma unroll
        for (int s = 0; s < 12; ++s) Bw[s] = wp[s * 4 + kg];
    }

    const float* sb = src + (size_t)b * sbs;
    for (int i = tid; i < 1280; i += 512) {
        int c = i / 10, p4 = (i - c * 10) * 4;
        int l = l0 - 4 + p4;
        f32x4 v;
        if (l >= 0 && l <= 508) {
            v = *(const f32x4*)(sb + (size_t)c * 512 + l);
        } else {
            #pragma unroll
            for (int e = 0; e < 4; ++e) {
                int le = l + e;
                v[e] = (le >= 0 && le < 512) ? sb[(size_t)c * 512 + le] : 0.f;
            }
        }
        *(f32x4*)(stage + c * 40 + p4) = v;
    }
    __syncthreads();
    for (int i = tid; i < 34 * 16; i += 512) {
        int h = i >> 4, c8 = i & 15;
        unsigned short pk[8];
        #pragma unroll
        for (int q = 0; q < 8; ++q) pk[q] = f2bf(stage[(c8 * 8 + q) * 40 + h + 3]);
        hyX[h * 16 + (c8 ^ (h & 7))] = *(uint4*)pk;
    }
    __syncthreads();

    f32x4 acc[2];
    acc[0] = (f32x4){0.f, 0.f, 0.f, 0.f};
    acc[1] = (f32x4){0.f, 0.f, 0.f, 0.f};
    __builtin_amdgcn_s_setprio(1);
    #pragma unroll
    for (int s = 0; s < 12; ++s) {
        int k = s >> 2;
        int chunk = (s & 3) * 4 + kg;
        bf16x8 Bf = Bw[s];
        #pragma unroll
        for (int lt = 0; lt < 2; ++lt) {
            int arow = 16 * lt + lr + k;
            bf16x8 a = __builtin_bit_cast(bf16x8, hyX[arow * 16 + ((arow & 7) ^ chunk)]);
            acc[lt] = __builtin_amdgcn_mfma_f32_16x16x32_bf16(a, Bf, acc[lt], 0, 0, 0);
        }
    }
    __builtin_amdgcn_s_setprio(0);

    float bv = bias[co];
    #pragma unroll
    for (int lt = 0; lt < 2; ++lt) {
        float v[4];
        #pragma unroll
        for (int j = 0; j < 4; ++j) {
            float t = acc[lt][j] + bv;
            v[j] = (act == 1) ? fmaxf(t, 0.f) : tanh_fast(t);
        }
        *(f32x4*)(dst + (size_t)b * dbs + (size_t)co * 512 + l0 + 16 * lt + 4 * kg) = *(f32x4*)v;
    }
}

// ==================== ns-step chunk kernel ====================
// 512 blocks (16 l-tiles of center 32 x 32 b), 512 threads, 2 blocks/CU.
// hyS double-buffered + y-temp double-buffered -> ONE lds_sync per step.
// omega/alpha/hz loaded DIRECT from global. Shrinking halo: staged rows
// l0-8..l0+39; valid after step i = [i+1,46-i] >= center for i<=7 -> ns<=8.
__global__ __launch_bounds__(512, 2) void chunk_k(
    const float* __restrict__ hy_in,   // [b][co][l], b-stride YB
    const float* __restrict__ hz_in,   // [b][co][l], b-stride 65536
    float* __restrict__ hz_out,
    const float* __restrict__ omega, const float* __restrict__ alpha,
    const unsigned short* __restrict__ w2,
    float* __restrict__ ybase,         // slab t0 base
    float* __restrict__ part, int t0, int ns)
{
    int tile = blockIdx.x, b = blockIdx.y;
    int tid = threadIdx.x, lane = tid & 63, wid = tid >> 6;
    int lr = lane & 15, kg = lane >> 4;
    int co = wid * 16 + lr;
    int l0 = tile * 32;

    __shared__ uint4 hySd[2][800];         // [buf][row h 0..49][chunk ^ (h&7)]
    __shared__ float ytmp[2 * 4608];       // [buf][co][36]; prologue aliases as stage[128][56]
    float* stage = ytmp;

    bf16x8 Bw[12];
    {
        const bf16x8* wp = (const bf16x8*)(w2 + (size_t)co * 384);
        #pragma unroll
        for (int s = 0; s < 12; ++s) Bw[s] = wp[s * 4 + kg];
    }

    f32x4 hyR[3], hzR[3], omR[3], alR[3];

    // ---- prologue: coalesced hy stage (cols 0..55 <-> l0-12 .. l0+43)
    {
        const float* src = hy_in + (size_t)b * YB;
        for (int i = tid; i < 128 * 14; i += 512) {
            int c = i / 14, p4 = (i - c * 14) * 4;
            int l = (l0 - 12 + p4) & 511;
            *(f32x4*)(stage + c * 56 + p4) = *(const f32x4*)(src + (size_t)c * 512 + l);
        }
    }
    __syncthreads();
    #pragma unroll
    for (int lt = 0; lt < 3; ++lt)
        hyR[lt] = *(const f32x4*)(stage + co * 56 + 16 * lt + 4 * kg + 4);
    for (int i = tid; i < 50 * 16; i += 512) {
        int h = i >> 4, c8 = i & 15;
        unsigned short pk[8];
        #pragma unroll
        for (int q = 0; q < 8; ++q) pk[q] = f2bf(stage[(c8 * 8 + q) * 56 + h + 3]);
        hySd[0][h * 16 + (c8 ^ (h & 7))] = *(uint4*)pk;
    }
    // direct global loads: omega/alpha/hz (thread's own state rows)
    {
        size_t ob = (size_t)b * 65536 + (size_t)co * 512;
        #pragma unroll
        for (int lt = 0; lt < 3; ++lt) {
            int l = (l0 - 8 + 16 * lt + 4 * kg) & 511;
            omR[lt] = *(const f32x4*)(omega + ob + l);
            alR[lt] = *(const f32x4*)(alpha + ob + l);
            if (t0 > 0) hzR[lt] = *(const f32x4*)(hz_in + ob + l);
            else        hzR[lt] = (f32x4){0.f, 0.f, 0.f, 0.f};
        }
    }
    __syncthreads();   // hyS[0] visible; stage reads done before loop overwrites ytmp

    // ---- ns steps, ONE lds_sync each
    for (int i = 0; i < ns; ++i) {
        const uint4* hc = &hySd[i & 1][0];
        unsigned short* hn16 = (unsigned short*)&hySd[(i + 1) & 1][0];
        float* yt = ytmp + (i & 1) * 4608;

        f32x4 acc[3];
        #pragma unroll
        for (int lt = 0; lt < 3; ++lt) acc[lt] = (f32x4){0.f, 0.f, 0.f, 0.f};
        __builtin_amdgcn_s_setprio(1);
        #pragma unroll
        for (int s = 0; s < 12; ++s) {
            int chunk = (s & 3) * 4 + kg;
            int k = s >> 2;
            bf16x8 Bf = Bw[s];
            #pragma unroll
            for (int lt = 0; lt < 3; ++lt) {
                int arow = 16 * lt + lr + k;
                bf16x8 a = __builtin_bit_cast(bf16x8, hc[arow * 16 + ((arow & 7) ^ chunk)]);
                acc[lt] = __builtin_amdgcn_mfma_f32_16x16x32_bf16(a, Bf, acc[lt], 0, 0, 0);
            }
        }
        __builtin_amdgcn_s_setprio(0);

        float lsum = 0.f;
        #pragma unroll
        for (int lt = 0; lt < 3; ++lt) {
            #pragma unroll
            for (int j = 0; j < 4; ++j) {
                float spring = tanh_fast(acc[lt][j]);
                float zn = hzR[lt][j] + DTc * (spring - omR[lt][j] * hyR[lt][j] - alR[lt][j] * hzR[lt][j]);
                float hn = hyR[lt][j] + DTc * zn;
                hzR[lt][j] = zn;
                hyR[lt][j] = hn;
            }
            bool valid = (lt == 0) ? (kg >= 2) : (lt == 2) ? (kg < 2) : true;
            int r0 = 16 * lt + 4 * kg;
            if (valid) {
                *(f32x4*)(yt + co * 36 + (r0 - 8)) = hyR[lt];
                lsum += hyR[lt][0] + hyR[lt][1] + hyR[lt][2] + hyR[lt][3];
                if (i == ns - 1)
                    *(f32x4*)(hz_out + (size_t)b * 65536 + (size_t)co * 512 + l0 + (r0 - 8)) = hzR[lt];
            }
            if (i < ns - 1) {
                #pragma unroll
                for (int j = 0; j < 4; ++j) {
                    int rr = r0 + j + 1;
                    int sidx = rr * 128 + (((co >> 3) ^ (rr & 7)) << 3) + (co & 7);
                    hn16[sidx] = f2bf(hyR[lt][j]);
                }
            }
        }
        lsum += __shfl_xor(lsum, 16);
        lsum += __shfl_xor(lsum, 32);
        if (kg == 0) part[(((size_t)b * 50 + t0 + i) * 128 + co) * 16 + tile] = lsum;

        lds_sync();   // hyS[nxt] + yt writes visible; prior yt reads drained

        // coalesced y store from yt (128B runs)
        {
            float* yrow = ybase + (size_t)b * YB + (size_t)i * YT;
            int cs = wid * 16 + (lane >> 3);
            int lq = (lane & 7) * 4;
            #pragma unroll
            for (int cq = 0; cq < 2; ++cq) {
                int c2 = cs + cq * 8;
                f32x4 v = *(const f32x4*)(yt + c2 * 36 + lq);
                *(f32x4*)(yrow + (size_t)c2 * 512 + l0 + lq) = v;
            }
        }
    }
}

// ==================== readout ====================
__global__ __launch_bounds__(256) void readout_k(
    const float* __restrict__ part, const float* __restrict__ fct,
    const float* __restrict__ rw1, const float* __restrict__ rb1,
    const float* __restrict__ rw2, const float* __restrict__ rb2,
    const float* __restrict__ rw3, const float* __restrict__ rb3,
    float* __restrict__ out)
{
    int b = blockIdx.x, tid = threadIdx.x;
    __shared__ float ybar[50 * 128];
    __shared__ float feat[26 * 128];
    __shared__ float h1[64];
    __shared__ float h2[32];
    for (int idx = tid; idx < 50 * 128; idx += 256) {
        const float* p = part + ((size_t)b * 6400 + idx) * 16;
        float s = 0.f;
        #pragma unroll
        for (int q = 0; q < 16; ++q) s += p[q];
        ybar[idx] = s * (1.f / 512.f);
    }
    __syncthreads();
    for (int idx = tid; idx < 26 * 128; idx += 256) {
        int k = idx >> 7, c = idx & 127;
        float s = 0.f;
        for (int t = 0; t < 50; ++t) s += fct[k * 50 + t] * ybar[t * 128 + c];
        feat[idx] = s;
    }
    __syncthreads();
    {
        int j = tid >> 2, q = tid & 3;
        float s = 0.f;
        const float* r = rw1 + (size_t)j * 3328 + q * 832;
        const float* f = feat + q * 832;
        for (int i = 0; i < 832; ++i) s += f[i] * r[i];
        s += __shfl_xor(s, 1);
        s += __shfl_xor(s, 2);
        if (q == 0) h1[j] = fmaxf(s + rb1[j], 0.f);
    }
    __syncthreads();
    if (tid < 32) {
        float s = 0.f;
        for (int i = 0; i < 64; ++i) s += h1[i] * rw2[tid * 64 + i];
        h2[tid] = fmaxf(s + rb2[tid], 0.f);
    }
    __syncthreads();
    if (tid == 0) {
        float s = 0.f;
        for (int i = 0; i < 32; ++i) s += h2[i] * rw3[i];
        out[b] = s + rb3[0];
    }
}

// ==================== launch ====================
extern "C" void kernel_launch(void* const* d_in, const int* in_sizes, int n_in,
                              void* d_out, int out_size, void* d_ws, size_t ws_size,
                              hipStream_t stream)
{
    const float* x   = (const float*)d_in[0];
    const float* ow1 = (const float*)d_in[1];  const float* ob1 = (const float*)d_in[2];
    const float* ow2 = (const float*)d_in[3];  const float* ob2 = (const float*)d_in[4];
    const float* ow3 = (const float*)d_in[5];  const float* ob3 = (const float*)d_in[6];
    const float* aw1 = (const float*)d_in[7];  const float* ab1 = (const float*)d_in[8];
    const float* aw2 = (const float*)d_in[9];  const float* ab2 = (const float*)d_in[10];
    const float* aw3 = (const float*)d_in[11]; const float* ab3 = (const float*)d_in[12];
    const float* hw1 = (const float*)d_in[13]; const float* hb1 = (const float*)d_in[14];
    const float* hw2 = (const float*)d_in[15]; const float* hb2 = (const float*)d_in[16];
    const float* hw3 = (const float*)d_in[17]; const float* hb3 = (const float*)d_in[18];
    const float* hw4 = (const float*)d_in[19]; const float* hb4 = (const float*)d_in[20];
    const float* wy  = (const float*)d_in[21];
    const float* fct = (const float*)d_in[22];
    const float* rw1 = (const float*)d_in[23]; const float* rb1 = (const float*)d_in[24];
    const float* rw2 = (const float*)d_in[25]; const float* rb2 = (const float*)d_in[26];
    const float* rw3 = (const float*)d_in[27]; const float* rb3 = (const float*)d_in[28];

    float* out  = (float*)d_out;
    float* yout = out + 32;                       // y_seq region
    float* ws   = (float*)d_ws;

    // ws layout (float offsets)
    float* OMEGA = ws;                            // 2,097,152
    float* ALPHA = ws + 2097152;                  // 2,097,152
    float* WT    = ws + 4194304;                  // 353,280 (fp32 transposes + u16 W2 region)
    float* PART  = ws + 4547584;                  // 3,276,800 (32*50*128*16)
    float* HZ0   = ws + 7824384;                  // 2,097,152
    float* HZ1   = ws + 9921536;                  // 2,097,152  (end 12,018,688 ~48.1 MB)

    // encoder scratch slabs inside y region (overwritten by chunks covering
    // t >= 42, long after last encoder use)
    float* To1 = yout + 44 * YT;
    float* Ta1 = yout + 45 * YT;
    float* Th1 = yout + 46 * YT;
    float* To2 = yout + 47 * YT;
    float* Ta2 = yout + 43 * YT;
    float* Th2 = yout + 49 * YT;
    float* Th3 = yout + 42 * YT;
    float* HY0 = yout + 48 * YT;

    float* OW1T = WT + 0;      float* AW1T = WT + 3072;   float* HW1T = WT + 6144;
    float* OW2T = WT + 9216;   float* OW3T = WT + 58368;
    float* AW2T = WT + 107520; float* AW3T = WT + 156672;
    unsigned short* W2WY = (unsigned short*)(WT + 205824);
    unsigned short* W2H2 = W2WY + 49152;
    unsigned short* W2H3 = W2WY + 98304;
    unsigned short* W2H4 = W2WY + 147456;

    WSrc wsrc;
    wsrc.p[0] = ow1; wsrc.p[1] = aw1; wsrc.p[2] = hw1;
    wsrc.p[3] = ow2; wsrc.p[4] = ow3; wsrc.p[5] = aw2; wsrc.p[6] = aw3;
    wsrc.p[7] = hw2; wsrc.p[8] = hw3; wsrc.p[9] = hw4; wsrc.p[10] = wy;
    wprep_all_k<<<1572, 256, 0, stream>>>(wsrc, WT);

    // layer 1 (fp32): all three encoders
    Jobs3 d1 = {{ {x, To1, OW1T, ob1, 4096, YB, 1},
                  {x, Ta1, AW1T, ab1, 4096, YB, 1},
                  {x, Th1, HW1T, hb1, 4096, YB, 1} }};
    conv8x3_k<<<dim3(8, 3, 32), 256, 0, stream>>>(d1);

    // omega/alpha layers 2-3 (fp32)
    Jobs3 d2 = {{ {To1, To2, OW2T, ob2, YB, YB, 1},
                  {Ta1, Ta2, AW2T, ab2, YB, YB, 1},
                  {To1, To2, OW2T, ob2, YB, YB, 1} }};
    conv128x3_k<<<dim3(8, 4, 32), 256, 0, stream>>>(d2);

    Jobs3 d3 = {{ {To2, OMEGA, OW3T, ob3, YB, 65536, 1},
                  {Ta2, ALPHA, AW3T, ab3, YB, 65536, 1},
                  {To2, OMEGA, OW3T, ob3, YB, 65536, 1} }};
    conv128x3_k<<<dim3(8, 4, 32), 256, 0, stream>>>(d3);

    // hy chain layers 2-4 (bf16 MFMA)
    mconv_k<<<dim3(16, 32), 512, 0, stream>>>(Th1, YB, Th2, YB, W2H2, hb2, 1);
    mconv_k<<<dim3(16, 32), 512, 0, stream>>>(Th2, YB, Th3, YB, W2H3, hb3, 1);
    mconv_k<<<dim3(16, 32), 512, 0, stream>>>(Th3, YB, HY0, YB, W2H4, hb4, 2);

    // ---- recurrence: 8-step chunks (8,8,8,8,8,8,2)
    {
        int t0 = 0, c = 0;
        while (t0 < 50) {
            int ns = (50 - t0 >= 8) ? 8 : (50 - t0);
            const float* hyin = (t0 == 0) ? HY0 : (yout + (size_t)(t0 - 1) * YT);
            const float* hzin = (c & 1) ? HZ1 : HZ0;
            float* hzout      = (c & 1) ? HZ0 : HZ1;
            chunk_k<<<dim3(16, 32), 512, 0, stream>>>(hyin, hzin, hzout,
                                                      OMEGA, ALPHA, W2WY,
                                                      yout + (size_t)t0 * YT, PART, t0, ns);
            t0 += ns; ++c;
        }
    }

    readout_k<<<32, 256, 0, stream>>>(PART, fct, rw1, rb1, rw2, rb2, rw3, rb3, out);
}

// Round 11
// 546.229 us; speedup vs baseline: 4.1398x; 1.1480x over previous
//
#include <hip/hip_runtime.h>
#include <math.h>

#define YB (50*128*512)   // y_seq batch stride (floats)
#define YT (128*512)      // y_seq time stride
#define DTc 0.5f

typedef __attribute__((ext_vector_type(8))) short bf16x8;
typedef __attribute__((ext_vector_type(4))) float f32x4;

__device__ __forceinline__ unsigned short f2bf(float f) {
    unsigned int u = __builtin_bit_cast(unsigned int, f);
    u += 0x7fffu + ((u >> 16) & 1u);          // RNE
    return (unsigned short)(u >> 16);
}
__device__ __forceinline__ float bf2f(unsigned short h) {
    unsigned int u = ((unsigned int)h) << 16;
    return __builtin_bit_cast(float, u);
}

__device__ __forceinline__ float tanh_fast(float x) {
    float ax = fabsf(x);
    float e  = __expf(-2.f * ax);
    float r  = (1.f - e) * __builtin_amdgcn_rcpf(1.f + e);
    return __builtin_copysignf(r, x);
}

// raw block barrier: waits LDS ops only, lets global stores stay in flight
__device__ __forceinline__ void lds_sync() {
    asm volatile("s_waitcnt lgkmcnt(0)" ::: "memory");
    __builtin_amdgcn_sched_barrier(0);
    __builtin_amdgcn_s_barrier();
    __builtin_amdgcn_sched_barrier(0);
}

// ==================== fused weight prep ====================
// wt floats: [0,9216) conv8 transposes.
// u16 region at wt+9216: 12 x 49152 kappa-format bf16 sets:
//   0 wy, 1 hw2, 2 hw3, 3 hw4, 4 ow2h,5 ow2l, 6 ow3h,7 ow3l, 8 aw2h,9 aw2l, 10 aw3h,11 aw3l
struct WSrc { const float* p[11]; };  // ow1,aw1,hw1, ow2,ow3,aw2,aw3,hw2,hw3,hw4, wy
__global__ void wprep_all_k(WSrc s, float* __restrict__ wt) {
    int idx = blockIdx.x * 256 + threadIdx.x;
    if (idx < 9216) {
        int wsel = idx / 3072, r = idx % 3072;
        int row = r >> 7, co = r & 127;
        int ci = row / 3, k = row - ci * 3;
        wt[idx] = s.p[wsel][(co * 8 + ci) * 3 + k];
    } else if (idx < 9216 + 589824) {
        int q = idx - 9216;
        int cv = q / 49152, r = q % 49152;
        int co = r / 384, kap = r % 384;
        int k = kap >> 7;
        int ci = ((kap >> 5) & 3) * 32 + (kap & 31);
        const int selmap[12] = {10, 7, 8, 9, 3, 3, 4, 4, 5, 5, 6, 6};
        float w = s.p[selmap[cv]][(co * 128 + ci) * 3 + k];
        unsigned short hv = f2bf(w);
        unsigned short ov = ((cv >= 4) && (cv & 1)) ? f2bf(w - bf2f(hv)) : hv;
        ((unsigned short*)(wt + 9216))[q] = ov;
    }
}

// ==================== conv8 layer (fp32, 3 jobs) ====================
struct Job { const float* src; float* dst; const float* wt; const float* bias; int sbs, dbs, act; };
struct Jobs3 { Job j[3]; };

__global__ __launch_bounds__(256) void conv8x3_k(Jobs3 js) {
    int jb = blockIdx.y % 3;
    Job jo = js.j[jb];
    int b = blockIdx.z, tile = blockIdx.x, tid = threadIdx.x;
    int l0 = tile * 64;
    int tl4 = (tid & 15) * 4;
    int co0 = (tid >> 4) * 8;
    __shared__ float xs[8 * 68];
    __shared__ float wsh[24 * 128];
    const float* sb = jo.src + (size_t)b * jo.sbs;
    for (int idx = tid; idx < 8 * 66; idx += 256) {
        int ci = idx / 66, ll = idx - ci * 66;
        int gl = l0 - 1 + ll;
        xs[ci * 68 + ll] = (gl >= 0 && gl < 512) ? sb[ci * 512 + gl] : 0.f;
    }
    for (int idx = tid; idx < 24 * 128; idx += 256) wsh[idx] = jo.wt[idx];
    __syncthreads();
    float acc[8][4] = {};
    #pragma unroll
    for (int ci = 0; ci < 8; ++ci) {
        float x6[6];
        #pragma unroll
        for (int j = 0; j < 6; ++j) x6[j] = xs[ci * 68 + tl4 + j];
        #pragma unroll
        for (int k = 0; k < 3; ++k) {
            float w8[8];
            #pragma unroll
            for (int i = 0; i < 8; ++i) w8[i] = wsh[(ci * 3 + k) * 128 + co0 + i];
            #pragma unroll
            for (int i = 0; i < 8; ++i)
                #pragma unroll
                for (int j = 0; j < 4; ++j)
                    acc[i][j] = fmaf(w8[i], x6[k + j], acc[i][j]);
        }
    }
    #pragma unroll
    for (int i = 0; i < 8; ++i) {
        int co = co0 + i;
        float bv = jo.bias[co];
        float4 o;
        o.x = fmaxf(acc[i][0] + bv, 0.f);
        o.y = fmaxf(acc[i][1] + bv, 0.f);
        o.z = fmaxf(acc[i][2] + bv, 0.f);
        o.w = fmaxf(acc[i][3] + bv, 0.f);
        *(float4*)(jo.dst + (size_t)b * jo.dbs + (size_t)co * 512 + l0 + tl4) = o;
    }
}

// ==================== bf16-MFMA conv128 (hy chain) ====================
// fp32 [b][ci][l] -> pack bf16 -> MFMA (zero-pad SAME) -> act -> fp32 [b][co][l]
// If hyt != null, also emits bf16 transposed output [b][l][c8] (uint4 granularity).
__global__ __launch_bounds__(512) void mconv_k(
    const float* __restrict__ src, int sbs,
    float* __restrict__ dst, int dbs,
    const unsigned short* __restrict__ w2,     // [co][384] bf16 kappa-format
    const float* __restrict__ bias, int act,   // 1 relu, 2 tanh
    unsigned short* __restrict__ hyt)
{
    int tile = blockIdx.x, b = blockIdx.y;
    int tid = threadIdx.x, lane = tid & 63, wid = tid >> 6;
    int lr = lane & 15, kg = lane >> 4;
    int co = wid * 16 + lr;
    int l0 = tile * 32;

    __shared__ float stage[128 * 40];      // cols <-> l0-4 .. l0+35
    __shared__ uint4 hyX[34 * 16];         // row h <-> l0-1+h, [row][chunk ^ (h&7)]

    bf16x8 Bw[12];
    {
        const bf16x8* wp = (const bf16x8*)(w2 + (size_t)co * 384);
        #pragma unroll
        for (int s = 0; s < 12; ++s) Bw[s] = wp[s * 4 + kg];
    }

    const float* sb = src + (size_t)b * sbs;
    for (int i = tid; i < 1280; i += 512) {
        int c = i / 10, p4 = (i - c * 10) * 4;
        int l = l0 - 4 + p4;
        f32x4 v;
        if (l >= 0 && l <= 508) {
            v = *(const f32x4*)(sb + (size_t)c * 512 + l);
        } else {
            #pragma unroll
            for (int e = 0; e < 4; ++e) {
                int le = l + e;
                v[e] = (le >= 0 && le < 512) ? sb[(size_t)c * 512 + le] : 0.f;
            }
        }
        *(f32x4*)(stage + c * 40 + p4) = v;
    }
    __syncthreads();
    for (int i = tid; i < 34 * 16; i += 512) {
        int h = i >> 4, c8 = i & 15;
        unsigned short pk[8];
        #pragma unroll
        for (int q = 0; q < 8; ++q) pk[q] = f2bf(stage[(c8 * 8 + q) * 40 + h + 3]);
        hyX[h * 16 + (c8 ^ (h & 7))] = *(uint4*)pk;
    }
    __syncthreads();

    f32x4 acc[2];
    acc[0] = (f32x4){0.f, 0.f, 0.f, 0.f};
    acc[1] = (f32x4){0.f, 0.f, 0.f, 0.f};
    __builtin_amdgcn_s_setprio(1);
    #pragma unroll
    for (int s = 0; s < 12; ++s) {
        int k = s >> 2;
        int chunk = (s & 3) * 4 + kg;
        bf16x8 Bf = Bw[s];
        #pragma unroll
        for (int lt = 0; lt < 2; ++lt) {
            int arow = 16 * lt + lr + k;
            bf16x8 a = __builtin_bit_cast(bf16x8, hyX[arow * 16 + ((arow & 7) ^ chunk)]);
            acc[lt] = __builtin_amdgcn_mfma_f32_16x16x32_bf16(a, Bf, acc[lt], 0, 0, 0);
        }
    }
    __builtin_amdgcn_s_setprio(0);

    float bv = bias[co];
    float vv[2][4];
    #pragma unroll
    for (int lt = 0; lt < 2; ++lt) {
        #pragma unroll
        for (int j = 0; j < 4; ++j) {
            float t = acc[lt][j] + bv;
            vv[lt][j] = (act == 1) ? fmaxf(t, 0.f) : tanh_fast(t);
        }
        *(f32x4*)(dst + (size_t)b * dbs + (size_t)co * 512 + l0 + 16 * lt + 4 * kg) = *(f32x4*)vv[lt];
    }

    if (hyt) {
        lds_sync();                       // all hyX MFMA reads complete
        unsigned short* t16 = (unsigned short*)hyX;
        #pragma unroll
        for (int lt = 0; lt < 2; ++lt)
            #pragma unroll
            for (int j = 0; j < 4; ++j)
                t16[(16 * lt + 4 * kg + j) * 128 + co] = f2bf(vv[lt][j]);
        lds_sync();
        int row = tid >> 4, c8 = tid & 15;    // tid < 512 -> row < 32
        ((uint4*)hyt)[((size_t)b * 512 + l0 + row) * 16 + c8] =
            ((uint4*)hyX)[row * 16 + c8];
    }
}

// ==================== split-bf16 MFMA conv128 (omega/alpha chains) ====================
// x = xh+xl, w = wh+wl (bf16 each); acc = xh*wh + xl*wh + xh*wl  (~1e-5 rel. error)
struct MJob { const float* src; float* dst; const unsigned short* whi;
              const unsigned short* wlo; const float* bias; int sbs, dbs; };
struct MJobs2 { MJob j[2]; };

__global__ __launch_bounds__(512) void mconv2_k(MJobs2 js) {
    MJob jo = js.j[blockIdx.z];
    int tile = blockIdx.x, b = blockIdx.y;
    int tid = threadIdx.x, lane = tid & 63, wid = tid >> 6;
    int lr = lane & 15, kg = lane >> 4;
    int co = wid * 16 + lr;
    int l0 = tile * 32;

    __shared__ float stage[128 * 40];
    __shared__ uint4 hiX[34 * 16];
    __shared__ uint4 loX[34 * 16];

    const bf16x8* wph = (const bf16x8*)(jo.whi + (size_t)co * 384);
    const bf16x8* wpl = (const bf16x8*)(jo.wlo + (size_t)co * 384);
    bf16x8 Bh[12];
    #pragma unroll
    for (int s = 0; s < 12; ++s) Bh[s] = wph[s * 4 + kg];

    const float* sb = jo.src + (size_t)b * jo.sbs;
    for (int i = tid; i < 1280; i += 512) {
        int c = i / 10, p4 = (i - c * 10) * 4;
        int l = l0 - 4 + p4;
        f32x4 v;
        if (l >= 0 && l <= 508) {
            v = *(const f32x4*)(sb + (size_t)c * 512 + l);
        } else {
            #pragma unroll
            for (int e = 0; e < 4; ++e) {
                int le = l + e;
                v[e] = (le >= 0 && le < 512) ? sb[(size_t)c * 512 + le] : 0.f;
            }
        }
        *(f32x4*)(stage + c * 40 + p4) = v;
    }
    __syncthreads();
    for (int i = tid; i < 34 * 16; i += 512) {
        int h = i >> 4, c8 = i & 15;
        unsigned short ph[8], pl[8];
        #pragma unroll
        for (int q = 0; q < 8; ++q) {
            float x = stage[(c8 * 8 + q) * 40 + h + 3];
            unsigned short hv = f2bf(x);
            ph[q] = hv;
            pl[q] = f2bf(x - bf2f(hv));
        }
        int sx = h * 16 + (c8 ^ (h & 7));
        hiX[sx] = *(uint4*)ph;
        loX[sx] = *(uint4*)pl;
    }
    __syncthreads();

    f32x4 acc[2];
    acc[0] = (f32x4){0.f, 0.f, 0.f, 0.f};
    acc[1] = (f32x4){0.f, 0.f, 0.f, 0.f};
    bf16x8 blc = wpl[kg];                        // prefetch s=0 lo-weights
    __builtin_amdgcn_s_setprio(1);
    #pragma unroll
    for (int s = 0; s < 12; ++s) {
        bf16x8 Bl = blc;
        if (s < 11) blc = wpl[(s + 1) * 4 + kg];
        int k = s >> 2;
        int chunk = (s & 3) * 4 + kg;
        #pragma unroll
        for (int lt = 0; lt < 2; ++lt) {
            int arow = 16 * lt + lr + k;
            int ai = arow * 16 + ((arow & 7) ^ chunk);
            bf16x8 ah = __builtin_bit_cast(bf16x8, hiX[ai]);
            bf16x8 al = __builtin_bit_cast(bf16x8, loX[ai]);
            acc[lt] = __builtin_amdgcn_mfma_f32_16x16x32_bf16(ah, Bh[s], acc[lt], 0, 0, 0);
            acc[lt] = __builtin_amdgcn_mfma_f32_16x16x32_bf16(al, Bh[s], acc[lt], 0, 0, 0);
            acc[lt] = __builtin_amdgcn_mfma_f32_16x16x32_bf16(ah, Bl,    acc[lt], 0, 0, 0);
        }
    }
    __builtin_amdgcn_s_setprio(0);

    float bv = jo.bias[co];
    #pragma unroll
    for (int lt = 0; lt < 2; ++lt) {
        float v[4];
        #pragma unroll
        for (int j = 0; j < 4; ++j) v[j] = fmaxf(acc[lt][j] + bv, 0.f);
        *(f32x4*)(jo.dst + (size_t)b * jo.dbs + (size_t)co * 512 + l0 + 16 * lt + 4 * kg) = *(f32x4*)v;
    }
}

// ==================== ns-step chunk kernel ====================
// 512 blocks (16 l-tiles of center 32 x 32 b), 512 threads, 2 blocks/CU.
// hy enters/leaves as packed bf16 HYT [b][l][c8] (ping-pong across chunks):
// prologue = ONE coalesced uint4 load pass + one barrier. hyR fp32 from y slab.
// hyS + y-temp double-buffered -> ONE lds_sync per step. Shrinking halo: ns<=8.
__global__ __launch_bounds__(512, 2) void chunk_k(
    const unsigned short* __restrict__ hyt_in,   // [b][512][16] uint4 bf16
    unsigned short* __restrict__ hyt_out,
    const float* __restrict__ hy_in,   // fp32 [b][co][l], b-stride YB (y slab t0-1 / HY0)
    const float* __restrict__ hz_in,   // [b][co][l], b-stride 65536
    float* __restrict__ hz_out,
    const float* __restrict__ omega, const float* __restrict__ alpha,
    const unsigned short* __restrict__ w2,
    float* __restrict__ ybase,         // slab t0 base
    float* __restrict__ part, int t0, int ns)
{
    int tile = blockIdx.x, b = blockIdx.y;
    int tid = threadIdx.x, lane = tid & 63, wid = tid >> 6;
    int lr = lane & 15, kg = lane >> 4;
    int co = wid * 16 + lr;
    int l0 = tile * 32;

    __shared__ uint4 hySd[2][800];         // [buf][row h 0..49][chunk ^ (h&7)]
    __shared__ float ytmp[2 * 4608];       // [buf][co][36]

    bf16x8 Bw[12];
    {
        const bf16x8* wp = (const bf16x8*)(w2 + (size_t)co * 384);
        #pragma unroll
        for (int s = 0; s < 12; ++s) Bw[s] = wp[s * 4 + kg];
    }

    f32x4 hyR[3], hzR[3], omR[3], alR[3];

    // ---- prologue: hySd[0] from HYT (coalesced), hyR/om/al/hz direct
    {
        const uint4* hsrc = (const uint4*)hyt_in + (size_t)b * 8192;
        for (int i = tid; i < 800; i += 512) {
            int h = i >> 4, c8 = i & 15;
            int l = (l0 - 9 + h) & 511;
            hySd[0][h * 16 + (c8 ^ (h & 7))] = hsrc[l * 16 + c8];
        }
    }
    {
        const float* src = hy_in + (size_t)b * YB;
        size_t ob = (size_t)b * 65536 + (size_t)co * 512;
        #pragma unroll
        for (int lt = 0; lt < 3; ++lt) {
            int l = (l0 - 8 + 16 * lt + 4 * kg) & 511;
            hyR[lt] = *(const f32x4*)(src + (size_t)co * 512 + l);
            omR[lt] = *(const f32x4*)(omega + ob + l);
            alR[lt] = *(const f32x4*)(alpha + ob + l);
            if (t0 > 0) hzR[lt] = *(const f32x4*)(hz_in + ob + l);
            else        hzR[lt] = (f32x4){0.f, 0.f, 0.f, 0.f};
        }
    }
    __syncthreads();   // hySd[0] visible

    // ---- ns steps, ONE lds_sync each
    for (int i = 0; i < ns; ++i) {
        const uint4* hc = &hySd[i & 1][0];
        unsigned short* hn16 = (unsigned short*)&hySd[(i + 1) & 1][0];
        float* yt = ytmp + (i & 1) * 4608;

        f32x4 acc[3];
        #pragma unroll
        for (int lt = 0; lt < 3; ++lt) acc[lt] = (f32x4){0.f, 0.f, 0.f, 0.f};
        __builtin_amdgcn_s_setprio(1);
        #pragma unroll
        for (int s = 0; s < 12; ++s) {
            int chunk = (s & 3) * 4 + kg;
            int k = s >> 2;
            bf16x8 Bf = Bw[s];
            #pragma unroll
            for (int lt = 0; lt < 3; ++lt) {
                int arow = 16 * lt + lr + k;
                bf16x8 a = __builtin_bit_cast(bf16x8, hc[arow * 16 + ((arow & 7) ^ chunk)]);
                acc[lt] = __builtin_amdgcn_mfma_f32_16x16x32_bf16(a, Bf, acc[lt], 0, 0, 0);
            }
        }
        __builtin_amdgcn_s_setprio(0);

        float lsum = 0.f;
        #pragma unroll
        for (int lt = 0; lt < 3; ++lt) {
            #pragma unroll
            for (int j = 0; j < 4; ++j) {
                float spring = tanh_fast(acc[lt][j]);
                float zn = hzR[lt][j] + DTc * (spring - omR[lt][j] * hyR[lt][j] - alR[lt][j] * hzR[lt][j]);
                float hn = hyR[lt][j] + DTc * zn;
                hzR[lt][j] = zn;
                hyR[lt][j] = hn;
            }
            bool valid = (lt == 0) ? (kg >= 2) : (lt == 2) ? (kg < 2) : true;
            int r0 = 16 * lt + 4 * kg;
            if (valid) {
                *(f32x4*)(yt + co * 36 + (r0 - 8)) = hyR[lt];
                lsum += hyR[lt][0] + hyR[lt][1] + hyR[lt][2] + hyR[lt][3];
                if (i == ns - 1)
                    *(f32x4*)(hz_out + (size_t)b * 65536 + (size_t)co * 512 + l0 + (r0 - 8)) = hzR[lt];
            }
            #pragma unroll
            for (int j = 0; j < 4; ++j) {
                int rr = r0 + j + 1;
                int sidx = rr * 128 + (((co >> 3) ^ (rr & 7)) << 3) + (co & 7);
                hn16[sidx] = f2bf(hyR[lt][j]);
            }
        }
        lsum += __shfl_xor(lsum, 16);
        lsum += __shfl_xor(lsum, 32);
        if (kg == 0) part[(((size_t)b * 50 + t0 + i) * 128 + co) * 16 + tile] = lsum;

        lds_sync();   // hySd[nxt] + yt writes visible; prior yt reads drained

        // coalesced y store from yt (128B runs)
        {
            float* yrow = ybase + (size_t)b * YB + (size_t)i * YT;
            int cs = wid * 16 + (lane >> 3);
            int lq = (lane & 7) * 4;
            #pragma unroll
            for (int cq = 0; cq < 2; ++cq) {
                int c2 = cs + cq * 8;
                f32x4 v = *(const f32x4*)(yt + c2 * 36 + lq);
                *(f32x4*)(yrow + (size_t)c2 * 512 + l0 + lq) = v;
            }
        }
    }

    // ---- epilogue: export center bf16 rows (hyS rows 9..40 <-> l0..l0+31)
    {
        const uint4* hl = &hySd[ns & 1][0];
        int row = tid >> 4, c8 = tid & 15;       // tid < 512
        int h = row + 9;
        ((uint4*)hyt_out)[((size_t)b * 512 + l0 + row) * 16 + c8] =
            hl[h * 16 + (c8 ^ (h & 7))];
    }
}

// ==================== readout ====================
__global__ __launch_bounds__(256) void readout_k(
    const float* __restrict__ part, const float* __restrict__ fct,
    const float* __restrict__ rw1, const float* __restrict__ rb1,
    const float* __restrict__ rw2, const float* __restrict__ rb2,
    const float* __restrict__ rw3, const float* __restrict__ rb3,
    float* __restrict__ out)
{
    int b = blockIdx.x, tid = threadIdx.x;
    __shared__ float ybar[50 * 128];
    __shared__ float feat[26 * 128];
    __shared__ float h1[64];
    __shared__ float h2[32];
    for (int idx = tid; idx < 50 * 128; idx += 256) {
        const float* p = part + ((size_t)b * 6400 + idx) * 16;
        float s = 0.f;
        #pragma unroll
        for (int q = 0; q < 16; ++q) s += p[q];
        ybar[idx] = s * (1.f / 512.f);
    }
    __syncthreads();
    for (int idx = tid; idx < 26 * 128; idx += 256) {
        int k = idx >> 7, c = idx & 127;
        float s = 0.f;
        for (int t = 0; t < 50; ++t) s += fct[k * 50 + t] * ybar[t * 128 + c];
        feat[idx] = s;
    }
    __syncthreads();
    {
        int j = tid >> 2, q = tid & 3;
        float s = 0.f;
        const float* r = rw1 + (size_t)j * 3328 + q * 832;
        const float* f = feat + q * 832;
        for (int i = 0; i < 832; ++i) s += f[i] * r[i];
        s += __shfl_xor(s, 1);
        s += __shfl_xor(s, 2);
        if (q == 0) h1[j] = fmaxf(s + rb1[j], 0.f);
    }
    __syncthreads();
    if (tid < 32) {
        float s = 0.f;
        for (int i = 0; i < 64; ++i) s += h1[i] * rw2[tid * 64 + i];
        h2[tid] = fmaxf(s + rb2[tid], 0.f);
    }
    __syncthreads();
    if (tid == 0) {
        float s = 0.f;
        for (int i = 0; i < 32; ++i) s += h2[i] * rw3[i];
        out[b] = s + rb3[0];
    }
}

// ==================== launch ====================
extern "C" void kernel_launch(void* const* d_in, const int* in_sizes, int n_in,
                              void* d_out, int out_size, void* d_ws, size_t ws_size,
                              hipStream_t stream)
{
    const float* x   = (const float*)d_in[0];
    const float* ow1 = (const float*)d_in[1];  const float* ob1 = (const float*)d_in[2];
    const float* ow2 = (const float*)d_in[3];  const float* ob2 = (const float*)d_in[4];
    const float* ow3 = (const float*)d_in[5];  const float* ob3 = (const float*)d_in[6];
    const float* aw1 = (const float*)d_in[7];  const float* ab1 = (const float*)d_in[8];
    const float* aw2 = (const float*)d_in[9];  const float* ab2 = (const float*)d_in[10];
    const float* aw3 = (const float*)d_in[11]; const float* ab3 = (const float*)d_in[12];
    const float* hw1 = (const float*)d_in[13]; const float* hb1 = (const float*)d_in[14];
    const float* hw2 = (const float*)d_in[15]; const float* hb2 = (const float*)d_in[16];
    const float* hw3 = (const float*)d_in[17]; const float* hb3 = (const float*)d_in[18];
    const float* hw4 = (const float*)d_in[19]; const float* hb4 = (const float*)d_in[20];
    const float* wy  = (const float*)d_in[21];
    const float* fct = (const float*)d_in[22];
    const float* rw1 = (const float*)d_in[23]; const float* rb1 = (const float*)d_in[24];
    const float* rw2 = (const float*)d_in[25]; const float* rb2 = (const float*)d_in[26];
    const float* rw3 = (const float*)d_in[27]; const float* rb3 = (const float*)d_in[28];

    float* out  = (float*)d_out;
    float* yout = out + 32;                       // y_seq region
    float* ws   = (float*)d_ws;

    // ws layout (float offsets)
    float* OMEGA = ws;                            // 2,097,152
    float* ALPHA = ws + 2097152;                  // 2,097,152
    float* WT    = ws + 4194304;                  // 304,128 (9216 fp32 + 12x49152 u16)
    float* PART  = ws + 4498432;                  // 3,276,800 (32*50*128*16)
    float* HZ0   = ws + 7775232;                  // 2,097,152
    float* HZ1   = ws + 9872384;                  // 2,097,152
    unsigned short* HYT0 = (unsigned short*)(ws + 11969536);   // 4MB (bf16 [b][l][c8])
    unsigned short* HYT1 = (unsigned short*)(ws + 13018112);   // 4MB; end 14,066,688 (~56.3MB)

    // encoder scratch slabs inside y region (overwritten by chunks covering
    // t >= 42, long after last encoder use)
    float* To1 = yout + 44 * YT;
    float* Ta1 = yout + 45 * YT;
    float* Th1 = yout + 46 * YT;
    float* To2 = yout + 47 * YT;
    float* Ta2 = yout + 43 * YT;
    float* Th2 = yout + 49 * YT;
    float* Th3 = yout + 42 * YT;
    float* HY0 = yout + 48 * YT;

    float* OW1T = WT + 0;  float* AW1T = WT + 3072;  float* HW1T = WT + 6144;
    unsigned short* U16 = (unsigned short*)(WT + 9216);
    unsigned short* W2WY = U16;
    unsigned short* W2H2 = U16 + 49152;
    unsigned short* W2H3 = U16 + 98304;
    unsigned short* W2H4 = U16 + 147456;
    unsigned short* OW2H = U16 + 196608;  unsigned short* OW2L = U16 + 245760;
    unsigned short* OW3H = U16 + 294912;  unsigned short* OW3L = U16 + 344064;
    unsigned short* AW2H = U16 + 393216;  unsigned short* AW2L = U16 + 442368;
    unsigned short* AW3H = U16 + 491520;  unsigned short* AW3L = U16 + 540672;

    WSrc wsrc;
    wsrc.p[0] = ow1; wsrc.p[1] = aw1; wsrc.p[2] = hw1;
    wsrc.p[3] = ow2; wsrc.p[4] = ow3; wsrc.p[5] = aw2; wsrc.p[6] = aw3;
    wsrc.p[7] = hw2; wsrc.p[8] = hw3; wsrc.p[9] = hw4; wsrc.p[10] = wy;
    wprep_all_k<<<2340, 256, 0, stream>>>(wsrc, WT);

    // layer 1 (fp32): all three encoders
    Jobs3 d1 = {{ {x, To1, OW1T, ob1, 4096, YB, 1},
                  {x, Ta1, AW1T, ab1, 4096, YB, 1},
                  {x, Th1, HW1T, hb1, 4096, YB, 1} }};
    conv8x3_k<<<dim3(8, 3, 32), 256, 0, stream>>>(d1);

    // omega/alpha layers 2-3 (split-bf16 MFMA)
    MJobs2 e2 = {{ {To1, To2, OW2H, OW2L, ob2, YB, YB},
                   {Ta1, Ta2, AW2H, AW2L, ab2, YB, YB} }};
    mconv2_k<<<dim3(16, 32, 2), 512, 0, stream>>>(e2);
    MJobs2 e3 = {{ {To2, OMEGA, OW3H, OW3L, ob3, YB, 65536},
                   {Ta2, ALPHA, AW3H, AW3L, ab3, YB, 65536} }};
    mconv2_k<<<dim3(16, 32, 2), 512, 0, stream>>>(e3);

    // hy chain layers 2-4 (bf16 MFMA); last layer seeds HYT0
    mconv_k<<<dim3(16, 32), 512, 0, stream>>>(Th1, YB, Th2, YB, W2H2, hb2, 1, nullptr);
    mconv_k<<<dim3(16, 32), 512, 0, stream>>>(Th2, YB, Th3, YB, W2H3, hb3, 1, nullptr);
    mconv_k<<<dim3(16, 32), 512, 0, stream>>>(Th3, YB, HY0, YB, W2H4, hb4, 2, HYT0);

    // ---- recurrence: 8-step chunks (8,8,8,8,8,8,2), bf16 HYT handoff
    {
        int t0 = 0, c = 0;
        while (t0 < 50) {
            int ns = (50 - t0 >= 8) ? 8 : (50 - t0);
            const unsigned short* hin = (c & 1) ? HYT1 : HYT0;
            unsigned short* hout      = (c & 1) ? HYT0 : HYT1;
            const float* hyin = (t0 == 0) ? HY0 : (yout + (size_t)(t0 - 1) * YT);
            const float* hzin = (c & 1) ? HZ1 : HZ0;
            float* hzout      = (c & 1) ? HZ0 : HZ1;
            chunk_k<<<dim3(16, 32), 512, 0, stream>>>(hin, hout, hyin, hzin, hzout,
                                                      OMEGA, ALPHA, W2WY,
                                                      yout + (size_t)t0 * YT, PART, t0, ns);
            t0 += ns; ++c;
        }
    }

    readout_k<<<32, 256, 0, stream>>>(PART, fct, rw1, rb1, rw2, rb2, rw3, rb3, out);
}

// Round 12
// 537.219 us; speedup vs baseline: 4.2092x; 1.0168x over previous
//
#include <hip/hip_runtime.h>
#include <math.h>

#define YB (50*128*512)   // y_seq batch stride (floats)
#define YT (128*512)      // y_seq time stride
#define DTc 0.5f

typedef __attribute__((ext_vector_type(8))) short bf16x8;
typedef __attribute__((ext_vector_type(4))) float f32x4;

__device__ __forceinline__ unsigned short f2bf(float f) {
    unsigned int u = __builtin_bit_cast(unsigned int, f);
    u += 0x7fffu + ((u >> 16) & 1u);          // RNE
    return (unsigned short)(u >> 16);
}
__device__ __forceinline__ float bf2f(unsigned short h) {
    unsigned int u = ((unsigned int)h) << 16;
    return __builtin_bit_cast(float, u);
}

__device__ __forceinline__ float tanh_fast(float x) {
    float ax = fabsf(x);
    float e  = __expf(-2.f * ax);
    float r  = (1.f - e) * __builtin_amdgcn_rcpf(1.f + e);
    return __builtin_copysignf(r, x);
}

// raw block barrier: waits LDS ops only, lets global stores stay in flight
__device__ __forceinline__ void lds_sync() {
    asm volatile("s_waitcnt lgkmcnt(0)" ::: "memory");
    __builtin_amdgcn_sched_barrier(0);
    __builtin_amdgcn_s_barrier();
    __builtin_amdgcn_sched_barrier(0);
}

// k=1 A-fragment from k=0 (row_shl:1, lanes 0..14) + k=2 (row_shr:1, lanes 1..15).
// Both deliver the same logical rows (r0+n+1); DPP rows == our 16-lane lr groups.
__device__ __forceinline__ uint4 dpp_k1(uint4 a0, uint4 a2) {
    uint4 r;
    int t;
    t = __builtin_amdgcn_update_dpp(0, (int)a0.x, 0x101, 0xF, 0xF, false);
    r.x = (unsigned)__builtin_amdgcn_update_dpp(t, (int)a2.x, 0x111, 0xF, 0xF, false);
    t = __builtin_amdgcn_update_dpp(0, (int)a0.y, 0x101, 0xF, 0xF, false);
    r.y = (unsigned)__builtin_amdgcn_update_dpp(t, (int)a2.y, 0x111, 0xF, 0xF, false);
    t = __builtin_amdgcn_update_dpp(0, (int)a0.z, 0x101, 0xF, 0xF, false);
    r.z = (unsigned)__builtin_amdgcn_update_dpp(t, (int)a2.z, 0x111, 0xF, 0xF, false);
    t = __builtin_amdgcn_update_dpp(0, (int)a0.w, 0x101, 0xF, 0xF, false);
    r.w = (unsigned)__builtin_amdgcn_update_dpp(t, (int)a2.w, 0x111, 0xF, 0xF, false);
    return r;
}

// ==================== fused weight prep ====================
// wt floats: [0,9216) conv8 transposes.
// u16 region at wt+9216: 12 x 49152 kappa-format bf16 sets:
//   0 wy, 1 hw2, 2 hw3, 3 hw4, 4 ow2h,5 ow2l, 6 ow3h,7 ow3l, 8 aw2h,9 aw2l, 10 aw3h,11 aw3l
struct WSrc { const float* p[11]; };  // ow1,aw1,hw1, ow2,ow3,aw2,aw3,hw2,hw3,hw4, wy
__global__ void wprep_all_k(WSrc s, float* __restrict__ wt) {
    int idx = blockIdx.x * 256 + threadIdx.x;
    if (idx < 9216) {
        int wsel = idx / 3072, r = idx % 3072;
        int row = r >> 7, co = r & 127;
        int ci = row / 3, k = row - ci * 3;
        wt[idx] = s.p[wsel][(co * 8 + ci) * 3 + k];
    } else if (idx < 9216 + 589824) {
        int q = idx - 9216;
        int cv = q / 49152, r = q % 49152;
        int co = r / 384, kap = r % 384;
        int k = kap >> 7;
        int ci = ((kap >> 5) & 3) * 32 + (kap & 31);
        const int selmap[12] = {10, 7, 8, 9, 3, 3, 4, 4, 5, 5, 6, 6};
        float w = s.p[selmap[cv]][(co * 128 + ci) * 3 + k];
        unsigned short hv = f2bf(w);
        unsigned short ov = ((cv >= 4) && (cv & 1)) ? f2bf(w - bf2f(hv)) : hv;
        ((unsigned short*)(wt + 9216))[q] = ov;
    }
}

// ==================== conv8 layer (fp32, 3 jobs) ====================
struct Job { const float* src; float* dst; const float* wt; const float* bias; int sbs, dbs, act; };
struct Jobs3 { Job j[3]; };

__global__ __launch_bounds__(256) void conv8x3_k(Jobs3 js) {
    int jb = blockIdx.y % 3;
    Job jo = js.j[jb];
    int b = blockIdx.z, tile = blockIdx.x, tid = threadIdx.x;
    int l0 = tile * 64;
    int tl4 = (tid & 15) * 4;
    int co0 = (tid >> 4) * 8;
    __shared__ float xs[8 * 68];
    __shared__ float wsh[24 * 128];
    const float* sb = jo.src + (size_t)b * jo.sbs;
    for (int idx = tid; idx < 8 * 66; idx += 256) {
        int ci = idx / 66, ll = idx - ci * 66;
        int gl = l0 - 1 + ll;
        xs[ci * 68 + ll] = (gl >= 0 && gl < 512) ? sb[ci * 512 + gl] : 0.f;
    }
    for (int idx = tid; idx < 24 * 128; idx += 256) wsh[idx] = jo.wt[idx];
    __syncthreads();
    float acc[8][4] = {};
    #pragma unroll
    for (int ci = 0; ci < 8; ++ci) {
        float x6[6];
        #pragma unroll
        for (int j = 0; j < 6; ++j) x6[j] = xs[ci * 68 + tl4 + j];
        #pragma unroll
        for (int k = 0; k < 3; ++k) {
            float w8[8];
            #pragma unroll
            for (int i = 0; i < 8; ++i) w8[i] = wsh[(ci * 3 + k) * 128 + co0 + i];
            #pragma unroll
            for (int i = 0; i < 8; ++i)
                #pragma unroll
                for (int j = 0; j < 4; ++j)
                    acc[i][j] = fmaf(w8[i], x6[k + j], acc[i][j]);
        }
    }
    #pragma unroll
    for (int i = 0; i < 8; ++i) {
        int co = co0 + i;
        float bv = jo.bias[co];
        float4 o;
        o.x = fmaxf(acc[i][0] + bv, 0.f);
        o.y = fmaxf(acc[i][1] + bv, 0.f);
        o.z = fmaxf(acc[i][2] + bv, 0.f);
        o.w = fmaxf(acc[i][3] + bv, 0.f);
        *(float4*)(jo.dst + (size_t)b * jo.dbs + (size_t)co * 512 + l0 + tl4) = o;
    }
}

// ==================== unified MFMA conv128 (relu) ====================
// wlo != null: split-bf16 (xh*wh + xl*wh + xh*wl). wlo == null: plain bf16.
struct UJob { const float* src; float* dst; const unsigned short* whi;
              const unsigned short* wlo; const float* bias; int sbs, dbs; };
struct UJobs3 { UJob j[3]; };

__global__ __launch_bounds__(512) void uconv_k(UJobs3 js) {
    UJob jo = js.j[blockIdx.z];
    int tile = blockIdx.x, b = blockIdx.y;
    int tid = threadIdx.x, lane = tid & 63, wid = tid >> 6;
    int lr = lane & 15, kg = lane >> 4;
    int co = wid * 16 + lr;
    int l0 = tile * 32;
    bool dual = (jo.wlo != nullptr);

    __shared__ float stage[128 * 40];
    __shared__ uint4 hiX[34 * 16];
    __shared__ uint4 loX[34 * 16];

    const bf16x8* wph = (const bf16x8*)(jo.whi + (size_t)co * 384);
    bf16x8 Bh[12];
    #pragma unroll
    for (int s = 0; s < 12; ++s) Bh[s] = wph[s * 4 + kg];

    const float* sb = jo.src + (size_t)b * jo.sbs;
    for (int i = tid; i < 1280; i += 512) {
        int c = i / 10, p4 = (i - c * 10) * 4;
        int l = l0 - 4 + p4;
        f32x4 v;
        if (l >= 0 && l <= 508) {
            v = *(const f32x4*)(sb + (size_t)c * 512 + l);
        } else {
            #pragma unroll
            for (int e = 0; e < 4; ++e) {
                int le = l + e;
                v[e] = (le >= 0 && le < 512) ? sb[(size_t)c * 512 + le] : 0.f;
            }
        }
        *(f32x4*)(stage + c * 40 + p4) = v;
    }
    __syncthreads();
    for (int i = tid; i < 34 * 16; i += 512) {
        int h = i >> 4, c8 = i & 15;
        unsigned short ph[8], pl[8];
        #pragma unroll
        for (int q = 0; q < 8; ++q) {
            float x = stage[(c8 * 8 + q) * 40 + h + 3];
            unsigned short hv = f2bf(x);
            ph[q] = hv;
            pl[q] = f2bf(x - bf2f(hv));
        }
        int sx = h * 16 + (c8 ^ (h & 7));
        hiX[sx] = *(uint4*)ph;
        if (dual) loX[sx] = *(uint4*)pl;
    }
    __syncthreads();

    f32x4 acc[2];
    acc[0] = (f32x4){0.f, 0.f, 0.f, 0.f};
    acc[1] = (f32x4){0.f, 0.f, 0.f, 0.f};
    __builtin_amdgcn_s_setprio(1);
    if (dual) {
        const bf16x8* wpl = (const bf16x8*)(jo.wlo + (size_t)co * 384);
        bf16x8 blc = wpl[kg];
        #pragma unroll
        for (int s = 0; s < 12; ++s) {
            bf16x8 Bl = blc;
            if (s < 11) blc = wpl[(s + 1) * 4 + kg];
            int k = s >> 2;
            int chunk = (s & 3) * 4 + kg;
            #pragma unroll
            for (int lt = 0; lt < 2; ++lt) {
                int arow = 16 * lt + lr + k;
                int ai = arow * 16 + ((arow & 7) ^ chunk);
                bf16x8 ah = __builtin_bit_cast(bf16x8, hiX[ai]);
                bf16x8 al = __builtin_bit_cast(bf16x8, loX[ai]);
                acc[lt] = __builtin_amdgcn_mfma_f32_16x16x32_bf16(ah, Bh[s], acc[lt], 0, 0, 0);
                acc[lt] = __builtin_amdgcn_mfma_f32_16x16x32_bf16(al, Bh[s], acc[lt], 0, 0, 0);
                acc[lt] = __builtin_amdgcn_mfma_f32_16x16x32_bf16(ah, Bl,    acc[lt], 0, 0, 0);
            }
        }
    } else {
        #pragma unroll
        for (int s = 0; s < 12; ++s) {
            int k = s >> 2;
            int chunk = (s & 3) * 4 + kg;
            #pragma unroll
            for (int lt = 0; lt < 2; ++lt) {
                int arow = 16 * lt + lr + k;
                bf16x8 ah = __builtin_bit_cast(bf16x8, hiX[arow * 16 + ((arow & 7) ^ chunk)]);
                acc[lt] = __builtin_amdgcn_mfma_f32_16x16x32_bf16(ah, Bh[s], acc[lt], 0, 0, 0);
            }
        }
    }
    __builtin_amdgcn_s_setprio(0);

    float bv = jo.bias[co];
    #pragma unroll
    for (int lt = 0; lt < 2; ++lt) {
        float v[4];
        #pragma unroll
        for (int j = 0; j < 4; ++j) v[j] = fmaxf(acc[lt][j] + bv, 0.f);
        *(f32x4*)(jo.dst + (size_t)b * jo.dbs + (size_t)co * 512 + l0 + 16 * lt + 4 * kg) = *(f32x4*)v;
    }
}

// ==================== bf16-MFMA conv128 (hy4: tanh + HYT seed) ====================
__global__ __launch_bounds__(512) void mconv_k(
    const float* __restrict__ src, int sbs,
    float* __restrict__ dst, int dbs,
    const unsigned short* __restrict__ w2,
    const float* __restrict__ bias,
    unsigned short* __restrict__ hyt)
{
    int tile = blockIdx.x, b = blockIdx.y;
    int tid = threadIdx.x, lane = tid & 63, wid = tid >> 6;
    int lr = lane & 15, kg = lane >> 4;
    int co = wid * 16 + lr;
    int l0 = tile * 32;

    __shared__ float stage[128 * 40];
    __shared__ uint4 hyX[34 * 16];

    bf16x8 Bw[12];
    {
        const bf16x8* wp = (const bf16x8*)(w2 + (size_t)co * 384);
        #pragma unroll
        for (int s = 0; s < 12; ++s) Bw[s] = wp[s * 4 + kg];
    }

    const float* sb = src + (size_t)b * sbs;
    for (int i = tid; i < 1280; i += 512) {
        int c = i / 10, p4 = (i - c * 10) * 4;
        int l = l0 - 4 + p4;
        f32x4 v;
        if (l >= 0 && l <= 508) {
            v = *(const f32x4*)(sb + (size_t)c * 512 + l);
        } else {
            #pragma unroll
            for (int e = 0; e < 4; ++e) {
                int le = l + e;
                v[e] = (le >= 0 && le < 512) ? sb[(size_t)c * 512 + le] : 0.f;
            }
        }
        *(f32x4*)(stage + c * 40 + p4) = v;
    }
    __syncthreads();
    for (int i = tid; i < 34 * 16; i += 512) {
        int h = i >> 4, c8 = i & 15;
        unsigned short pk[8];
        #pragma unroll
        for (int q = 0; q < 8; ++q) pk[q] = f2bf(stage[(c8 * 8 + q) * 40 + h + 3]);
        hyX[h * 16 + (c8 ^ (h & 7))] = *(uint4*)pk;
    }
    __syncthreads();

    f32x4 acc[2];
    acc[0] = (f32x4){0.f, 0.f, 0.f, 0.f};
    acc[1] = (f32x4){0.f, 0.f, 0.f, 0.f};
    __builtin_amdgcn_s_setprio(1);
    #pragma unroll
    for (int s = 0; s < 12; ++s) {
        int k = s >> 2;
        int chunk = (s & 3) * 4 + kg;
        bf16x8 Bf = Bw[s];
        #pragma unroll
        for (int lt = 0; lt < 2; ++lt) {
            int arow = 16 * lt + lr + k;
            bf16x8 a = __builtin_bit_cast(bf16x8, hyX[arow * 16 + ((arow & 7) ^ chunk)]);
            acc[lt] = __builtin_amdgcn_mfma_f32_16x16x32_bf16(a, Bf, acc[lt], 0, 0, 0);
        }
    }
    __builtin_amdgcn_s_setprio(0);

    float bv = bias[co];
    float vv[2][4];
    #pragma unroll
    for (int lt = 0; lt < 2; ++lt) {
        #pragma unroll
        for (int j = 0; j < 4; ++j)
            vv[lt][j] = tanh_fast(acc[lt][j] + bv);
        *(f32x4*)(dst + (size_t)b * dbs + (size_t)co * 512 + l0 + 16 * lt + 4 * kg) = *(f32x4*)vv[lt];
    }

    lds_sync();                       // all hyX MFMA reads complete
    {
        unsigned short* t16 = (unsigned short*)hyX;
        #pragma unroll
        for (int lt = 0; lt < 2; ++lt)
            #pragma unroll
            for (int j = 0; j < 4; ++j)
                t16[(16 * lt + 4 * kg + j) * 128 + co] = f2bf(vv[lt][j]);
        lds_sync();
        int row = tid >> 4, c8 = tid & 15;    // tid < 512 -> row < 32
        ((uint4*)hyt)[((size_t)b * 512 + l0 + row) * 16 + c8] =
            ((uint4*)hyX)[row * 16 + c8];
    }
}

// ==================== ns-step chunk kernel ====================
// 512 blocks (16 l-tiles of center 32 x 32 b), 512 threads, 2 blocks/CU.
// A-reads: k0,k2 from LDS; k1 via DPP (row_shl/shr within lr groups) -> 24
// reads/wave/step instead of 36. hy enters/leaves as packed bf16 HYT.
// hyS + y-temp double-buffered -> ONE lds_sync per step. Shrinking halo: ns<=8.
__global__ __launch_bounds__(512, 2) void chunk_k(
    const unsigned short* __restrict__ hyt_in,   // [b][512][16] uint4 bf16
    unsigned short* __restrict__ hyt_out,
    const float* __restrict__ hy_in,   // fp32 [b][co][l], b-stride YB
    const float* __restrict__ hz_in,   // [b][co][l], b-stride 65536
    float* __restrict__ hz_out,
    const float* __restrict__ omega, const float* __restrict__ alpha,
    const unsigned short* __restrict__ w2,
    float* __restrict__ ybase,         // slab t0 base
    float* __restrict__ part, int t0, int ns)
{
    int tile = blockIdx.x, b = blockIdx.y;
    int tid = threadIdx.x, lane = tid & 63, wid = tid >> 6;
    int lr = lane & 15, kg = lane >> 4;
    int co = wid * 16 + lr;
    int l0 = tile * 32;

    __shared__ uint4 hySd[2][800];         // [buf][row h 0..49][chunk ^ (h&7)]
    __shared__ float ytmp[2 * 4608];       // [buf][co][36]

    bf16x8 Bw[12];
    {
        const bf16x8* wp = (const bf16x8*)(w2 + (size_t)co * 384);
        #pragma unroll
        for (int s = 0; s < 12; ++s) Bw[s] = wp[s * 4 + kg];
    }

    f32x4 hyR[3], hzR[3], omR[3], alR[3];

    // ---- prologue: hySd[0] from HYT (coalesced), hyR/om/al/hz direct
    {
        const uint4* hsrc = (const uint4*)hyt_in + (size_t)b * 8192;
        for (int i = tid; i < 800; i += 512) {
            int h = i >> 4, c8 = i & 15;
            int l = (l0 - 9 + h) & 511;
            hySd[0][h * 16 + (c8 ^ (h & 7))] = hsrc[l * 16 + c8];
        }
    }
    {
        const float* src = hy_in + (size_t)b * YB;
        size_t ob = (size_t)b * 65536 + (size_t)co * 512;
        #pragma unroll
        for (int lt = 0; lt < 3; ++lt) {
            int l = (l0 - 8 + 16 * lt + 4 * kg) & 511;
            hyR[lt] = *(const f32x4*)(src + (size_t)co * 512 + l);
            omR[lt] = *(const f32x4*)(omega + ob + l);
            alR[lt] = *(const f32x4*)(alpha + ob + l);
            if (t0 > 0) hzR[lt] = *(const f32x4*)(hz_in + ob + l);
            else        hzR[lt] = (f32x4){0.f, 0.f, 0.f, 0.f};
        }
    }
    __syncthreads();   // hySd[0] visible

    // ---- ns steps, ONE lds_sync each
    for (int i = 0; i < ns; ++i) {
        const uint4* hc = &hySd[i & 1][0];
        unsigned short* hn16 = (unsigned short*)&hySd[(i + 1) & 1][0];
        float* yt = ytmp + (i & 1) * 4608;

        f32x4 acc[3];
        #pragma unroll
        for (int lt = 0; lt < 3; ++lt) acc[lt] = (f32x4){0.f, 0.f, 0.f, 0.f};
        __builtin_amdgcn_s_setprio(1);
        #pragma unroll
        for (int cs = 0; cs < 4; ++cs) {
            int chunk = cs * 4 + kg;
            bf16x8 B0 = Bw[cs], B1 = Bw[cs + 4], B2 = Bw[cs + 8];
            #pragma unroll
            for (int lt = 0; lt < 3; ++lt) {
                int r0 = 16 * lt + lr;
                int r2 = r0 + 2;
                uint4 a0 = hc[r0 * 16 + ((r0 & 7) ^ chunk)];
                uint4 a2 = hc[r2 * 16 + ((r2 & 7) ^ chunk)];
                acc[lt] = __builtin_amdgcn_mfma_f32_16x16x32_bf16(
                    __builtin_bit_cast(bf16x8, a0), B0, acc[lt], 0, 0, 0);
                acc[lt] = __builtin_amdgcn_mfma_f32_16x16x32_bf16(
                    __builtin_bit_cast(bf16x8, a2), B2, acc[lt], 0, 0, 0);
                uint4 a1 = dpp_k1(a0, a2);
                acc[lt] = __builtin_amdgcn_mfma_f32_16x16x32_bf16(
                    __builtin_bit_cast(bf16x8, a1), B1, acc[lt], 0, 0, 0);
            }
        }
        __builtin_amdgcn_s_setprio(0);

        float lsum = 0.f;
        #pragma unroll
        for (int lt = 0; lt < 3; ++lt) {
            #pragma unroll
            for (int j = 0; j < 4; ++j) {
                float spring = tanh_fast(acc[lt][j]);
                float zn = hzR[lt][j] + DTc * (spring - omR[lt][j] * hyR[lt][j] - alR[lt][j] * hzR[lt][j]);
                float hn = hyR[lt][j] + DTc * zn;
                hzR[lt][j] = zn;
                hyR[lt][j] = hn;
            }
            bool valid = (lt == 0) ? (kg >= 2) : (lt == 2) ? (kg < 2) : true;
            int r0 = 16 * lt + 4 * kg;
            if (valid) {
                *(f32x4*)(yt + co * 36 + (r0 - 8)) = hyR[lt];
                lsum += hyR[lt][0] + hyR[lt][1] + hyR[lt][2] + hyR[lt][3];
                if (i == ns - 1)
                    *(f32x4*)(hz_out + (size_t)b * 65536 + (size_t)co * 512 + l0 + (r0 - 8)) = hzR[lt];
            }
            #pragma unroll
            for (int j = 0; j < 4; ++j) {
                int rr = r0 + j + 1;
                int sidx = rr * 128 + (((co >> 3) ^ (rr & 7)) << 3) + (co & 7);
                hn16[sidx] = f2bf(hyR[lt][j]);
            }
        }
        lsum += __shfl_xor(lsum, 16);
        lsum += __shfl_xor(lsum, 32);
        if (kg == 0) part[(((size_t)b * 50 + t0 + i) * 128 + co) * 16 + tile] = lsum;

        lds_sync();   // hySd[nxt] + yt writes visible; prior yt reads drained

        // coalesced y store from yt (128B runs)
        {
            float* yrow = ybase + (size_t)b * YB + (size_t)i * YT;
            int cs2 = wid * 16 + (lane >> 3);
            int lq = (lane & 7) * 4;
            #pragma unroll
            for (int cq = 0; cq < 2; ++cq) {
                int c2 = cs2 + cq * 8;
                f32x4 v = *(const f32x4*)(yt + c2 * 36 + lq);
                *(f32x4*)(yrow + (size_t)c2 * 512 + l0 + lq) = v;
            }
        }
    }

    // ---- epilogue: export center bf16 rows (hyS rows 9..40 <-> l0..l0+31)
    {
        const uint4* hl = &hySd[ns & 1][0];
        int row = tid >> 4, c8 = tid & 15;       // tid < 512
        int h = row + 9;
        ((uint4*)hyt_out)[((size_t)b * 512 + l0 + row) * 16 + c8] =
            hl[h * 16 + (c8 ^ (h & 7))];
    }
}

// ==================== readout ====================
__global__ __launch_bounds__(256) void readout_k(
    const float* __restrict__ part, const float* __restrict__ fct,
    const float* __restrict__ rw1, const float* __restrict__ rb1,
    const float* __restrict__ rw2, const float* __restrict__ rb2,
    const float* __restrict__ rw3, const float* __restrict__ rb3,
    float* __restrict__ out)
{
    int b = blockIdx.x, tid = threadIdx.x;
    __shared__ float ybar[50 * 128];
    __shared__ float feat[26 * 128];
    __shared__ float h1[64];
    __shared__ float h2[32];
    for (int idx = tid; idx < 50 * 128; idx += 256) {
        const float* p = part + ((size_t)b * 6400 + idx) * 16;
        float s = 0.f;
        #pragma unroll
        for (int q = 0; q < 16; ++q) s += p[q];
        ybar[idx] = s * (1.f / 512.f);
    }
    __syncthreads();
    for (int idx = tid; idx < 26 * 128; idx += 256) {
        int k = idx >> 7, c = idx & 127;
        float s = 0.f;
        for (int t = 0; t < 50; ++t) s += fct[k * 50 + t] * ybar[t * 128 + c];
        feat[idx] = s;
    }
    __syncthreads();
    {
        int j = tid >> 2, q = tid & 3;
        float s = 0.f;
        const float* r = rw1 + (size_t)j * 3328 + q * 832;
        const float* f = feat + q * 832;
        for (int i = 0; i < 832; ++i) s += f[i] * r[i];
        s += __shfl_xor(s, 1);
        s += __shfl_xor(s, 2);
        if (q == 0) h1[j] = fmaxf(s + rb1[j], 0.f);
    }
    __syncthreads();
    if (tid < 32) {
        float s = 0.f;
        for (int i = 0; i < 64; ++i) s += h1[i] * rw2[tid * 64 + i];
        h2[tid] = fmaxf(s + rb2[tid], 0.f);
    }
    __syncthreads();
    if (tid == 0) {
        float s = 0.f;
        for (int i = 0; i < 32; ++i) s += h2[i] * rw3[i];
        out[b] = s + rb3[0];
    }
}

// ==================== launch ====================
extern "C" void kernel_launch(void* const* d_in, const int* in_sizes, int n_in,
                              void* d_out, int out_size, void* d_ws, size_t ws_size,
                              hipStream_t stream)
{
    const float* x   = (const float*)d_in[0];
    const float* ow1 = (const float*)d_in[1];  const float* ob1 = (const float*)d_in[2];
    const float* ow2 = (const float*)d_in[3];  const float* ob2 = (const float*)d_in[4];
    const float* ow3 = (const float*)d_in[5];  const float* ob3 = (const float*)d_in[6];
    const float* aw1 = (const float*)d_in[7];  const float* ab1 = (const float*)d_in[8];
    const float* aw2 = (const float*)d_in[9];  const float* ab2 = (const float*)d_in[10];
    const float* aw3 = (const float*)d_in[11]; const float* ab3 = (const float*)d_in[12];
    const float* hw1 = (const float*)d_in[13]; const float* hb1 = (const float*)d_in[14];
    const float* hw2 = (const float*)d_in[15]; const float* hb2 = (const float*)d_in[16];
    const float* hw3 = (const float*)d_in[17]; const float* hb3 = (const float*)d_in[18];
    const float* hw4 = (const float*)d_in[19]; const float* hb4 = (const float*)d_in[20];
    const float* wy  = (const float*)d_in[21];
    const float* fct = (const float*)d_in[22];
    const float* rw1 = (const float*)d_in[23]; const float* rb1 = (const float*)d_in[24];
    const float* rw2 = (const float*)d_in[25]; const float* rb2 = (const float*)d_in[26];
    const float* rw3 = (const float*)d_in[27]; const float* rb3 = (const float*)d_in[28];

    float* out  = (float*)d_out;
    float* yout = out + 32;                       // y_seq region
    float* ws   = (float*)d_ws;

    // ws layout (float offsets)
    float* OMEGA = ws;                            // 2,097,152
    float* ALPHA = ws + 2097152;                  // 2,097,152
    float* WT    = ws + 4194304;                  // 304,128 (9216 fp32 + 12x49152 u16)
    float* PART  = ws + 4498432;                  // 3,276,800 (32*50*128*16)
    float* HZ0   = ws + 7775232;                  // 2,097,152
    float* HZ1   = ws + 9872384;                  // 2,097,152
    unsigned short* HYT0 = (unsigned short*)(ws + 11969536);   // 4MB (bf16 [b][l][c8])
    unsigned short* HYT1 = (unsigned short*)(ws + 13018112);   // 4MB; end 14,066,688 (~56.3MB)

    // encoder scratch slabs inside y region (overwritten by chunks covering
    // t >= 42, long after last encoder use)
    float* To1 = yout + 44 * YT;
    float* Ta1 = yout + 45 * YT;
    float* Th1 = yout + 46 * YT;
    float* To2 = yout + 47 * YT;
    float* Ta2 = yout + 43 * YT;
    float* Th2 = yout + 49 * YT;
    float* Th3 = yout + 42 * YT;
    float* HY0 = yout + 48 * YT;

    float* OW1T = WT + 0;  float* AW1T = WT + 3072;  float* HW1T = WT + 6144;
    unsigned short* U16 = (unsigned short*)(WT + 9216);
    unsigned short* W2WY = U16;
    unsigned short* W2H2 = U16 + 49152;
    unsigned short* W2H3 = U16 + 98304;
    unsigned short* W2H4 = U16 + 147456;
    unsigned short* OW2H = U16 + 196608;  unsigned short* OW2L = U16 + 245760;
    unsigned short* OW3H = U16 + 294912;  unsigned short* OW3L = U16 + 344064;
    unsigned short* AW2H = U16 + 393216;  unsigned short* AW2L = U16 + 442368;
    unsigned short* AW3H = U16 + 491520;  unsigned short* AW3L = U16 + 540672;

    WSrc wsrc;
    wsrc.p[0] = ow1; wsrc.p[1] = aw1; wsrc.p[2] = hw1;
    wsrc.p[3] = ow2; wsrc.p[4] = ow3; wsrc.p[5] = aw2; wsrc.p[6] = aw3;
    wsrc.p[7] = hw2; wsrc.p[8] = hw3; wsrc.p[9] = hw4; wsrc.p[10] = wy;
    wprep_all_k<<<2340, 256, 0, stream>>>(wsrc, WT);

    // layer 1 (fp32): all three encoders
    Jobs3 d1 = {{ {x, To1, OW1T, ob1, 4096, YB, 1},
                  {x, Ta1, AW1T, ab1, 4096, YB, 1},
                  {x, Th1, HW1T, hb1, 4096, YB, 1} }};
    conv8x3_k<<<dim3(8, 3, 32), 256, 0, stream>>>(d1);

    // layer 2: omega/alpha split-bf16 + hy plain bf16, ONE launch
    UJobs3 u2 = {{ {To1, To2, OW2H, OW2L, ob2, YB, YB},
                   {Ta1, Ta2, AW2H, AW2L, ab2, YB, YB},
                   {Th1, Th2, W2H2, nullptr, hb2, YB, YB} }};
    uconv_k<<<dim3(16, 32, 3), 512, 0, stream>>>(u2);

    // layer 3: same pattern
    UJobs3 u3 = {{ {To2, OMEGA, OW3H, OW3L, ob3, YB, 65536},
                   {Ta2, ALPHA, AW3H, AW3L, ab3, YB, 65536},
                   {Th2, Th3, W2H3, nullptr, hb3, YB, YB} }};
    uconv_k<<<dim3(16, 32, 3), 512, 0, stream>>>(u3);

    // hy layer 4 (tanh) + HYT0 seed
    mconv_k<<<dim3(16, 32), 512, 0, stream>>>(Th3, YB, HY0, YB, W2H4, hb4, HYT0);

    // ---- recurrence: 8-step chunks (8,8,8,8,8,8,2), bf16 HYT handoff
    {
        int t0 = 0, c = 0;
        while (t0 < 50) {
            int ns = (50 - t0 >= 8) ? 8 : (50 - t0);
            const unsigned short* hin = (c & 1) ? HYT1 : HYT0;
            unsigned short* hout      = (c & 1) ? HYT0 : HYT1;
            const float* hyin = (t0 == 0) ? HY0 : (yout + (size_t)(t0 - 1) * YT);
            const float* hzin = (c & 1) ? HZ1 : HZ0;
            float* hzout      = (c & 1) ? HZ0 : HZ1;
            chunk_k<<<dim3(16, 32), 512, 0, stream>>>(hin, hout, hyin, hzin, hzout,
                                                      OMEGA, ALPHA, W2WY,
                                                      yout + (size_t)t0 * YT, PART, t0, ns);
            t0 += ns; ++c;
        }
    }

    readout_k<<<32, 256, 0, stream>>>(PART, fct, rw1, rb1, rw2, rb2, rw3, rb3, out);
}